// Round 1
// baseline (4849.039 us; speedup 1.0000x reference)
//
#include <hip/hip_runtime.h>
#include <hip/hip_bf16.h>
#include <math.h>

// Problem constants
constexpr int Hdim = 768;
constexpr int NH   = 12;
constexpr int HD   = 64;
constexpr int NLAYER = 4;
constexpr int Bb   = 4;
constexpr int Ss   = 1024;
constexpr int Mm   = Bb * Ss;   // 4096 rows
constexpr int NL   = 2;

// ---------------------------------------------------------------------------
// Embedding gather: x[row,:] = emb[ids[row],:]
// ---------------------------------------------------------------------------
__global__ void embed_kernel(const int* __restrict__ ids,
                             const float* __restrict__ emb,
                             float* __restrict__ x) {
    int row = blockIdx.x;              // 0..4095
    int t = threadIdx.x;               // 0..191 (192*4 = 768)
    int id = ids[row];
    const float4* src = (const float4*)(emb + (size_t)id * Hdim);
    float4* dst = (float4*)(x + (size_t)row * Hdim);
    dst[t] = src[t];
}

// ---------------------------------------------------------------------------
// GEMM: Y[m,n] = sum_k X[m,k] * W[n,k] + bias[n]  (+relu) (+resid)
// M=4096, N=768, K=768. Block tile 128x96, BK=16, 256 threads, 8x6 micro.
// ---------------------------------------------------------------------------
constexpr int BM = 128, BN = 96, BK = 16;
constexpr int PX = 132;   // padded LDS stride for X tile (k-major)
constexpr int PW = 100;   // padded LDS stride for W tile

__global__ __launch_bounds__(256) void gemm_kernel(
    const float* __restrict__ Xg, const float* __restrict__ Wg,
    const float* __restrict__ bias, const float* __restrict__ resid,
    float* __restrict__ Y, int relu)
{
    __shared__ float Xs[BK][PX];
    __shared__ float Ws[BK][PW];
    const int tid = threadIdx.x;
    const int tx = tid & 15;     // n micro index (0..15) -> 6 cols each
    const int ty = tid >> 4;     // m micro index (0..15) -> 8 rows each
    const int m0 = blockIdx.x * BM;
    const int n0 = blockIdx.y * BN;
    const int tr = tid >> 2;     // 0..63
    const int tc = tid & 3;      // float4 slot along K

    float acc[8][6];
    #pragma unroll
    for (int i = 0; i < 8; ++i)
        #pragma unroll
        for (int j = 0; j < 6; ++j) acc[i][j] = 0.f;

    for (int k0 = 0; k0 < 768; k0 += BK) {
        // X tile: rows m0..m0+127, cols k0..k0+15 (transpose into k-major LDS)
        {
            const float* xp = Xg + (size_t)(m0 + tr) * Hdim + k0 + tc * 4;
            float4 v0 = *(const float4*)xp;
            float4 v1 = *(const float4*)(xp + (size_t)64 * Hdim);
            Xs[tc*4+0][tr] = v0.x; Xs[tc*4+1][tr] = v0.y;
            Xs[tc*4+2][tr] = v0.z; Xs[tc*4+3][tr] = v0.w;
            Xs[tc*4+0][tr+64] = v1.x; Xs[tc*4+1][tr+64] = v1.y;
            Xs[tc*4+2][tr+64] = v1.z; Xs[tc*4+3][tr+64] = v1.w;
        }
        // W tile: rows n0..n0+95
        {
            const float* wp = Wg + (size_t)(n0 + tr) * Hdim + k0 + tc * 4;
            float4 w0 = *(const float4*)wp;
            Ws[tc*4+0][tr] = w0.x; Ws[tc*4+1][tr] = w0.y;
            Ws[tc*4+2][tr] = w0.z; Ws[tc*4+3][tr] = w0.w;
            if (tid < 128) {
                float4 w1 = *(const float4*)(wp + (size_t)64 * Hdim);
                Ws[tc*4+0][tr+64] = w1.x; Ws[tc*4+1][tr+64] = w1.y;
                Ws[tc*4+2][tr+64] = w1.z; Ws[tc*4+3][tr+64] = w1.w;
            }
        }
        __syncthreads();
        #pragma unroll
        for (int kk = 0; kk < BK; ++kk) {
            float a[8], bv[6];
            *(float4*)&a[0] = *(const float4*)&Xs[kk][ty*8];
            *(float4*)&a[4] = *(const float4*)&Xs[kk][ty*8+4];
            *(float2*)&bv[0] = *(const float2*)&Ws[kk][tx*6];
            *(float2*)&bv[2] = *(const float2*)&Ws[kk][tx*6+2];
            *(float2*)&bv[4] = *(const float2*)&Ws[kk][tx*6+4];
            #pragma unroll
            for (int i = 0; i < 8; ++i)
                #pragma unroll
                for (int j = 0; j < 6; ++j)
                    acc[i][j] = fmaf(a[i], bv[j], acc[i][j]);
        }
        __syncthreads();
    }

    float bcol[6];
    #pragma unroll
    for (int j = 0; j < 6; ++j) bcol[j] = bias[n0 + tx*6 + j];

    #pragma unroll
    for (int i = 0; i < 8; ++i) {
        const int row = m0 + ty*8 + i;
        float* yp = Y + (size_t)row * Hdim + n0 + tx*6;
        const float* rp = resid ? (resid + (size_t)row * Hdim + n0 + tx*6) : nullptr;
        #pragma unroll
        for (int j = 0; j < 6; ++j) {
            float v = acc[i][j] + bcol[j];
            if (relu) v = v > 0.f ? v : 0.f;
            if (rp) v += rp[j];
            yp[j] = v;
        }
    }
}

// ---------------------------------------------------------------------------
// Flash attention (fp32). One wave per block; thread t owns q-row qt*64+t.
// K/V staged in LDS tiles of 64 rows; online softmax in registers.
// ---------------------------------------------------------------------------
__global__ __launch_bounds__(64) void attn_kernel(
    const float* __restrict__ Q, const float* __restrict__ K,
    const float* __restrict__ V, float* __restrict__ O)
{
    __shared__ float Ks[64][68];
    __shared__ float Vs[64][68];
    const int t = threadIdx.x;        // 0..63
    const int qt = blockIdx.x;        // 0..15
    const int h  = blockIdx.y;        // 0..11
    const int b  = blockIdx.z;        // 0..3
    const int s  = qt * 64 + t;

    const float* qp = Q + ((size_t)(b * Ss + s) * Hdim + h * HD);
    float4 q[16];
    #pragma unroll
    for (int i = 0; i < 16; ++i) {
        float4 v = ((const float4*)qp)[i];
        v.x *= 0.125f; v.y *= 0.125f; v.z *= 0.125f; v.w *= 0.125f;  // 1/sqrt(64)
        q[i] = v;
    }
    float4 o[16];
    #pragma unroll
    for (int i = 0; i < 16; ++i) o[i] = make_float4(0.f, 0.f, 0.f, 0.f);
    float mval = -1e30f, lval = 0.f;

    const float* kbase = K + ((size_t)(b * Ss) * Hdim + h * HD);
    const float* vbase = V + ((size_t)(b * Ss) * Hdim + h * HD);
    const int c4 = (t & 15) * 4;
    const int r0 = t >> 4;

    for (int jt = 0; jt < 16; ++jt) {
        __syncthreads();
        #pragma unroll
        for (int r = 0; r < 16; ++r) {
            int row = r * 4 + r0;
            const float* kp = kbase + (size_t)(jt * 64 + row) * Hdim + c4;
            const float* vp = vbase + (size_t)(jt * 64 + row) * Hdim + c4;
            *(float4*)&Ks[row][c4] = *(const float4*)kp;
            *(float4*)&Vs[row][c4] = *(const float4*)vp;
        }
        __syncthreads();
        for (int j = 0; j < 64; ++j) {
            const float4* kr = (const float4*)&Ks[j][0];
            float sc = 0.f;
            #pragma unroll
            for (int i = 0; i < 16; ++i) {
                float4 kv = kr[i];
                sc = fmaf(q[i].x, kv.x, sc);
                sc = fmaf(q[i].y, kv.y, sc);
                sc = fmaf(q[i].z, kv.z, sc);
                sc = fmaf(q[i].w, kv.w, sc);
            }
            if (sc > mval) {
                float corr = __expf(mval - sc);
                mval = sc;
                lval *= corr;
                #pragma unroll
                for (int i = 0; i < 16; ++i) {
                    o[i].x *= corr; o[i].y *= corr; o[i].z *= corr; o[i].w *= corr;
                }
            }
            float p = __expf(sc - mval);
            lval += p;
            const float4* vr = (const float4*)&Vs[j][0];
            #pragma unroll
            for (int i = 0; i < 16; ++i) {
                float4 vv = vr[i];
                o[i].x = fmaf(p, vv.x, o[i].x);
                o[i].y = fmaf(p, vv.y, o[i].y);
                o[i].z = fmaf(p, vv.z, o[i].z);
                o[i].w = fmaf(p, vv.w, o[i].w);
            }
        }
    }
    float inv = 1.f / lval;
    float* op = O + ((size_t)(b * Ss + s) * Hdim + h * HD);
    #pragma unroll
    for (int i = 0; i < 16; ++i) {
        float4 v = o[i];
        v.x *= inv; v.y *= inv; v.z *= inv; v.w *= inv;
        ((float4*)op)[i] = v;
    }
}

// ---------------------------------------------------------------------------
// Classifier: logits[b,n] = dot(x[b,0,:], Wc[n,:]) + bc[n]
// ---------------------------------------------------------------------------
__global__ void cls_kernel(const float* __restrict__ x,
                           const float* __restrict__ Wc,
                           const float* __restrict__ bc,
                           float* __restrict__ out) {
    const int b = blockIdx.x >> 1;
    const int n = blockIdx.x & 1;
    const int t = threadIdx.x;
    const float* px = x + (size_t)b * Ss * Hdim;   // row s=0
    const float* pw = Wc + (size_t)n * Hdim;
    float partial = 0.f;
    for (int k = t; k < Hdim; k += 256) partial = fmaf(px[k], pw[k], partial);
    __shared__ float red[256];
    red[t] = partial;
    __syncthreads();
    for (int off = 128; off > 0; off >>= 1) {
        if (t < off) red[t] += red[t + off];
        __syncthreads();
    }
    if (t == 0) out[blockIdx.x] = red[0] + bc[n];
}

// ---------------------------------------------------------------------------
extern "C" void kernel_launch(void* const* d_in, const int* in_sizes, int n_in,
                              void* d_out, int out_size, void* d_ws, size_t ws_size,
                              hipStream_t stream) {
    const int*   ids = (const int*)d_in[0];
    const float* emb = (const float*)d_in[1];
    const float* Wq  = (const float*)d_in[2];
    const float* bq  = (const float*)d_in[3];
    const float* Wk  = (const float*)d_in[4];
    const float* bk  = (const float*)d_in[5];
    const float* Wv  = (const float*)d_in[6];
    const float* bv  = (const float*)d_in[7];
    const float* Wi  = (const float*)d_in[8];
    const float* bi  = (const float*)d_in[9];
    const float* Wo  = (const float*)d_in[10];
    const float* bo  = (const float*)d_in[11];
    const float* Wc  = (const float*)d_in[12];
    const float* bc  = (const float*)d_in[13];
    float* out = (float*)d_out;

    const size_t bufElems = (size_t)Mm * Hdim;   // 3,145,728 floats = 12.6 MB
    float* hbuf = (float*)d_ws;
    float* qb   = hbuf + bufElems;
    float* kb   = qb + bufElems;
    float* vb   = kb + bufElems;
    float* ab   = vb + bufElems;   // attention output; inter reuses qb

    embed_kernel<<<Mm, 192, 0, stream>>>(ids, emb, hbuf);

    dim3 ggrid(Mm / BM, Hdim / BN);   // 32 x 8 = 256 blocks
    for (int l = 0; l < NLAYER; ++l) {
        const float* wq = Wq + (size_t)l * Hdim * Hdim;
        const float* wk = Wk + (size_t)l * Hdim * Hdim;
        const float* wv = Wv + (size_t)l * Hdim * Hdim;
        const float* wi = Wi + (size_t)l * Hdim * Hdim;
        const float* wo = Wo + (size_t)l * Hdim * Hdim;

        gemm_kernel<<<ggrid, 256, 0, stream>>>(hbuf, wq, bq + l * Hdim, nullptr, qb, 0);
        gemm_kernel<<<ggrid, 256, 0, stream>>>(hbuf, wk, bk + l * Hdim, nullptr, kb, 0);
        gemm_kernel<<<ggrid, 256, 0, stream>>>(hbuf, wv, bv + l * Hdim, nullptr, vb, 0);
        attn_kernel<<<dim3(Ss / 64, NH, Bb), 64, 0, stream>>>(qb, kb, vb, ab);
        gemm_kernel<<<ggrid, 256, 0, stream>>>(ab, wi, bi + l * Hdim, nullptr, qb, 1);
        gemm_kernel<<<ggrid, 256, 0, stream>>>(qb, wo, bo + l * Hdim, ab, hbuf, 0);
    }

    cls_kernel<<<Bb * NL, 256, 0, stream>>>(hbuf, Wc, bc, out);
}

// Round 2
// 3265.252 us; speedup vs baseline: 1.4850x; 1.4850x over previous
//
#include <hip/hip_runtime.h>
#include <hip/hip_bf16.h>
#include <math.h>

// Problem constants
constexpr int Hdim = 768;
constexpr int NH   = 12;
constexpr int HD   = 64;
constexpr int NLAYER = 4;
constexpr int Bb   = 4;
constexpr int Ss   = 1024;
constexpr int Mm   = Bb * Ss;   // 4096 rows
constexpr int NL   = 2;

// ---------------------------------------------------------------------------
// Embedding gather: x[row,:] = emb[ids[row],:]
// ---------------------------------------------------------------------------
__global__ void embed_kernel(const int* __restrict__ ids,
                             const float* __restrict__ emb,
                             float* __restrict__ x) {
    int row = blockIdx.x;              // 0..4095
    int t = threadIdx.x;               // 0..191 (192*4 = 768)
    int id = ids[row];
    const float4* src = (const float4*)(emb + (size_t)id * Hdim);
    float4* dst = (float4*)(x + (size_t)row * Hdim);
    dst[t] = src[t];
}

// ---------------------------------------------------------------------------
// GEMM: Y[m,n] = sum_k X[m,k] * W[n,k] + bias[n]  (+relu) (+resid)
// M=4096, N=768, K=768. Block tile 128x96, BK=16, 256 threads, 8x6 micro.
// ---------------------------------------------------------------------------
constexpr int BM = 128, BN = 96, BK = 16;
constexpr int PX = 132;   // padded LDS stride for X tile (k-major)
constexpr int PW = 100;   // padded LDS stride for W tile

__global__ __launch_bounds__(256) void gemm_kernel(
    const float* __restrict__ Xg, const float* __restrict__ Wg,
    const float* __restrict__ bias, const float* __restrict__ resid,
    float* __restrict__ Y, int relu)
{
    __shared__ float Xs[BK][PX];
    __shared__ float Ws[BK][PW];
    const int tid = threadIdx.x;
    const int tx = tid & 15;     // n micro index (0..15) -> 6 cols each
    const int ty = tid >> 4;     // m micro index (0..15) -> 8 rows each
    const int m0 = blockIdx.x * BM;
    const int n0 = blockIdx.y * BN;
    const int tr = tid >> 2;     // 0..63
    const int tc = tid & 3;      // float4 slot along K

    float acc[8][6];
    #pragma unroll
    for (int i = 0; i < 8; ++i)
        #pragma unroll
        for (int j = 0; j < 6; ++j) acc[i][j] = 0.f;

    for (int k0 = 0; k0 < 768; k0 += BK) {
        {
            const float* xp = Xg + (size_t)(m0 + tr) * Hdim + k0 + tc * 4;
            float4 v0 = *(const float4*)xp;
            float4 v1 = *(const float4*)(xp + (size_t)64 * Hdim);
            Xs[tc*4+0][tr] = v0.x; Xs[tc*4+1][tr] = v0.y;
            Xs[tc*4+2][tr] = v0.z; Xs[tc*4+3][tr] = v0.w;
            Xs[tc*4+0][tr+64] = v1.x; Xs[tc*4+1][tr+64] = v1.y;
            Xs[tc*4+2][tr+64] = v1.z; Xs[tc*4+3][tr+64] = v1.w;
        }
        {
            const float* wp = Wg + (size_t)(n0 + tr) * Hdim + k0 + tc * 4;
            float4 w0 = *(const float4*)wp;
            Ws[tc*4+0][tr] = w0.x; Ws[tc*4+1][tr] = w0.y;
            Ws[tc*4+2][tr] = w0.z; Ws[tc*4+3][tr] = w0.w;
            if (tid < 128) {
                float4 w1 = *(const float4*)(wp + (size_t)64 * Hdim);
                Ws[tc*4+0][tr+64] = w1.x; Ws[tc*4+1][tr+64] = w1.y;
                Ws[tc*4+2][tr+64] = w1.z; Ws[tc*4+3][tr+64] = w1.w;
            }
        }
        __syncthreads();
        #pragma unroll
        for (int kk = 0; kk < BK; ++kk) {
            float a[8], bv[6];
            *(float4*)&a[0] = *(const float4*)&Xs[kk][ty*8];
            *(float4*)&a[4] = *(const float4*)&Xs[kk][ty*8+4];
            *(float2*)&bv[0] = *(const float2*)&Ws[kk][tx*6];
            *(float2*)&bv[2] = *(const float2*)&Ws[kk][tx*6+2];
            *(float2*)&bv[4] = *(const float2*)&Ws[kk][tx*6+4];
            #pragma unroll
            for (int i = 0; i < 8; ++i)
                #pragma unroll
                for (int j = 0; j < 6; ++j)
                    acc[i][j] = fmaf(a[i], bv[j], acc[i][j]);
        }
        __syncthreads();
    }

    float bcol[6];
    #pragma unroll
    for (int j = 0; j < 6; ++j) bcol[j] = bias[n0 + tx*6 + j];

    #pragma unroll
    for (int i = 0; i < 8; ++i) {
        const int row = m0 + ty*8 + i;
        float* yp = Y + (size_t)row * Hdim + n0 + tx*6;
        const float* rp = resid ? (resid + (size_t)row * Hdim + n0 + tx*6) : nullptr;
        #pragma unroll
        for (int j = 0; j < 6; ++j) {
            float v = acc[i][j] + bcol[j];
            if (relu) v = v > 0.f ? v : 0.f;
            if (rp) v += rp[j];
            yp[j] = v;
        }
    }
}

// ---------------------------------------------------------------------------
// Flash attention (fp32), KV-split 4 ways within a 256-thread block.
// Wave w handles KV rows [256w, 256w+256) in 16-row tiles staged in its own
// LDS region; lane owns one q-row (online softmax in registers, deferred
// per-8-row max). Partial (m,l,o) merged across the 4 waves through LDS.
// ---------------------------------------------------------------------------
__global__ __launch_bounds__(256) void attn_kernel(
    const float* __restrict__ Q, const float* __restrict__ K,
    const float* __restrict__ V, float* __restrict__ O)
{
    __shared__ float KVs[2][4][16][68];          // [K/V][wave][row][col pad] = 34816 B
    __shared__ float Ml[4][64], Ll[4][64];       // per-wave m,l per q-row
    __shared__ float Linv[64];

    const int tid  = threadIdx.x;
    const int lane = tid & 63;
    const int w    = tid >> 6;                   // KV chunk 0..3
    const int qt = blockIdx.x;                   // 0..15
    const int h  = blockIdx.y;                   // 0..11
    const int b  = blockIdx.z;                   // 0..3
    const int qrow = qt * 64 + lane;

    // Load q row (scaled by 1/sqrt(64)); same rows in all 4 waves.
    const float* qp = Q + ((size_t)(b * Ss + qrow) * Hdim + h * HD);
    float4 q[16];
    #pragma unroll
    for (int i = 0; i < 16; ++i) {
        float4 v = ((const float4*)qp)[i];
        v.x *= 0.125f; v.y *= 0.125f; v.z *= 0.125f; v.w *= 0.125f;
        q[i] = v;
    }
    float4 o[16];
    #pragma unroll
    for (int i = 0; i < 16; ++i) o[i] = make_float4(0.f, 0.f, 0.f, 0.f);
    float mval = -1e30f, lval = 0.f;

    const float* kbase = K + ((size_t)(b * Ss + w * 256) * Hdim + h * HD);
    const float* vbase = V + ((size_t)(b * Ss + w * 256) * Hdim + h * HD);
    const int srow = lane >> 4;          // 0..3
    const int scol = (lane & 15) * 4;    // 0..60

    float (*Ks)[68] = KVs[0][w];
    float (*Vs)[68] = KVs[1][w];

    for (int tile = 0; tile < 16; ++tile) {
        const float* kp = kbase + (size_t)(tile * 16 + srow) * Hdim + scol;
        const float* vp = vbase + (size_t)(tile * 16 + srow) * Hdim + scol;
        __syncthreads();   // previous tile's reads done before overwrite
        #pragma unroll
        for (int r = 0; r < 4; ++r) {
            *(float4*)&Ks[srow + r*4][scol] = *(const float4*)(kp + (size_t)(r*4) * Hdim);
            *(float4*)&Vs[srow + r*4][scol] = *(const float4*)(vp + (size_t)(r*4) * Hdim);
        }
        __syncthreads();
        #pragma unroll
        for (int half = 0; half < 2; ++half) {
            float s[8];
            #pragma unroll
            for (int j = 0; j < 8; ++j) {
                const float4* kr = (const float4*)&Ks[half*8 + j][0];
                float sc = 0.f;
                #pragma unroll
                for (int i = 0; i < 16; ++i) {
                    float4 kv = kr[i];
                    sc = fmaf(q[i].x, kv.x, sc);
                    sc = fmaf(q[i].y, kv.y, sc);
                    sc = fmaf(q[i].z, kv.z, sc);
                    sc = fmaf(q[i].w, kv.w, sc);
                }
                s[j] = sc;
            }
            float tmax = s[0];
            #pragma unroll
            for (int j = 1; j < 8; ++j) tmax = fmaxf(tmax, s[j]);
            if (tmax > mval) {
                float corr = __expf(mval - tmax);
                mval = tmax;
                lval *= corr;
                #pragma unroll
                for (int i = 0; i < 16; ++i) {
                    o[i].x *= corr; o[i].y *= corr; o[i].z *= corr; o[i].w *= corr;
                }
            }
            #pragma unroll
            for (int j = 0; j < 8; ++j) {
                float p = __expf(s[j] - mval);
                lval += p;
                const float4* vr = (const float4*)&Vs[half*8 + j][0];
                #pragma unroll
                for (int i = 0; i < 16; ++i) {
                    float4 vv = vr[i];
                    o[i].x = fmaf(p, vv.x, o[i].x);
                    o[i].y = fmaf(p, vv.y, o[i].y);
                    o[i].z = fmaf(p, vv.z, o[i].z);
                    o[i].w = fmaf(p, vv.w, o[i].w);
                }
            }
        }
    }

    // ---- merge the 4 per-wave partials -----------------------------------
    Ml[w][lane] = mval;
    Ll[w][lane] = lval;
    __syncthreads();
    float M = fmaxf(fmaxf(Ml[0][lane], Ml[1][lane]), fmaxf(Ml[2][lane], Ml[3][lane]));
    float Ls = 0.f;
    #pragma unroll
    for (int ww = 0; ww < 4; ++ww) Ls += Ll[ww][lane] * __expf(Ml[ww][lane] - M);
    float myscale = __expf(mval - M);
    #pragma unroll
    for (int i = 0; i < 16; ++i) {
        o[i].x *= myscale; o[i].y *= myscale; o[i].z *= myscale; o[i].w *= myscale;
    }

    // obuf[64][69] overlays the KV staging region (4416 <= 8704 floats).
    float* obuf = &KVs[0][0][0][0];
    for (int ww = 0; ww < 4; ++ww) {
        if (w == ww) {
            float* orow = obuf + lane * 69;
            if (ww == 0) {
                #pragma unroll
                for (int i = 0; i < 16; ++i) {
                    orow[i*4+0] = o[i].x; orow[i*4+1] = o[i].y;
                    orow[i*4+2] = o[i].z; orow[i*4+3] = o[i].w;
                }
                Linv[lane] = 1.f / Ls;
            } else {
                #pragma unroll
                for (int i = 0; i < 16; ++i) {
                    orow[i*4+0] += o[i].x; orow[i*4+1] += o[i].y;
                    orow[i*4+2] += o[i].z; orow[i*4+3] += o[i].w;
                }
            }
        }
        __syncthreads();
    }

    // ---- write output: thread t -> row t>>2, 16 cols starting (t&3)*16 ----
    const int r  = tid >> 2;
    const int c0 = (tid & 3) * 16;
    const float inv = Linv[r];
    float* op = O + ((size_t)(b * Ss + qt * 64 + r) * Hdim + h * HD + c0);
    #pragma unroll
    for (int i = 0; i < 4; ++i) {
        float4 vv;
        vv.x = obuf[r*69 + c0 + i*4 + 0] * inv;
        vv.y = obuf[r*69 + c0 + i*4 + 1] * inv;
        vv.z = obuf[r*69 + c0 + i*4 + 2] * inv;
        vv.w = obuf[r*69 + c0 + i*4 + 3] * inv;
        ((float4*)op)[i] = vv;
    }
}

// ---------------------------------------------------------------------------
// Classifier: logits[b,n] = dot(x[b,0,:], Wc[n,:]) + bc[n]
// ---------------------------------------------------------------------------
__global__ void cls_kernel(const float* __restrict__ x,
                           const float* __restrict__ Wc,
                           const float* __restrict__ bc,
                           float* __restrict__ out) {
    const int b = blockIdx.x >> 1;
    const int n = blockIdx.x & 1;
    const int t = threadIdx.x;
    const float* px = x + (size_t)b * Ss * Hdim;   // row s=0
    const float* pw = Wc + (size_t)n * Hdim;
    float partial = 0.f;
    for (int k = t; k < Hdim; k += 256) partial = fmaf(px[k], pw[k], partial);
    __shared__ float red[256];
    red[t] = partial;
    __syncthreads();
    for (int off = 128; off > 0; off >>= 1) {
        if (t < off) red[t] += red[t + off];
        __syncthreads();
    }
    if (t == 0) out[blockIdx.x] = red[0] + bc[n];
}

// ---------------------------------------------------------------------------
extern "C" void kernel_launch(void* const* d_in, const int* in_sizes, int n_in,
                              void* d_out, int out_size, void* d_ws, size_t ws_size,
                              hipStream_t stream) {
    const int*   ids = (const int*)d_in[0];
    const float* emb = (const float*)d_in[1];
    const float* Wq  = (const float*)d_in[2];
    const float* bq  = (const float*)d_in[3];
    const float* Wk  = (const float*)d_in[4];
    const float* bk  = (const float*)d_in[5];
    const float* Wv  = (const float*)d_in[6];
    const float* bv  = (const float*)d_in[7];
    const float* Wi  = (const float*)d_in[8];
    const float* bi  = (const float*)d_in[9];
    const float* Wo  = (const float*)d_in[10];
    const float* bo  = (const float*)d_in[11];
    const float* Wc  = (const float*)d_in[12];
    const float* bc  = (const float*)d_in[13];
    float* out = (float*)d_out;

    const size_t bufElems = (size_t)Mm * Hdim;   // 3,145,728 floats = 12.6 MB
    float* hbuf = (float*)d_ws;
    float* qb   = hbuf + bufElems;
    float* kb   = qb + bufElems;
    float* vb   = kb + bufElems;
    float* ab   = vb + bufElems;   // attention output; inter reuses qb

    embed_kernel<<<Mm, 192, 0, stream>>>(ids, emb, hbuf);

    dim3 ggrid(Mm / BM, Hdim / BN);   // 32 x 8 = 256 blocks
    for (int l = 0; l < NLAYER; ++l) {
        const float* wq = Wq + (size_t)l * Hdim * Hdim;
        const float* wk = Wk + (size_t)l * Hdim * Hdim;
        const float* wv = Wv + (size_t)l * Hdim * Hdim;
        const float* wi = Wi + (size_t)l * Hdim * Hdim;
        const float* wo = Wo + (size_t)l * Hdim * Hdim;

        gemm_kernel<<<ggrid, 256, 0, stream>>>(hbuf, wq, bq + l * Hdim, nullptr, qb, 0);
        gemm_kernel<<<ggrid, 256, 0, stream>>>(hbuf, wk, bk + l * Hdim, nullptr, kb, 0);
        gemm_kernel<<<ggrid, 256, 0, stream>>>(hbuf, wv, bv + l * Hdim, nullptr, vb, 0);
        attn_kernel<<<dim3(Ss / 64, NH, Bb), 256, 0, stream>>>(qb, kb, vb, ab);
        gemm_kernel<<<ggrid, 256, 0, stream>>>(ab, wi, bi + l * Hdim, nullptr, qb, 1);
        gemm_kernel<<<ggrid, 256, 0, stream>>>(qb, wo, bo + l * Hdim, ab, hbuf, 0);
    }

    cls_kernel<<<Bb * NL, 256, 0, stream>>>(hbuf, Wc, bc, out);
}

// Round 3
// 1991.352 us; speedup vs baseline: 2.4350x; 1.6397x over previous
//
#include <hip/hip_runtime.h>
#include <hip/hip_bf16.h>
#include <math.h>

// Problem constants
constexpr int Hdim = 768;
constexpr int NH   = 12;
constexpr int HD   = 64;
constexpr int NLAYER = 4;
constexpr int Bb   = 4;
constexpr int Ss   = 1024;
constexpr int Mm   = Bb * Ss;   // 4096 rows
constexpr int NL   = 2;

typedef short  bf16x8 __attribute__((ext_vector_type(8)));
typedef float  f32x4  __attribute__((ext_vector_type(4)));

__device__ __forceinline__ ushort f2bf(float f) {
    uint u = __float_as_uint(f);
    u += 0x7FFF + ((u >> 16) & 1);          // round-to-nearest-even
    return (ushort)(u >> 16);
}
__device__ __forceinline__ float bf2f(ushort h) {
    return __uint_as_float(((uint)h) << 16);
}

// ---------------------------------------------------------------------------
// Embedding gather: x[row,:] = emb[ids[row],:], plus bf16 hi/lo split copies.
// ---------------------------------------------------------------------------
__global__ void embed_kernel(const int* __restrict__ ids,
                             const float* __restrict__ emb,
                             float* __restrict__ x,
                             ushort* __restrict__ xh, ushort* __restrict__ xl) {
    int row = blockIdx.x;              // 0..4095
    int t = threadIdx.x;               // 0..191
    int id = ids[row];
    float4 v = ((const float4*)(emb + (size_t)id * Hdim))[t];
    ((float4*)(x + (size_t)row * Hdim))[t] = v;
    ushort4 h, l;
    h.x = f2bf(v.x); l.x = f2bf(v.x - bf2f(h.x));
    h.y = f2bf(v.y); l.y = f2bf(v.y - bf2f(h.y));
    h.z = f2bf(v.z); l.z = f2bf(v.z - bf2f(h.z));
    h.w = f2bf(v.w); l.w = f2bf(v.w - bf2f(h.w));
    *(ushort4*)(xh + (size_t)row * Hdim + t * 4) = h;
    *(ushort4*)(xl + (size_t)row * Hdim + t * 4) = l;
}

// ---------------------------------------------------------------------------
// Split one layer's five weight matrices (768x768 each) into bf16 hi/lo.
// Grid: 5 * 147456 quads / 256 = 2880 blocks.
// ---------------------------------------------------------------------------
__global__ void split5_kernel(const float* __restrict__ w0, const float* __restrict__ w1,
                              const float* __restrict__ w2, const float* __restrict__ w3,
                              const float* __restrict__ w4,
                              ushort* __restrict__ hi, ushort* __restrict__ lo) {
    int i = blockIdx.x * 256 + threadIdx.x;   // quad index, 0..737279
    int which = i / 147456;
    int j = i - which * 147456;
    const float* src = which == 0 ? w0 : which == 1 ? w1 : which == 2 ? w2
                     : which == 3 ? w3 : w4;
    float4 v = ((const float4*)src)[j];
    ushort4 h, l;
    h.x = f2bf(v.x); l.x = f2bf(v.x - bf2f(h.x));
    h.y = f2bf(v.y); l.y = f2bf(v.y - bf2f(h.y));
    h.z = f2bf(v.z); l.z = f2bf(v.z - bf2f(h.z));
    h.w = f2bf(v.w); l.w = f2bf(v.w - bf2f(h.w));
    size_t o = (size_t)which * 589824 + (size_t)j * 4;
    *(ushort4*)(hi + o) = h;
    *(ushort4*)(lo + o) = l;
}

// ---------------------------------------------------------------------------
// Split-bf16 MFMA GEMM: Y[m,n] = sum_k X[m,k]*W[n,k] (+bias, +relu, +resid).
// X,W supplied as bf16 hi/lo pairs; product via Ahi*Bhi + Ahi*Blo + Alo*Bhi.
// Block tile 64x96, BK=32, 256 threads = 4 waves, wave tile 32x48 (2x3 frags
// of 16x16x32). Grid (4096/64=64, 768/96=8) = 512 blocks.
// ---------------------------------------------------------------------------
constexpr int TM = 64, TN = 96, TK = 32, LSTR = 40;  // LDS row stride (bf16)

__global__ __launch_bounds__(256) void gemm_mfma(
    const ushort* __restrict__ Xhi, const ushort* __restrict__ Xlo,
    const ushort* __restrict__ Whi, const ushort* __restrict__ Wlo,
    const float* __restrict__ bias, const float* __restrict__ resid,
    float* __restrict__ Yf, ushort* __restrict__ Yhi, ushort* __restrict__ Ylo,
    int relu)
{
    __shared__ ushort Xs[2][TM * LSTR];   // [hi/lo][64*40]  = 10240 B
    __shared__ ushort Ws[2][TN * LSTR];   // [hi/lo][96*40]  = 15360 B

    const int tid  = threadIdx.x;
    const int m0   = blockIdx.x * TM;
    const int n0   = blockIdx.y * TN;
    const int lane = tid & 63, wid = tid >> 6;
    const int wr = wid >> 1, wc = wid & 1;          // wave grid 2(M) x 2(N)
    const int l15 = lane & 15, lk = (lane >> 4) * 8;

    const int srow = tid >> 2;          // staging row 0..63
    const int sseg = (tid & 3) * 8;     // staging col segment (bf16 units)

    f32x4 acc[2][3];
    #pragma unroll
    for (int m = 0; m < 2; ++m)
        #pragma unroll
        for (int n = 0; n < 3; ++n) acc[m][n] = (f32x4){0.f, 0.f, 0.f, 0.f};

    for (int k0 = 0; k0 < Hdim; k0 += TK) {
        __syncthreads();
        {   // X tile: 64 rows x 32 cols, hi+lo
            const size_t g = (size_t)(m0 + srow) * Hdim + k0 + sseg;
            *(uint4*)&Xs[0][srow * LSTR + sseg] = *(const uint4*)(Xhi + g);
            *(uint4*)&Xs[1][srow * LSTR + sseg] = *(const uint4*)(Xlo + g);
        }
        {   // W tile: 96 rows x 32 cols, hi+lo
            const size_t g = (size_t)(n0 + srow) * Hdim + k0 + sseg;
            *(uint4*)&Ws[0][srow * LSTR + sseg] = *(const uint4*)(Whi + g);
            *(uint4*)&Ws[1][srow * LSTR + sseg] = *(const uint4*)(Wlo + g);
            if (tid < 128) {
                const int r2 = srow + 64;
                const size_t g2 = (size_t)(n0 + r2) * Hdim + k0 + sseg;
                *(uint4*)&Ws[0][r2 * LSTR + sseg] = *(const uint4*)(Whi + g2);
                *(uint4*)&Ws[1][r2 * LSTR + sseg] = *(const uint4*)(Wlo + g2);
            }
        }
        __syncthreads();

        bf16x8 ah[2], al[2], bh[3], bl[3];
        #pragma unroll
        for (int m = 0; m < 2; ++m) {
            const int r = wr * 32 + m * 16 + l15;
            ah[m] = *(const bf16x8*)&Xs[0][r * LSTR + lk];
            al[m] = *(const bf16x8*)&Xs[1][r * LSTR + lk];
        }
        #pragma unroll
        for (int n = 0; n < 3; ++n) {
            const int r = wc * 48 + n * 16 + l15;
            bh[n] = *(const bf16x8*)&Ws[0][r * LSTR + lk];
            bl[n] = *(const bf16x8*)&Ws[1][r * LSTR + lk];
        }
        #pragma unroll
        for (int m = 0; m < 2; ++m)
            #pragma unroll
            for (int n = 0; n < 3; ++n) {
                acc[m][n] = __builtin_amdgcn_mfma_f32_16x16x32_bf16(ah[m], bh[n], acc[m][n], 0, 0, 0);
                acc[m][n] = __builtin_amdgcn_mfma_f32_16x16x32_bf16(ah[m], bl[n], acc[m][n], 0, 0, 0);
                acc[m][n] = __builtin_amdgcn_mfma_f32_16x16x32_bf16(al[m], bh[n], acc[m][n], 0, 0, 0);
            }
    }

    // Epilogue. D layout: col = lane&15, row = (lane>>4)*4 + reg.
    const int rbase = m0 + wr * 32 + (lane >> 4) * 4;
    #pragma unroll
    for (int n = 0; n < 3; ++n) {
        const int col = n0 + wc * 48 + n * 16 + l15;
        const float bc_ = bias[col];
        #pragma unroll
        for (int m = 0; m < 2; ++m) {
            #pragma unroll
            for (int r = 0; r < 4; ++r) {
                const int row = rbase + m * 16 + r;
                const size_t idx = (size_t)row * Hdim + col;
                float v = acc[m][n][r] + bc_;
                if (relu) v = v > 0.f ? v : 0.f;
                if (resid) v += resid[idx];
                if (Yf) Yf[idx] = v;
                if (Yhi) {
                    const ushort h = f2bf(v);
                    Yhi[idx] = h;
                    Ylo[idx] = f2bf(v - bf2f(h));
                }
            }
        }
    }
}

// ---------------------------------------------------------------------------
// Flash attention (fp32), KV-split 4 ways within a 256-thread block.
// Epilogue also emits bf16 hi/lo split of O (feeds the Wi GEMM).
// ---------------------------------------------------------------------------
__global__ __launch_bounds__(256) void attn_kernel(
    const float* __restrict__ Q, const float* __restrict__ K,
    const float* __restrict__ V, float* __restrict__ O,
    ushort* __restrict__ Ohi, ushort* __restrict__ Olo)
{
    __shared__ float KVs[2][4][16][68];
    __shared__ float Ml[4][64], Ll[4][64];
    __shared__ float Linv[64];

    const int tid  = threadIdx.x;
    const int lane = tid & 63;
    const int w    = tid >> 6;
    const int qt = blockIdx.x;
    const int h  = blockIdx.y;
    const int b  = blockIdx.z;
    const int qrow = qt * 64 + lane;

    const float* qp = Q + ((size_t)(b * Ss + qrow) * Hdim + h * HD);
    float4 q[16];
    #pragma unroll
    for (int i = 0; i < 16; ++i) {
        float4 v = ((const float4*)qp)[i];
        v.x *= 0.125f; v.y *= 0.125f; v.z *= 0.125f; v.w *= 0.125f;
        q[i] = v;
    }
    float4 o[16];
    #pragma unroll
    for (int i = 0; i < 16; ++i) o[i] = make_float4(0.f, 0.f, 0.f, 0.f);
    float mval = -1e30f, lval = 0.f;

    const float* kbase = K + ((size_t)(b * Ss + w * 256) * Hdim + h * HD);
    const float* vbase = V + ((size_t)(b * Ss + w * 256) * Hdim + h * HD);
    const int srow = lane >> 4;
    const int scol = (lane & 15) * 4;

    float (*Ks)[68] = KVs[0][w];
    float (*Vs)[68] = KVs[1][w];

    for (int tile = 0; tile < 16; ++tile) {
        const float* kp = kbase + (size_t)(tile * 16 + srow) * Hdim + scol;
        const float* vp = vbase + (size_t)(tile * 16 + srow) * Hdim + scol;
        __syncthreads();
        #pragma unroll
        for (int r = 0; r < 4; ++r) {
            *(float4*)&Ks[srow + r*4][scol] = *(const float4*)(kp + (size_t)(r*4) * Hdim);
            *(float4*)&Vs[srow + r*4][scol] = *(const float4*)(vp + (size_t)(r*4) * Hdim);
        }
        __syncthreads();
        #pragma unroll
        for (int half = 0; half < 2; ++half) {
            float s[8];
            #pragma unroll
            for (int j = 0; j < 8; ++j) {
                const float4* kr = (const float4*)&Ks[half*8 + j][0];
                float sc = 0.f;
                #pragma unroll
                for (int i = 0; i < 16; ++i) {
                    float4 kv = kr[i];
                    sc = fmaf(q[i].x, kv.x, sc);
                    sc = fmaf(q[i].y, kv.y, sc);
                    sc = fmaf(q[i].z, kv.z, sc);
                    sc = fmaf(q[i].w, kv.w, sc);
                }
                s[j] = sc;
            }
            float tmax = s[0];
            #pragma unroll
            for (int j = 1; j < 8; ++j) tmax = fmaxf(tmax, s[j]);
            if (tmax > mval) {
                float corr = __expf(mval - tmax);
                mval = tmax;
                lval *= corr;
                #pragma unroll
                for (int i = 0; i < 16; ++i) {
                    o[i].x *= corr; o[i].y *= corr; o[i].z *= corr; o[i].w *= corr;
                }
            }
            #pragma unroll
            for (int j = 0; j < 8; ++j) {
                float p = __expf(s[j] - mval);
                lval += p;
                const float4* vr = (const float4*)&Vs[half*8 + j][0];
                #pragma unroll
                for (int i = 0; i < 16; ++i) {
                    float4 vv = vr[i];
                    o[i].x = fmaf(p, vv.x, o[i].x);
                    o[i].y = fmaf(p, vv.y, o[i].y);
                    o[i].z = fmaf(p, vv.z, o[i].z);
                    o[i].w = fmaf(p, vv.w, o[i].w);
                }
            }
        }
    }

    Ml[w][lane] = mval;
    Ll[w][lane] = lval;
    __syncthreads();
    float M = fmaxf(fmaxf(Ml[0][lane], Ml[1][lane]), fmaxf(Ml[2][lane], Ml[3][lane]));
    float Ls = 0.f;
    #pragma unroll
    for (int ww = 0; ww < 4; ++ww) Ls += Ll[ww][lane] * __expf(Ml[ww][lane] - M);
    float myscale = __expf(mval - M);
    #pragma unroll
    for (int i = 0; i < 16; ++i) {
        o[i].x *= myscale; o[i].y *= myscale; o[i].z *= myscale; o[i].w *= myscale;
    }

    float* obuf = &KVs[0][0][0][0];
    for (int ww = 0; ww < 4; ++ww) {
        if (w == ww) {
            float* orow = obuf + lane * 69;
            if (ww == 0) {
                #pragma unroll
                for (int i = 0; i < 16; ++i) {
                    orow[i*4+0] = o[i].x; orow[i*4+1] = o[i].y;
                    orow[i*4+2] = o[i].z; orow[i*4+3] = o[i].w;
                }
                Linv[lane] = 1.f / Ls;
            } else {
                #pragma unroll
                for (int i = 0; i < 16; ++i) {
                    orow[i*4+0] += o[i].x; orow[i*4+1] += o[i].y;
                    orow[i*4+2] += o[i].z; orow[i*4+3] += o[i].w;
                }
            }
        }
        __syncthreads();
    }

    const int r  = tid >> 2;
    const int c0 = (tid & 3) * 16;
    const float inv = Linv[r];
    const size_t bidx = (size_t)(b * Ss + qt * 64 + r) * Hdim + h * HD + c0;
    #pragma unroll
    for (int i = 0; i < 4; ++i) {
        float4 vv;
        vv.x = obuf[r*69 + c0 + i*4 + 0] * inv;
        vv.y = obuf[r*69 + c0 + i*4 + 1] * inv;
        vv.z = obuf[r*69 + c0 + i*4 + 2] * inv;
        vv.w = obuf[r*69 + c0 + i*4 + 3] * inv;
        ((float4*)(O + bidx))[i] = vv;
        ushort4 hh, ll;
        hh.x = f2bf(vv.x); ll.x = f2bf(vv.x - bf2f(hh.x));
        hh.y = f2bf(vv.y); ll.y = f2bf(vv.y - bf2f(hh.y));
        hh.z = f2bf(vv.z); ll.z = f2bf(vv.z - bf2f(hh.z));
        hh.w = f2bf(vv.w); ll.w = f2bf(vv.w - bf2f(hh.w));
        *(ushort4*)(Ohi + bidx + i*4) = hh;
        *(ushort4*)(Olo + bidx + i*4) = ll;
    }
}

// ---------------------------------------------------------------------------
// Classifier: logits[b,n] = dot(x[b,0,:], Wc[n,:]) + bc[n]
// ---------------------------------------------------------------------------
__global__ void cls_kernel(const float* __restrict__ x,
                           const float* __restrict__ Wc,
                           const float* __restrict__ bc,
                           float* __restrict__ out) {
    const int b = blockIdx.x >> 1;
    const int n = blockIdx.x & 1;
    const int t = threadIdx.x;
    const float* px = x + (size_t)b * Ss * Hdim;
    const float* pw = Wc + (size_t)n * Hdim;
    float partial = 0.f;
    for (int k = t; k < Hdim; k += 256) partial = fmaf(px[k], pw[k], partial);
    __shared__ float red[256];
    red[t] = partial;
    __syncthreads();
    for (int off = 128; off > 0; off >>= 1) {
        if (t < off) red[t] += red[t + off];
        __syncthreads();
    }
    if (t == 0) out[blockIdx.x] = red[0] + bc[n];
}

// ---------------------------------------------------------------------------
extern "C" void kernel_launch(void* const* d_in, const int* in_sizes, int n_in,
                              void* d_out, int out_size, void* d_ws, size_t ws_size,
                              hipStream_t stream) {
    const int*   ids = (const int*)d_in[0];
    const float* emb = (const float*)d_in[1];
    const float* Wq  = (const float*)d_in[2];
    const float* bq  = (const float*)d_in[3];
    const float* Wk  = (const float*)d_in[4];
    const float* bk  = (const float*)d_in[5];
    const float* Wv  = (const float*)d_in[6];
    const float* bv  = (const float*)d_in[7];
    const float* Wi  = (const float*)d_in[8];
    const float* bi  = (const float*)d_in[9];
    const float* Wo  = (const float*)d_in[10];
    const float* bo  = (const float*)d_in[11];
    const float* Wc  = (const float*)d_in[12];
    const float* bc  = (const float*)d_in[13];
    float* out = (float*)d_out;

    const size_t F  = (size_t)Mm * Hdim;   // 3,145,728 elements
    const size_t WS = (size_t)Hdim * Hdim; // 589,824 elements

    float*  hbuf  = (float*)d_ws;          // fp32 activations
    float*  qb    = hbuf + F;
    float*  kb    = qb + F;
    float*  vb    = kb + F;
    float*  ab    = vb + F;
    ushort* hb_hi = (ushort*)(ab + F);     // bf16 splits
    ushort* hb_lo = hb_hi + F;
    ushort* ab_hi = hb_lo + F;
    ushort* ab_lo = ab_hi + F;
    ushort* in_hi = ab_lo + F;
    ushort* in_lo = in_hi + F;
    ushort* w_hi  = in_lo + F;             // per-layer weight split (5 matrices)
    ushort* w_lo  = w_hi + 5 * WS;         // total ws usage ~112 MB

    embed_kernel<<<Mm, 192, 0, stream>>>(ids, emb, hbuf, hb_hi, hb_lo);

    dim3 ggrid(Mm / TM, Hdim / TN);        // (64, 8) = 512 blocks
    for (int l = 0; l < NLAYER; ++l) {
        const size_t off = (size_t)l * WS;
        split5_kernel<<<2880, 256, 0, stream>>>(Wq + off, Wk + off, Wv + off,
                                                Wi + off, Wo + off, w_hi, w_lo);
        gemm_mfma<<<ggrid, 256, 0, stream>>>(hb_hi, hb_lo, w_hi + 0*WS, w_lo + 0*WS,
                                             bq + l*Hdim, nullptr, qb, nullptr, nullptr, 0);
        gemm_mfma<<<ggrid, 256, 0, stream>>>(hb_hi, hb_lo, w_hi + 1*WS, w_lo + 1*WS,
                                             bk + l*Hdim, nullptr, kb, nullptr, nullptr, 0);
        gemm_mfma<<<ggrid, 256, 0, stream>>>(hb_hi, hb_lo, w_hi + 2*WS, w_lo + 2*WS,
                                             bv + l*Hdim, nullptr, vb, nullptr, nullptr, 0);
        attn_kernel<<<dim3(Ss / 64, NH, Bb), 256, 0, stream>>>(qb, kb, vb, ab, ab_hi, ab_lo);
        gemm_mfma<<<ggrid, 256, 0, stream>>>(ab_hi, ab_lo, w_hi + 3*WS, w_lo + 3*WS,
                                             bi + l*Hdim, nullptr, nullptr, in_hi, in_lo, 1);
        gemm_mfma<<<ggrid, 256, 0, stream>>>(in_hi, in_lo, w_hi + 4*WS, w_lo + 4*WS,
                                             bo + l*Hdim, ab, hbuf, hb_hi, hb_lo, 0);
    }

    cls_kernel<<<Bb * NL, 256, 0, stream>>>(hbuf, Wc, bc, out);
}

// Round 5
// 1196.245 us; speedup vs baseline: 4.0535x; 1.6647x over previous
//
#include <hip/hip_runtime.h>
#include <hip/hip_bf16.h>
#include <math.h>

// Problem constants
constexpr int Hdim = 768;
constexpr int NH   = 12;
constexpr int HD   = 64;
constexpr int NLAYER = 4;
constexpr int Bb   = 4;
constexpr int Ss   = 1024;
constexpr int Mm   = Bb * Ss;   // 4096 rows
constexpr int NL   = 2;

typedef short  bf16x8 __attribute__((ext_vector_type(8)));
typedef short  bf16x4 __attribute__((ext_vector_type(4)));
typedef float  f32x4  __attribute__((ext_vector_type(4)));

__device__ __forceinline__ ushort f2bf(float f) {
    uint u = __float_as_uint(f);
    u += 0x7FFF + ((u >> 16) & 1);          // round-to-nearest-even
    return (ushort)(u >> 16);
}
__device__ __forceinline__ float bf2f(ushort h) {
    return __uint_as_float(((uint)h) << 16);
}

// 16x16x16 bf16 MFMA (K=16). Builtin when available; else tied-accumulator
// asm (D==C in the same registers -> no src/dst aliasing hazard).
__device__ __forceinline__ f32x4 mfma16(bf16x4 a, bf16x4 b, f32x4 c) {
#if __has_builtin(__builtin_amdgcn_mfma_f32_16x16x16bf16_1k)
    return __builtin_amdgcn_mfma_f32_16x16x16bf16_1k(a, b, c, 0, 0, 0);
#else
    asm("v_mfma_f32_16x16x16_bf16 %0, %1, %2, %0" : "+v"(c) : "v"(a), "v"(b));
    return c;
#endif
}

// ---------------------------------------------------------------------------
// Embedding gather: emits bf16 hi/lo split of x.
// ---------------------------------------------------------------------------
__global__ void embed_kernel(const int* __restrict__ ids,
                             const float* __restrict__ emb,
                             ushort* __restrict__ xh, ushort* __restrict__ xl) {
    int row = blockIdx.x;              // 0..4095
    int t = threadIdx.x;               // 0..191
    int id = ids[row];
    float4 v = ((const float4*)(emb + (size_t)id * Hdim))[t];
    ushort4 h, l;
    h.x = f2bf(v.x); l.x = f2bf(v.x - bf2f(h.x));
    h.y = f2bf(v.y); l.y = f2bf(v.y - bf2f(h.y));
    h.z = f2bf(v.z); l.z = f2bf(v.z - bf2f(h.z));
    h.w = f2bf(v.w); l.w = f2bf(v.w - bf2f(h.w));
    *(ushort4*)(xh + (size_t)row * Hdim + t * 4) = h;
    *(ushort4*)(xl + (size_t)row * Hdim + t * 4) = l;
}

// ---------------------------------------------------------------------------
// Split one layer's five weight matrices (768x768) into bf16 hi/lo.
// ---------------------------------------------------------------------------
__global__ void split5_kernel(const float* __restrict__ w0, const float* __restrict__ w1,
                              const float* __restrict__ w2, const float* __restrict__ w3,
                              const float* __restrict__ w4,
                              ushort* __restrict__ hi, ushort* __restrict__ lo) {
    int i = blockIdx.x * 256 + threadIdx.x;   // quad index
    int which = i / 147456;
    int j = i - which * 147456;
    const float* src = which == 0 ? w0 : which == 1 ? w1 : which == 2 ? w2
                     : which == 3 ? w3 : w4;
    float4 v = ((const float4*)src)[j];
    ushort4 h, l;
    h.x = f2bf(v.x); l.x = f2bf(v.x - bf2f(h.x));
    h.y = f2bf(v.y); l.y = f2bf(v.y - bf2f(h.y));
    h.z = f2bf(v.z); l.z = f2bf(v.z - bf2f(h.z));
    h.w = f2bf(v.w); l.w = f2bf(v.w - bf2f(h.w));
    size_t o = (size_t)which * 589824 + (size_t)j * 4;
    *(ushort4*)(hi + o) = h;
    *(ushort4*)(lo + o) = l;
}

// ---------------------------------------------------------------------------
// Split-bf16 MFMA GEMM: Y[m,n] = sum_k X[m,k]*W[n,k] (+bias, +relu, +resid).
// Block 64x96, BK=32, 4 waves. (Verified numerically in round 3.)
// ---------------------------------------------------------------------------
constexpr int TM = 64, TN = 96, TK = 32, LSTR = 40;

__global__ __launch_bounds__(256) void gemm_mfma(
    const ushort* __restrict__ Xhi, const ushort* __restrict__ Xlo,
    const ushort* __restrict__ Whi, const ushort* __restrict__ Wlo,
    const float* __restrict__ bias,
    const ushort* __restrict__ residH, const ushort* __restrict__ residL,
    float* __restrict__ Yf, ushort* __restrict__ Yhi, ushort* __restrict__ Ylo,
    int relu)
{
    __shared__ ushort Xs[2][TM * LSTR];
    __shared__ ushort Ws[2][TN * LSTR];

    const int tid  = threadIdx.x;
    const int m0   = blockIdx.x * TM;
    const int n0   = blockIdx.y * TN;
    const int lane = tid & 63, wid = tid >> 6;
    const int wr = wid >> 1, wc = wid & 1;
    const int l15 = lane & 15, lk = (lane >> 4) * 8;

    const int srow = tid >> 2;
    const int sseg = (tid & 3) * 8;

    f32x4 acc[2][3];
    #pragma unroll
    for (int m = 0; m < 2; ++m)
        #pragma unroll
        for (int n = 0; n < 3; ++n) acc[m][n] = (f32x4){0.f, 0.f, 0.f, 0.f};

    for (int k0 = 0; k0 < Hdim; k0 += TK) {
        __syncthreads();
        {
            const size_t g = (size_t)(m0 + srow) * Hdim + k0 + sseg;
            *(uint4*)&Xs[0][srow * LSTR + sseg] = *(const uint4*)(Xhi + g);
            *(uint4*)&Xs[1][srow * LSTR + sseg] = *(const uint4*)(Xlo + g);
        }
        {
            const size_t g = (size_t)(n0 + srow) * Hdim + k0 + sseg;
            *(uint4*)&Ws[0][srow * LSTR + sseg] = *(const uint4*)(Whi + g);
            *(uint4*)&Ws[1][srow * LSTR + sseg] = *(const uint4*)(Wlo + g);
            if (tid < 128) {
                const int r2 = srow + 64;
                const size_t g2 = (size_t)(n0 + r2) * Hdim + k0 + sseg;
                *(uint4*)&Ws[0][r2 * LSTR + sseg] = *(const uint4*)(Whi + g2);
                *(uint4*)&Ws[1][r2 * LSTR + sseg] = *(const uint4*)(Wlo + g2);
            }
        }
        __syncthreads();

        bf16x8 ah[2], al[2], bh[3], bl[3];
        #pragma unroll
        for (int m = 0; m < 2; ++m) {
            const int r = wr * 32 + m * 16 + l15;
            ah[m] = *(const bf16x8*)&Xs[0][r * LSTR + lk];
            al[m] = *(const bf16x8*)&Xs[1][r * LSTR + lk];
        }
        #pragma unroll
        for (int n = 0; n < 3; ++n) {
            const int r = wc * 48 + n * 16 + l15;
            bh[n] = *(const bf16x8*)&Ws[0][r * LSTR + lk];
            bl[n] = *(const bf16x8*)&Ws[1][r * LSTR + lk];
        }
        #pragma unroll
        for (int m = 0; m < 2; ++m)
            #pragma unroll
            for (int n = 0; n < 3; ++n) {
                acc[m][n] = __builtin_amdgcn_mfma_f32_16x16x32_bf16(ah[m], bh[n], acc[m][n], 0, 0, 0);
                acc[m][n] = __builtin_amdgcn_mfma_f32_16x16x32_bf16(ah[m], bl[n], acc[m][n], 0, 0, 0);
                acc[m][n] = __builtin_amdgcn_mfma_f32_16x16x32_bf16(al[m], bh[n], acc[m][n], 0, 0, 0);
            }
    }

    const int rbase = m0 + wr * 32 + (lane >> 4) * 4;
    #pragma unroll
    for (int n = 0; n < 3; ++n) {
        const int col = n0 + wc * 48 + n * 16 + l15;
        const float bc_ = bias[col];
        #pragma unroll
        for (int m = 0; m < 2; ++m) {
            #pragma unroll
            for (int r = 0; r < 4; ++r) {
                const int row = rbase + m * 16 + r;
                const size_t idx = (size_t)row * Hdim + col;
                float v = acc[m][n][r] + bc_;
                if (relu) v = v > 0.f ? v : 0.f;
                if (residH) v += bf2f(residH[idx]) + bf2f(residL[idx]);
                if (Yf) Yf[idx] = v;
                if (Yhi) {
                    const ushort h = f2bf(v);
                    Yhi[idx] = h;
                    Ylo[idx] = f2bf(v - bf2f(h));
                }
            }
        }
    }
}

// ---------------------------------------------------------------------------
// MFMA flash attention, split-bf16. Block = 128 q rows, 4 waves x 32 q.
// S^T = K*Q^T (16x16x32): q = lane&15 -> lane-local softmax (2 shfl_xor).
// O^T = V^T*P^T (16x16x16): P fragment register pattern matches the score
// output registers exactly (k = (lane>>4)*4+j) -> zero cross-lane movement.
// ---------------------------------------------------------------------------
__global__ __launch_bounds__(256, 2) void attn_mfma(
    const ushort* __restrict__ Qh, const ushort* __restrict__ Ql,
    const ushort* __restrict__ Kh, const ushort* __restrict__ Kl,
    const ushort* __restrict__ Vh, const ushort* __restrict__ Vl,
    ushort* __restrict__ Oh, ushort* __restrict__ Ol)
{
    __shared__ ushort sm[4][64][72];   // Khi, Klo, Vthi, Vtlo = 36864 B

    const int tid  = threadIdx.x;
    const int lane = tid & 63, wid = tid >> 6;
    const int l15  = lane & 15, g = lane >> 4;
    const int qtile = blockIdx.x;      // 0..7
    const int h = blockIdx.y, b = blockIdx.z;

    const size_t rowbase = (size_t)b * Ss;
    const int    colbase = h * HD;
    const int    q0 = qtile * 128 + wid * 32;

    // Hoisted Q fragments [qfrag][kstep][hi/lo]
    bf16x8 qf[2][2][2];
    #pragma unroll
    for (int nf = 0; nf < 2; ++nf) {
        const size_t r = (rowbase + q0 + nf * 16 + l15) * Hdim + colbase;
        #pragma unroll
        for (int ks = 0; ks < 2; ++ks) {
            qf[nf][ks][0] = *(const bf16x8*)(Qh + r + ks * 32 + g * 8);
            qf[nf][ks][1] = *(const bf16x8*)(Ql + r + ks * 32 + g * 8);
        }
    }

    f32x4 accO[4][2];                  // [dfrag][qfrag]; O^T: d=g*4+r, q=l15
    #pragma unroll
    for (int mf = 0; mf < 4; ++mf)
        #pragma unroll
        for (int nf = 0; nf < 2; ++nf) accO[mf][nf] = (f32x4){0.f, 0.f, 0.f, 0.f};
    float mrun[2] = {-1e30f, -1e30f}, lrun[2] = {0.f, 0.f};

    const int srow = tid >> 2, sp = tid & 3;

    for (int tile = 0; tile < 16; ++tile) {
        __syncthreads();
        // ---- stage K rows + transposed V (hi/lo) -------------------------
        const size_t krow = (rowbase + tile * 64 + srow) * Hdim + colbase;
        #pragma unroll
        for (int u = 0; u < 2; ++u) {
            const int seg = sp * 2 + u;                  // 0..7
            *(uint4*)&sm[0][srow][seg * 8] = *(const uint4*)(Kh + krow + seg * 8);
            *(uint4*)&sm[1][srow][seg * 8] = *(const uint4*)(Kl + krow + seg * 8);
            union { uint4 q; ushort s[8]; } vh_, vl_;
            vh_.q = *(const uint4*)(Vh + krow + seg * 8);
            vl_.q = *(const uint4*)(Vl + krow + seg * 8);
            #pragma unroll
            for (int j = 0; j < 8; ++j) {
                sm[2][seg * 8 + j][srow] = vh_.s[j];
                sm[3][seg * 8 + j][srow] = vl_.s[j];
            }
        }
        __syncthreads();

        // ---- S^T = K · Q^T (split 3-term) --------------------------------
        f32x4 sc[4][2];
        #pragma unroll
        for (int m = 0; m < 4; ++m)
            #pragma unroll
            for (int nf = 0; nf < 2; ++nf) sc[m][nf] = (f32x4){0.f, 0.f, 0.f, 0.f};
        #pragma unroll
        for (int ks = 0; ks < 2; ++ks)
            #pragma unroll
            for (int m = 0; m < 4; ++m) {
                bf16x8 kh_ = *(const bf16x8*)&sm[0][m * 16 + l15][ks * 32 + g * 8];
                bf16x8 kl_ = *(const bf16x8*)&sm[1][m * 16 + l15][ks * 32 + g * 8];
                #pragma unroll
                for (int nf = 0; nf < 2; ++nf) {
                    sc[m][nf] = __builtin_amdgcn_mfma_f32_16x16x32_bf16(kh_, qf[nf][ks][0], sc[m][nf], 0, 0, 0);
                    sc[m][nf] = __builtin_amdgcn_mfma_f32_16x16x32_bf16(kh_, qf[nf][ks][1], sc[m][nf], 0, 0, 0);
                    sc[m][nf] = __builtin_amdgcn_mfma_f32_16x16x32_bf16(kl_, qf[nf][ks][0], sc[m][nf], 0, 0, 0);
                }
            }

        // ---- online softmax (lane-local per q) + pack P hi/lo ------------
        bf16x4 pbh[4][2], pbl[4][2];
        #pragma unroll
        for (int nf = 0; nf < 2; ++nf) {
            float tmax = -1e30f;
            #pragma unroll
            for (int m = 0; m < 4; ++m)
                #pragma unroll
                for (int r = 0; r < 4; ++r) {
                    sc[m][nf][r] *= 0.125f;
                    tmax = fmaxf(tmax, sc[m][nf][r]);
                }
            tmax = fmaxf(tmax, __shfl_xor(tmax, 16));
            tmax = fmaxf(tmax, __shfl_xor(tmax, 32));
            const float mnew = fmaxf(mrun[nf], tmax);
            const float corr = __expf(mrun[nf] - mnew);
            mrun[nf] = mnew;
            float psum = 0.f;
            #pragma unroll
            for (int m = 0; m < 4; ++m)
                #pragma unroll
                for (int r = 0; r < 4; ++r) {
                    const float p = __expf(sc[m][nf][r] - mnew);
                    sc[m][nf][r] = p;
                    psum += p;
                }
            psum += __shfl_xor(psum, 16);
            psum += __shfl_xor(psum, 32);
            lrun[nf] = lrun[nf] * corr + psum;
            #pragma unroll
            for (int mf = 0; mf < 4; ++mf) {
                accO[mf][nf][0] *= corr; accO[mf][nf][1] *= corr;
                accO[mf][nf][2] *= corr; accO[mf][nf][3] *= corr;
            }
            #pragma unroll
            for (int kt = 0; kt < 4; ++kt)
                #pragma unroll
                for (int r = 0; r < 4; ++r) {
                    const float p = sc[kt][nf][r];
                    const ushort hh = f2bf(p);
                    pbh[kt][nf][r] = (short)hh;
                    pbl[kt][nf][r] = (short)f2bf(p - bf2f(hh));
                }
        }

        // ---- O^T += V^T · P^T (16x16x16, split 3-term) -------------------
        #pragma unroll
        for (int kt = 0; kt < 4; ++kt)
            #pragma unroll
            for (int mf = 0; mf < 4; ++mf) {
                bf16x4 vh_ = *(const bf16x4*)&sm[2][mf * 16 + l15][kt * 16 + g * 4];
                bf16x4 vl_ = *(const bf16x4*)&sm[3][mf * 16 + l15][kt * 16 + g * 4];
                #pragma unroll
                for (int nf = 0; nf < 2; ++nf) {
                    accO[mf][nf] = mfma16(vh_, pbh[kt][nf], accO[mf][nf]);
                    accO[mf][nf] = mfma16(vh_, pbl[kt][nf], accO[mf][nf]);
                    accO[mf][nf] = mfma16(vl_, pbh[kt][nf], accO[mf][nf]);
                }
            }
    }

    // ---- epilogue: transpose O through LDS, emit bf16 hi/lo --------------
    __syncthreads();
    float* ot = (float*)&sm[0][0][0] + wid * 2176;   // 32 rows x stride 68
    #pragma unroll
    for (int nf = 0; nf < 2; ++nf) {
        const float linv = 1.f / lrun[nf];
        #pragma unroll
        for (int mf = 0; mf < 4; ++mf)
            #pragma unroll
            for (int r = 0; r < 4; ++r)
                ot[(nf * 16 + l15) * 68 + mf * 16 + g * 4 + r] = accO[mf][nf][r] * linv;
    }
    __syncthreads();
    const int orow = lane >> 1, oc = (lane & 1) * 32;
    const size_t gaddr = (rowbase + q0 + orow) * Hdim + colbase + oc;
    #pragma unroll
    for (int i = 0; i < 8; ++i) {
        float4 vv = *(float4*)&ot[orow * 68 + oc + i * 4];
        ushort4 hh, ll;
        hh.x = f2bf(vv.x); ll.x = f2bf(vv.x - bf2f(hh.x));
        hh.y = f2bf(vv.y); ll.y = f2bf(vv.y - bf2f(hh.y));
        hh.z = f2bf(vv.z); ll.z = f2bf(vv.z - bf2f(hh.z));
        hh.w = f2bf(vv.w); ll.w = f2bf(vv.w - bf2f(hh.w));
        *(ushort4*)(Oh + gaddr + i * 4) = hh;
        *(ushort4*)(Ol + gaddr + i * 4) = ll;
    }
}

// ---------------------------------------------------------------------------
// Classifier: logits[b,n] = dot(x[b,0,:], Wc[n,:]) + bc[n]
// ---------------------------------------------------------------------------
__global__ void cls_kernel(const float* __restrict__ x,
                           const float* __restrict__ Wc,
                           const float* __restrict__ bc,
                           float* __restrict__ out) {
    const int b = blockIdx.x >> 1;
    const int n = blockIdx.x & 1;
    const int t = threadIdx.x;
    const float* px = x + (size_t)b * Ss * Hdim;
    const float* pw = Wc + (size_t)n * Hdim;
    float partial = 0.f;
    for (int k = t; k < Hdim; k += 256) partial = fmaf(px[k], pw[k], partial);
    __shared__ float red[256];
    red[t] = partial;
    __syncthreads();
    for (int off = 128; off > 0; off >>= 1) {
        if (t < off) red[t] += red[t + off];
        __syncthreads();
    }
    if (t == 0) out[blockIdx.x] = red[0] + bc[n];
}

// ---------------------------------------------------------------------------
extern "C" void kernel_launch(void* const* d_in, const int* in_sizes, int n_in,
                              void* d_out, int out_size, void* d_ws, size_t ws_size,
                              hipStream_t stream) {
    const int*   ids = (const int*)d_in[0];
    const float* emb = (const float*)d_in[1];
    const float* Wq  = (const float*)d_in[2];
    const float* bq  = (const float*)d_in[3];
    const float* Wk  = (const float*)d_in[4];
    const float* bk  = (const float*)d_in[5];
    const float* Wv  = (const float*)d_in[6];
    const float* bv  = (const float*)d_in[7];
    const float* Wi  = (const float*)d_in[8];
    const float* bi  = (const float*)d_in[9];
    const float* Wo  = (const float*)d_in[10];
    const float* bo  = (const float*)d_in[11];
    const float* Wc  = (const float*)d_in[12];
    const float* bc  = (const float*)d_in[13];
    float* out = (float*)d_out;

    const size_t F  = (size_t)Mm * Hdim;
    const size_t WS = (size_t)Hdim * Hdim;

    float*  hbuf  = (float*)d_ws;              // fp32 activations (for cls)
    ushort* hb_hi = (ushort*)(hbuf + F);
    ushort* hb_lo = hb_hi + F;
    ushort* qh = hb_lo + F;  ushort* ql = qh + F;
    ushort* kh = ql + F;     ushort* kl = kh + F;
    ushort* vh = kl + F;     ushort* vl = vh + F;
    ushort* ah = vl + F;     ushort* al = ah + F;
    ushort* ih = al + F;     ushort* il = ih + F;
    ushort* w_hi = il + F;
    ushort* w_lo = w_hi + 5 * WS;

    embed_kernel<<<Mm, 192, 0, stream>>>(ids, emb, hb_hi, hb_lo);

    dim3 ggrid(Mm / TM, Hdim / TN);            // (64, 8)
    for (int l = 0; l < NLAYER; ++l) {
        const size_t off = (size_t)l * WS;
        split5_kernel<<<2880, 256, 0, stream>>>(Wq + off, Wk + off, Wv + off,
                                                Wi + off, Wo + off, w_hi, w_lo);
        gemm_mfma<<<ggrid, 256, 0, stream>>>(hb_hi, hb_lo, w_hi + 0*WS, w_lo + 0*WS,
                                             bq + l*Hdim, nullptr, nullptr,
                                             nullptr, qh, ql, 0);
        gemm_mfma<<<ggrid, 256, 0, stream>>>(hb_hi, hb_lo, w_hi + 1*WS, w_lo + 1*WS,
                                             bk + l*Hdim, nullptr, nullptr,
                                             nullptr, kh, kl, 0);
        gemm_mfma<<<ggrid, 256, 0, stream>>>(hb_hi, hb_lo, w_hi + 2*WS, w_lo + 2*WS,
                                             bv + l*Hdim, nullptr, nullptr,
                                             nullptr, vh, vl, 0);
        attn_mfma<<<dim3(Ss / 128, NH, Bb), 256, 0, stream>>>(qh, ql, kh, kl, vh, vl, ah, al);
        gemm_mfma<<<ggrid, 256, 0, stream>>>(ah, al, w_hi + 3*WS, w_lo + 3*WS,
                                             bi + l*Hdim, nullptr, nullptr,
                                             nullptr, ih, il, 1);
        gemm_mfma<<<ggrid, 256, 0, stream>>>(ih, il, w_hi + 4*WS, w_lo + 4*WS,
                                             bo + l*Hdim, ah, al,
                                             hbuf, hb_hi, hb_lo, 0);
    }

    cls_kernel<<<Bb * NL, 256, 0, stream>>>(hbuf, Wc, bc, out);
}

// Round 6
// 738.631 us; speedup vs baseline: 6.5649x; 1.6195x over previous
//
#include <hip/hip_runtime.h>
#include <hip/hip_bf16.h>
#include <math.h>

// Problem constants
constexpr int Hdim = 768;
constexpr int NH   = 12;
constexpr int HD   = 64;
constexpr int NLAYER = 4;
constexpr int Bb   = 4;
constexpr int Ss   = 1024;
constexpr int Mm   = Bb * Ss;   // 4096 rows
constexpr int NL   = 2;

typedef short  bf16x8 __attribute__((ext_vector_type(8)));
typedef short  bf16x4 __attribute__((ext_vector_type(4)));
typedef float  f32x4  __attribute__((ext_vector_type(4)));

__device__ __forceinline__ ushort f2bf(float f) {
    uint u = __float_as_uint(f);
    u += 0x7FFF + ((u >> 16) & 1);          // round-to-nearest-even
    return (ushort)(u >> 16);
}
__device__ __forceinline__ float bf2f(ushort h) {
    return __uint_as_float(((uint)h) << 16);
}

// 16x16x16 bf16 MFMA (K=16). Builtin when available; else tied-accumulator asm.
__device__ __forceinline__ f32x4 mfma16(bf16x4 a, bf16x4 b, f32x4 c) {
#if __has_builtin(__builtin_amdgcn_mfma_f32_16x16x16bf16_1k)
    return __builtin_amdgcn_mfma_f32_16x16x16bf16_1k(a, b, c, 0, 0, 0);
#else
    asm("v_mfma_f32_16x16x16_bf16 %0, %1, %2, %0" : "+v"(c) : "v"(a), "v"(b));
    return c;
#endif
}

// async global->LDS, 16B per lane; LDS dest = wave-uniform base + lane*16.
__device__ __forceinline__ void gload16(const void* g, void* l) {
    __builtin_amdgcn_global_load_lds(
        (const __attribute__((address_space(1))) unsigned int*)g,
        (__attribute__((address_space(3))) unsigned int*)l, 16, 0, 0);
}

// ---------------------------------------------------------------------------
// Embedding gather: emits bf16 hi/lo split of x.
// ---------------------------------------------------------------------------
__global__ void embed_kernel(const int* __restrict__ ids,
                             const float* __restrict__ emb,
                             ushort* __restrict__ xh, ushort* __restrict__ xl) {
    int row = blockIdx.x;              // 0..4095
    int t = threadIdx.x;               // 0..191
    int id = ids[row];
    float4 v = ((const float4*)(emb + (size_t)id * Hdim))[t];
    ushort4 h, l;
    h.x = f2bf(v.x); l.x = f2bf(v.x - bf2f(h.x));
    h.y = f2bf(v.y); l.y = f2bf(v.y - bf2f(h.y));
    h.z = f2bf(v.z); l.z = f2bf(v.z - bf2f(h.z));
    h.w = f2bf(v.w); l.w = f2bf(v.w - bf2f(h.w));
    *(ushort4*)(xh + (size_t)row * Hdim + t * 4) = h;
    *(ushort4*)(xl + (size_t)row * Hdim + t * 4) = l;
}

// ---------------------------------------------------------------------------
// Split one layer's five weight matrices (768x768) into bf16 hi/lo.
// ---------------------------------------------------------------------------
__global__ void split5_kernel(const float* __restrict__ w0, const float* __restrict__ w1,
                              const float* __restrict__ w2, const float* __restrict__ w3,
                              const float* __restrict__ w4,
                              ushort* __restrict__ hi, ushort* __restrict__ lo) {
    int i = blockIdx.x * 256 + threadIdx.x;   // quad index
    int which = i / 147456;
    int j = i - which * 147456;
    const float* src = which == 0 ? w0 : which == 1 ? w1 : which == 2 ? w2
                     : which == 3 ? w3 : w4;
    float4 v = ((const float4*)src)[j];
    ushort4 h, l;
    h.x = f2bf(v.x); l.x = f2bf(v.x - bf2f(h.x));
    h.y = f2bf(v.y); l.y = f2bf(v.y - bf2f(h.y));
    h.z = f2bf(v.z); l.z = f2bf(v.z - bf2f(h.z));
    h.w = f2bf(v.w); l.w = f2bf(v.w - bf2f(h.w));
    size_t o = (size_t)which * 589824 + (size_t)j * 4;
    *(ushort4*)(hi + o) = h;
    *(ushort4*)(lo + o) = l;
}

// ---------------------------------------------------------------------------
// Split-bf16 MFMA GEMM, m97-style: BM=64 BN=128 BK=64, 4 waves (wave 32x64),
// global_load_lds staging with pre-swizzled source (slot ^= row&7), swizzled
// ds_read_b128 fragment reads (2-way banks). N may be 768 or 2304 (fused QKV:
// output segment seg=col/768 -> Y + seg*outSeg, bias b0/b1/b2 per segment).
// ---------------------------------------------------------------------------
__global__ __launch_bounds__(256) void gemm_mfma(
    const ushort* __restrict__ Xh, const ushort* __restrict__ Xl,
    const ushort* __restrict__ Wh, const ushort* __restrict__ Wl,
    const float* __restrict__ b0, const float* __restrict__ b1,
    const float* __restrict__ b2,
    const ushort* __restrict__ residH, const ushort* __restrict__ residL,
    ushort* __restrict__ Yh, ushort* __restrict__ Yl,
    int relu, size_t outSeg)
{
    __shared__ ushort lds[24576];   // Ah@0(4096) Al@4096 Bh@8192(8192) Bl@16384

    const int tid = threadIdx.x;
    const int lane = tid & 63, w = tid >> 6;
    const int l15 = lane & 15, g = lane >> 4;
    const int wr = w >> 1, wc = w & 1;
    const int m0 = blockIdx.x * 64, n0 = blockIdx.y * 128;

    // staging lane constants: 8 rows x 8 slots(16B) per wave-instr
    const int srow = lane >> 3;                    // 0..7
    const int sswz = 8 * ((lane & 7) ^ srow);      // swizzled slot (ushorts)
    const ushort* pAh = Xh + (size_t)(m0 + w*16 + srow) * Hdim + sswz;
    const ushort* pAl = Xl + (size_t)(m0 + w*16 + srow) * Hdim + sswz;
    const ushort* pBh = Wh + (size_t)(n0 + w*32 + srow) * Hdim + sswz;
    const ushort* pBl = Wl + (size_t)(n0 + w*32 + srow) * Hdim + sswz;
    ushort* lAh = &lds[0]     + w * 1024;
    ushort* lAl = &lds[4096]  + w * 1024;
    ushort* lBh = &lds[8192]  + w * 2048;
    ushort* lBl = &lds[16384] + w * 2048;

    f32x4 acc[2][4];
    #pragma unroll
    for (int m = 0; m < 2; ++m)
        #pragma unroll
        for (int n = 0; n < 4; ++n) acc[m][n] = (f32x4){0.f, 0.f, 0.f, 0.f};

    // fragment read offsets (per-lane constants + compile-time ks/g)
    const int fsw = l15 & 7;

    for (int k0 = 0; k0 < Hdim; k0 += 64) {
        __syncthreads();
        gload16(pAh + k0,          lAh);
        gload16(pAh + k0 + 8*Hdim, lAh + 512);
        gload16(pAl + k0,          lAl);
        gload16(pAl + k0 + 8*Hdim, lAl + 512);
        gload16(pBh + k0,           lBh);
        gload16(pBh + k0 + 8*Hdim,  lBh + 512);
        gload16(pBh + k0 + 16*Hdim, lBh + 1024);
        gload16(pBh + k0 + 24*Hdim, lBh + 1536);
        gload16(pBl + k0,           lBl);
        gload16(pBl + k0 + 8*Hdim,  lBl + 512);
        gload16(pBl + k0 + 16*Hdim, lBl + 1024);
        gload16(pBl + k0 + 24*Hdim, lBl + 1536);
        __syncthreads();

        #pragma unroll
        for (int ks = 0; ks < 2; ++ks) {
            const int so = 8 * ((ks*4 + g) ^ fsw);
            bf16x8 xh_[2], xl_[2];
            #pragma unroll
            for (int m = 0; m < 2; ++m) {
                const int off = (wr*32 + m*16 + l15) * 64 + so;
                xh_[m] = *(const bf16x8*)&lds[off];
                xl_[m] = *(const bf16x8*)&lds[4096 + off];
            }
            #pragma unroll
            for (int n = 0; n < 4; ++n) {
                const int off = (wc*64 + n*16 + l15) * 64 + so;
                bf16x8 wh_ = *(const bf16x8*)&lds[8192 + off];
                bf16x8 wl_ = *(const bf16x8*)&lds[16384 + off];
                #pragma unroll
                for (int m = 0; m < 2; ++m) {
                    acc[m][n] = __builtin_amdgcn_mfma_f32_16x16x32_bf16(xh_[m], wh_, acc[m][n], 0, 0, 0);
                    acc[m][n] = __builtin_amdgcn_mfma_f32_16x16x32_bf16(xh_[m], wl_, acc[m][n], 0, 0, 0);
                    acc[m][n] = __builtin_amdgcn_mfma_f32_16x16x32_bf16(xl_[m], wh_, acc[m][n], 0, 0, 0);
                }
            }
        }
    }

    // Epilogue. D layout: col=lane&15, row=(lane>>4)*4+reg.
    const int rb = m0 + wr*32 + g*4;
    #pragma unroll
    for (int n = 0; n < 4; ++n) {
        const int col = n0 + wc*64 + n*16 + l15;
        const int seg = col / Hdim;
        const int lc  = col - seg * Hdim;
        const float bias = (seg == 0 ? b0 : seg == 1 ? b1 : b2)[lc];
        #pragma unroll
        for (int m = 0; m < 2; ++m) {
            #pragma unroll
            for (int r = 0; r < 4; ++r) {
                const size_t idx = (size_t)seg * outSeg + (size_t)(rb + m*16 + r) * Hdim + lc;
                float v = acc[m][n][r] + bias;
                if (relu) v = v > 0.f ? v : 0.f;
                if (residH) v += bf2f(residH[idx]) + bf2f(residL[idx]);
                const ushort hh = f2bf(v);
                Yh[idx] = hh;
                Yl[idx] = f2bf(v - bf2f(hh));
            }
        }
    }
}

// ---------------------------------------------------------------------------
// MFMA flash attention, split-bf16. Block = 128 q rows, 4 waves x 32 q.
// K staged via global_load_lds (linear [64][64], XOR-swizzled reads);
// V^T reg-staged with kx = vrow ^ (vsp<<4) swizzle (conflict-free writes).
// ---------------------------------------------------------------------------
__global__ __launch_bounds__(256, 2) void attn_mfma(
    const ushort* __restrict__ Qh, const ushort* __restrict__ Ql,
    const ushort* __restrict__ Kh, const ushort* __restrict__ Kl,
    const ushort* __restrict__ Vh, const ushort* __restrict__ Vl,
    ushort* __restrict__ Oh, ushort* __restrict__ Ol)
{
    __shared__ ushort sm[17408];   // Kh[64][64]@0, Kl@4096, Vth[64][72]@8192, Vtl@12800

    const int tid  = threadIdx.x;
    const int lane = tid & 63, wid = tid >> 6;
    const int l15  = lane & 15, g = lane >> 4;
    const int qtile = blockIdx.x;      // 0..7
    const int h = blockIdx.y, b = blockIdx.z;

    const size_t rowbase = (size_t)b * Ss;
    const int    colbase = h * HD;
    const int    q0 = qtile * 128 + wid * 32;

    // Hoisted Q fragments [qfrag][kstep][hi/lo]
    bf16x8 qf[2][2][2];
    #pragma unroll
    for (int nf = 0; nf < 2; ++nf) {
        const size_t r = (rowbase + q0 + nf * 16 + l15) * Hdim + colbase;
        #pragma unroll
        for (int ks = 0; ks < 2; ++ks) {
            qf[nf][ks][0] = *(const bf16x8*)(Qh + r + ks * 32 + g * 8);
            qf[nf][ks][1] = *(const bf16x8*)(Ql + r + ks * 32 + g * 8);
        }
    }

    f32x4 accO[4][2];                  // [dfrag][qfrag]; O^T: d=g*4+r, q=l15
    #pragma unroll
    for (int mf = 0; mf < 4; ++mf)
        #pragma unroll
        for (int nf = 0; nf < 2; ++nf) accO[mf][nf] = (f32x4){0.f, 0.f, 0.f, 0.f};
    float mrun[2] = {-1e30f, -1e30f}, lrun[2] = {0.f, 0.f};

    // K staging lane constants (gload_lds, 8 rows x 8 slots per instr)
    const int s8 = lane >> 3;
    const int kswz = 8 * ((lane & 7) ^ s8);
    const ushort* gK0 = Kh + (rowbase + wid*16 + s8) * Hdim + colbase + kswz;
    const ushort* gK1 = Kl + (rowbase + wid*16 + s8) * Hdim + colbase + kswz;
    ushort* lK0 = &sm[0]    + wid * 1024;
    ushort* lK1 = &sm[4096] + wid * 1024;

    // V staging constants
    const int vrow = tid >> 2, vsp = tid & 3;
    const int kx = vrow ^ (vsp << 4);          // swizzled k position

    const int fsw = l15 & 7;

    for (int tile = 0; tile < 16; ++tile) {
        __syncthreads();
        const size_t ko = (size_t)(tile * 64) * Hdim;
        gload16(gK0 + ko,           lK0);
        gload16(gK0 + ko + 8*Hdim,  lK0 + 512);
        gload16(gK1 + ko,           lK1);
        gload16(gK1 + ko + 8*Hdim,  lK1 + 512);
        // V^T reg-staged (swizzled, conflict-free)
        const size_t vg = (rowbase + tile * 64 + vrow) * Hdim + colbase;
        #pragma unroll
        for (int u = 0; u < 2; ++u) {
            const int seg = vsp * 2 + u;
            union { uint4 q; ushort s[8]; } vh_, vl_;
            vh_.q = *(const uint4*)(Vh + vg + seg * 8);
            vl_.q = *(const uint4*)(Vl + vg + seg * 8);
            #pragma unroll
            for (int j = 0; j < 8; ++j) {
                const int d = seg * 8 + j;
                sm[8192  + d * 72 + kx] = vh_.s[j];
                sm[12800 + d * 72 + kx] = vl_.s[j];
            }
        }
        __syncthreads();

        // ---- S^T = K · Q^T (split 3-term) --------------------------------
        f32x4 sc[4][2];
        #pragma unroll
        for (int m = 0; m < 4; ++m)
            #pragma unroll
            for (int nf = 0; nf < 2; ++nf) sc[m][nf] = (f32x4){0.f, 0.f, 0.f, 0.f};
        #pragma unroll
        for (int ks = 0; ks < 2; ++ks) {
            const int so = 8 * ((ks*4 + g) ^ fsw);
            #pragma unroll
            for (int m = 0; m < 4; ++m) {
                const int off = (m * 16 + l15) * 64 + so;
                bf16x8 kh_ = *(const bf16x8*)&sm[off];
                bf16x8 kl_ = *(const bf16x8*)&sm[4096 + off];
                #pragma unroll
                for (int nf = 0; nf < 2; ++nf) {
                    sc[m][nf] = __builtin_amdgcn_mfma_f32_16x16x32_bf16(kh_, qf[nf][ks][0], sc[m][nf], 0, 0, 0);
                    sc[m][nf] = __builtin_amdgcn_mfma_f32_16x16x32_bf16(kh_, qf[nf][ks][1], sc[m][nf], 0, 0, 0);
                    sc[m][nf] = __builtin_amdgcn_mfma_f32_16x16x32_bf16(kl_, qf[nf][ks][0], sc[m][nf], 0, 0, 0);
                }
            }
        }

        // ---- online softmax (lane-local per q) + pack P hi/lo ------------
        bf16x4 pbh[4][2], pbl[4][2];
        #pragma unroll
        for (int nf = 0; nf < 2; ++nf) {
            float tmax = -1e30f;
            #pragma unroll
            for (int m = 0; m < 4; ++m)
                #pragma unroll
                for (int r = 0; r < 4; ++r) {
                    sc[m][nf][r] *= 0.125f;
                    tmax = fmaxf(tmax, sc[m][nf][r]);
                }
            tmax = fmaxf(tmax, __shfl_xor(tmax, 16));
            tmax = fmaxf(tmax, __shfl_xor(tmax, 32));
            const float mnew = fmaxf(mrun[nf], tmax);
            const float corr = __expf(mrun[nf] - mnew);
            mrun[nf] = mnew;
            float psum = 0.f;
            #pragma unroll
            for (int m = 0; m < 4; ++m)
                #pragma unroll
                for (int r = 0; r < 4; ++r) {
                    const float p = __expf(sc[m][nf][r] - mnew);
                    sc[m][nf][r] = p;
                    psum += p;
                }
            psum += __shfl_xor(psum, 16);
            psum += __shfl_xor(psum, 32);
            lrun[nf] = lrun[nf] * corr + psum;
            #pragma unroll
            for (int mf = 0; mf < 4; ++mf) {
                accO[mf][nf][0] *= corr; accO[mf][nf][1] *= corr;
                accO[mf][nf][2] *= corr; accO[mf][nf][3] *= corr;
            }
            #pragma unroll
            for (int kt = 0; kt < 4; ++kt)
                #pragma unroll
                for (int r = 0; r < 4; ++r) {
                    const float p = sc[kt][nf][r];
                    const ushort hh = f2bf(p);
                    pbh[kt][nf][r] = (short)hh;
                    pbl[kt][nf][r] = (short)f2bf(p - bf2f(hh));
                }
        }

        // ---- O^T += V^T · P^T (16x16x16, split 3-term) -------------------
        #pragma unroll
        for (int kt = 0; kt < 4; ++kt)
            #pragma unroll
            for (int mf = 0; mf < 4; ++mf) {
                const int voff = (mf * 16 + l15) * 72 + ((kt ^ mf) * 16 + g * 4);
                bf16x4 vh_ = *(const bf16x4*)&sm[8192 + voff];
                bf16x4 vl_ = *(const bf16x4*)&sm[12800 + voff];
                #pragma unroll
                for (int nf = 0; nf < 2; ++nf) {
                    accO[mf][nf] = mfma16(vh_, pbh[kt][nf], accO[mf][nf]);
                    accO[mf][nf] = mfma16(vh_, pbl[kt][nf], accO[mf][nf]);
                    accO[mf][nf] = mfma16(vl_, pbh[kt][nf], accO[mf][nf]);
                }
            }
    }

    // ---- epilogue: transpose O through LDS, emit bf16 hi/lo --------------
    __syncthreads();
    float* ot = (float*)sm + wid * 2176;   // 32 rows x stride 68
    #pragma unroll
    for (int nf = 0; nf < 2; ++nf) {
        const float linv = 1.f / lrun[nf];
        #pragma unroll
        for (int mf = 0; mf < 4; ++mf)
            #pragma unroll
            for (int r = 0; r < 4; ++r)
                ot[(nf * 16 + l15) * 68 + mf * 16 + g * 4 + r] = accO[mf][nf][r] * linv;
    }
    __syncthreads();
    const int orow = lane >> 1, oc = (lane & 1) * 32;
    const size_t gaddr = (rowbase + q0 + orow) * Hdim + colbase + oc;
    #pragma unroll
    for (int i = 0; i < 8; ++i) {
        float4 vv = *(float4*)&ot[orow * 68 + oc + i * 4];
        ushort4 hh, ll;
        hh.x = f2bf(vv.x); ll.x = f2bf(vv.x - bf2f(hh.x));
        hh.y = f2bf(vv.y); ll.y = f2bf(vv.y - bf2f(hh.y));
        hh.z = f2bf(vv.z); ll.z = f2bf(vv.z - bf2f(hh.z));
        hh.w = f2bf(vv.w); ll.w = f2bf(vv.w - bf2f(hh.w));
        *(ushort4*)(Oh + gaddr + i * 4) = hh;
        *(ushort4*)(Ol + gaddr + i * 4) = ll;
    }
}

// ---------------------------------------------------------------------------
// Classifier: logits[b,n] = dot(x[b,0,:], Wc[n,:]) + bc[n]  (x from hi/lo)
// ---------------------------------------------------------------------------
__global__ void cls_kernel(const ushort* __restrict__ xh, const ushort* __restrict__ xl,
                           const float* __restrict__ Wc,
                           const float* __restrict__ bc,
                           float* __restrict__ out) {
    const int b = blockIdx.x >> 1;
    const int n = blockIdx.x & 1;
    const int t = threadIdx.x;
    const ushort* ph = xh + (size_t)b * Ss * Hdim;   // row s=0
    const ushort* pl = xl + (size_t)b * Ss * Hdim;
    const float* pw = Wc + (size_t)n * Hdim;
    float partial = 0.f;
    for (int k = t; k < Hdim; k += 256)
        partial = fmaf(bf2f(ph[k]) + bf2f(pl[k]), pw[k], partial);
    __shared__ float red[256];
    red[t] = partial;
    __syncthreads();
    for (int off = 128; off > 0; off >>= 1) {
        if (t < off) red[t] += red[t + off];
        __syncthreads();
    }
    if (t == 0) out[blockIdx.x] = red[0] + bc[n];
}

// ---------------------------------------------------------------------------
extern "C" void kernel_launch(void* const* d_in, const int* in_sizes, int n_in,
                              void* d_out, int out_size, void* d_ws, size_t ws_size,
                              hipStream_t stream) {
    const int*   ids = (const int*)d_in[0];
    const float* emb = (const float*)d_in[1];
    const float* Wq  = (const float*)d_in[2];
    const float* bq  = (const float*)d_in[3];
    const float* Wk  = (const float*)d_in[4];
    const float* bk  = (const float*)d_in[5];
    const float* Wv  = (const float*)d_in[6];
    const float* bv  = (const float*)d_in[7];
    const float* Wi  = (const float*)d_in[8];
    const float* bi  = (const float*)d_in[9];
    const float* Wo  = (const float*)d_in[10];
    const float* bo  = (const float*)d_in[11];
    const float* Wc  = (const float*)d_in[12];
    const float* bc  = (const float*)d_in[13];
    float* out = (float*)d_out;

    const size_t F  = (size_t)Mm * Hdim;      // 3,145,728
    const size_t WS = (size_t)Hdim * Hdim;    // 589,824

    ushort* hb_hi  = (ushort*)d_ws;
    ushort* hb_lo  = hb_hi + F;
    ushort* qkv_hi = hb_lo + F;               // 3F
    ushort* qkv_lo = qkv_hi + 3 * F;          // 3F
    ushort* ah     = qkv_lo + 3 * F;
    ushort* al     = ah + F;
    ushort* ih     = al + F;
    ushort* il     = ih + F;
    ushort* w_hi   = il + F;                  // 5*WS per layer (reused)
    ushort* w_lo   = w_hi + 5 * WS;

    embed_kernel<<<Mm, 192, 0, stream>>>(ids, emb, hb_hi, hb_lo);

    for (int l = 0; l < NLAYER; ++l) {
        const size_t off = (size_t)l * WS;
        split5_kernel<<<2880, 256, 0, stream>>>(Wq + off, Wk + off, Wv + off,
                                                Wi + off, Wo + off, w_hi, w_lo);
        // fused QKV: W rows 0..2303 = Wq|Wk|Wv (contiguous in w_hi)
        gemm_mfma<<<dim3(Mm/64, 2304/128), 256, 0, stream>>>(
            hb_hi, hb_lo, w_hi, w_lo,
            bq + l*Hdim, bk + l*Hdim, bv + l*Hdim,
            nullptr, nullptr, qkv_hi, qkv_lo, 0, F);
        attn_mfma<<<dim3(Ss/128, NH, Bb), 256, 0, stream>>>(
            qkv_hi, qkv_lo, qkv_hi + F, qkv_lo + F, qkv_hi + 2*F, qkv_lo + 2*F,
            ah, al);
        gemm_mfma<<<dim3(Mm/64, Hdim/128), 256, 0, stream>>>(
            ah, al, w_hi + 3*WS, w_lo + 3*WS,
            bi + l*Hdim, bi + l*Hdim, bi + l*Hdim,
            nullptr, nullptr, ih, il, 1, 0);
        gemm_mfma<<<dim3(Mm/64, Hdim/128), 256, 0, stream>>>(
            ih, il, w_hi + 4*WS, w_lo + 4*WS,
            bo + l*Hdim, bo + l*Hdim, bo + l*Hdim,
            ah, al, hb_hi, hb_lo, 0, 0);
    }

    cls_kernel<<<Bb * NL, 256, 0, stream>>>(hb_hi, hb_lo, Wc, bc, out);
}

// Round 7
// 721.929 us; speedup vs baseline: 6.7168x; 1.0231x over previous
//
#include <hip/hip_runtime.h>
#include <hip/hip_bf16.h>
#include <math.h>

// Problem constants
constexpr int Hdim = 768;
constexpr int NH   = 12;
constexpr int HD   = 64;
constexpr int NLAYER = 4;
constexpr int Bb   = 4;
constexpr int Ss   = 1024;
constexpr int Mm   = Bb * Ss;   // 4096 rows
constexpr int NL   = 2;
constexpr int PL   = Bb * NH * Ss;   // 49152 q-rows total

typedef short  bf16x8 __attribute__((ext_vector_type(8)));
typedef short  bf16x4 __attribute__((ext_vector_type(4)));
typedef float  f32x4  __attribute__((ext_vector_type(4)));

__device__ __forceinline__ ushort f2bf(float f) {
    uint u = __float_as_uint(f);
    u += 0x7FFF + ((u >> 16) & 1);          // round-to-nearest-even
    return (ushort)(u >> 16);
}
__device__ __forceinline__ float bf2f(ushort h) {
    return __uint_as_float(((uint)h) << 16);
}

// 16x16x16 bf16 MFMA (K=16). Builtin when available; else tied-accumulator asm.
__device__ __forceinline__ f32x4 mfma16(bf16x4 a, bf16x4 b, f32x4 c) {
#if __has_builtin(__builtin_amdgcn_mfma_f32_16x16x16bf16_1k)
    return __builtin_amdgcn_mfma_f32_16x16x16bf16_1k(a, b, c, 0, 0, 0);
#else
    asm("v_mfma_f32_16x16x16_bf16 %0, %1, %2, %0" : "+v"(c) : "v"(a), "v"(b));
    return c;
#endif
}

// async global->LDS, 16B per lane; LDS dest = wave-uniform base + lane*16.
__device__ __forceinline__ void gload16(const void* g, void* l) {
    __builtin_amdgcn_global_load_lds(
        (const __attribute__((address_space(1))) unsigned int*)g,
        (__attribute__((address_space(3))) unsigned int*)l, 16, 0, 0);
}

// ---------------------------------------------------------------------------
// Embedding gather: emits bf16 hi/lo split of x.
// ---------------------------------------------------------------------------
__global__ void embed_kernel(const int* __restrict__ ids,
                             const float* __restrict__ emb,
                             ushort* __restrict__ xh, ushort* __restrict__ xl) {
    int row = blockIdx.x;              // 0..4095
    int t = threadIdx.x;               // 0..191
    int id = ids[row];
    float4 v = ((const float4*)(emb + (size_t)id * Hdim))[t];
    ushort4 h, l;
    h.x = f2bf(v.x); l.x = f2bf(v.x - bf2f(h.x));
    h.y = f2bf(v.y); l.y = f2bf(v.y - bf2f(h.y));
    h.z = f2bf(v.z); l.z = f2bf(v.z - bf2f(h.z));
    h.w = f2bf(v.w); l.w = f2bf(v.w - bf2f(h.w));
    *(ushort4*)(xh + (size_t)row * Hdim + t * 4) = h;
    *(ushort4*)(xl + (size_t)row * Hdim + t * 4) = l;
}

// ---------------------------------------------------------------------------
// Split one layer's five weight matrices (768x768) into bf16 hi/lo.
// ---------------------------------------------------------------------------
__global__ void split5_kernel(const float* __restrict__ w0, const float* __restrict__ w1,
                              const float* __restrict__ w2, const float* __restrict__ w3,
                              const float* __restrict__ w4,
                              ushort* __restrict__ hi, ushort* __restrict__ lo) {
    int i = blockIdx.x * 256 + threadIdx.x;   // quad index
    int which = i / 147456;
    int j = i - which * 147456;
    const float* src = which == 0 ? w0 : which == 1 ? w1 : which == 2 ? w2
                     : which == 3 ? w3 : w4;
    float4 v = ((const float4*)src)[j];
    ushort4 h, l;
    h.x = f2bf(v.x); l.x = f2bf(v.x - bf2f(h.x));
    h.y = f2bf(v.y); l.y = f2bf(v.y - bf2f(h.y));
    h.z = f2bf(v.z); l.z = f2bf(v.z - bf2f(h.z));
    h.w = f2bf(v.w); l.w = f2bf(v.w - bf2f(h.w));
    size_t o = (size_t)which * 589824 + (size_t)j * 4;
    *(ushort4*)(hi + o) = h;
    *(ushort4*)(lo + o) = l;
}

// ---------------------------------------------------------------------------
// Split-bf16 MFMA GEMM: BM=64, BN=NFR*32, BK=64, 4 waves (wave 32 x NFR*16).
// NFR=4 -> BN=128 (QKV fused, N=2304); NFR=2 -> BN=64 (Wi/Wo, grid 768).
// ---------------------------------------------------------------------------
template<int NFR>
__global__ __launch_bounds__(256) void gemm_mfma(
    const ushort* __restrict__ Xh, const ushort* __restrict__ Xl,
    const ushort* __restrict__ Wh, const ushort* __restrict__ Wl,
    const float* __restrict__ b0, const float* __restrict__ b1,
    const float* __restrict__ b2,
    const ushort* __restrict__ residH, const ushort* __restrict__ residL,
    ushort* __restrict__ Yh, ushort* __restrict__ Yl,
    int relu, size_t outSeg)
{
    constexpr int BOFF = 8192;                 // B-hi base (ushorts)
    constexpr int BLO  = 8192 + NFR * 2048;    // B-lo base
    __shared__ ushort lds[8192 + NFR * 4096];

    const int tid = threadIdx.x;
    const int lane = tid & 63, w = tid >> 6;
    const int l15 = lane & 15, g = lane >> 4;
    const int wr = w >> 1, wc = w & 1;
    const int m0 = blockIdx.x * 64, n0 = blockIdx.y * (NFR * 32);

    const int srow = lane >> 3;                    // 0..7
    const int sswz = 8 * ((lane & 7) ^ srow);      // swizzled slot (ushorts)
    const ushort* pAh = Xh + (size_t)(m0 + w*16 + srow) * Hdim + sswz;
    const ushort* pAl = Xl + (size_t)(m0 + w*16 + srow) * Hdim + sswz;
    const ushort* pBh = Wh + (size_t)(n0 + w*(NFR*8) + srow) * Hdim + sswz;
    const ushort* pBl = Wl + (size_t)(n0 + w*(NFR*8) + srow) * Hdim + sswz;
    ushort* lAh = &lds[0]    + w * 1024;
    ushort* lAl = &lds[4096] + w * 1024;
    ushort* lBh = &lds[BOFF] + w * (NFR * 512);
    ushort* lBl = &lds[BLO]  + w * (NFR * 512);

    f32x4 acc[2][NFR];
    #pragma unroll
    for (int m = 0; m < 2; ++m)
        #pragma unroll
        for (int n = 0; n < NFR; ++n) acc[m][n] = (f32x4){0.f, 0.f, 0.f, 0.f};

    const int fsw = l15 & 7;

    for (int k0 = 0; k0 < Hdim; k0 += 64) {
        __syncthreads();
        gload16(pAh + k0,          lAh);
        gload16(pAh + k0 + 8*Hdim, lAh + 512);
        gload16(pAl + k0,          lAl);
        gload16(pAl + k0 + 8*Hdim, lAl + 512);
        #pragma unroll
        for (int j = 0; j < NFR; ++j) {
            gload16(pBh + k0 + j*8*Hdim, lBh + j*512);
            gload16(pBl + k0 + j*8*Hdim, lBl + j*512);
        }
        __syncthreads();

        #pragma unroll
        for (int ks = 0; ks < 2; ++ks) {
            const int so = 8 * ((ks*4 + g) ^ fsw);
            bf16x8 xh_[2], xl_[2];
            #pragma unroll
            for (int m = 0; m < 2; ++m) {
                const int off = (wr*32 + m*16 + l15) * 64 + so;
                xh_[m] = *(const bf16x8*)&lds[off];
                xl_[m] = *(const bf16x8*)&lds[4096 + off];
            }
            #pragma unroll
            for (int n = 0; n < NFR; ++n) {
                const int off = (wc*(NFR*16) + n*16 + l15) * 64 + so;
                bf16x8 wh_ = *(const bf16x8*)&lds[BOFF + off];
                bf16x8 wl_ = *(const bf16x8*)&lds[BLO + off];
                #pragma unroll
                for (int m = 0; m < 2; ++m) {
                    acc[m][n] = __builtin_amdgcn_mfma_f32_16x16x32_bf16(xh_[m], wh_, acc[m][n], 0, 0, 0);
                    acc[m][n] = __builtin_amdgcn_mfma_f32_16x16x32_bf16(xh_[m], wl_, acc[m][n], 0, 0, 0);
                    acc[m][n] = __builtin_amdgcn_mfma_f32_16x16x32_bf16(xl_[m], wh_, acc[m][n], 0, 0, 0);
                }
            }
        }
    }

    // Epilogue. D layout: col=lane&15, row=(lane>>4)*4+reg.
    const int rb = m0 + wr*32 + g*4;
    #pragma unroll
    for (int n = 0; n < NFR; ++n) {
        const int col = n0 + wc*(NFR*16) + n*16 + l15;
        const int seg = col / Hdim;
        const int lc  = col - seg * Hdim;
        const float bias = (seg == 0 ? b0 : seg == 1 ? b1 : b2)[lc];
        #pragma unroll
        for (int m = 0; m < 2; ++m) {
            #pragma unroll
            for (int r = 0; r < 4; ++r) {
                const size_t idx = (size_t)seg * outSeg + (size_t)(rb + m*16 + r) * Hdim + lc;
                float v = acc[m][n][r] + bias;
                if (relu) v = v > 0.f ? v : 0.f;
                if (residH) v += bf2f(residH[idx]) + bf2f(residL[idx]);
                const ushort hh = f2bf(v);
                Yh[idx] = hh;
                Yl[idx] = f2bf(v - bf2f(hh));
            }
        }
    }
}

// ---------------------------------------------------------------------------
// MFMA flash attention partials, KV-split 2-way. Block = 128 q rows x 512 KV
// rows (part = blockIdx.x&1). K double-buffered via global_load_lds prefetch;
// V reg-prefetched (issue early, LDS-write after the PV barrier). Writes
// unnormalized O^T partials + (m, l) per q-row; merge_kernel combines.
// LDS map (ushorts): K0h@0 K0l@4096 K1h@8192 K1l@12288 Vth@16384 Vtl@20992.
// ---------------------------------------------------------------------------
__global__ __launch_bounds__(256, 3) void attn_mfma(
    const ushort* __restrict__ Qh, const ushort* __restrict__ Ql,
    const ushort* __restrict__ Kh, const ushort* __restrict__ Kl,
    const ushort* __restrict__ Vh, const ushort* __restrict__ Vl,
    float* __restrict__ Op0, float* __restrict__ Op1,
    float* __restrict__ Mp, float* __restrict__ Lp)
{
    __shared__ ushort sm[25600];   // 51200 B

    const int tid  = threadIdx.x;
    const int lane = tid & 63, wid = tid >> 6;
    const int l15  = lane & 15, g = lane >> 4;
    const int qtile = blockIdx.x >> 1, part = blockIdx.x & 1;
    const int h = blockIdx.y, b = blockIdx.z;

    const size_t rowbase = (size_t)b * Ss;
    const int    colbase = h * HD;
    const int    q0 = qtile * 128 + wid * 32;
    const int    kv0 = part * 512;

    // Hoisted Q fragments [qfrag][kstep][hi/lo]
    bf16x8 qf[2][2][2];
    #pragma unroll
    for (int nf = 0; nf < 2; ++nf) {
        const size_t r = (rowbase + q0 + nf * 16 + l15) * Hdim + colbase;
        #pragma unroll
        for (int ks = 0; ks < 2; ++ks) {
            qf[nf][ks][0] = *(const bf16x8*)(Qh + r + ks * 32 + g * 8);
            qf[nf][ks][1] = *(const bf16x8*)(Ql + r + ks * 32 + g * 8);
        }
    }

    f32x4 accO[4][2];
    #pragma unroll
    for (int mf = 0; mf < 4; ++mf)
        #pragma unroll
        for (int nf = 0; nf < 2; ++nf) accO[mf][nf] = (f32x4){0.f, 0.f, 0.f, 0.f};
    float mrun[2] = {-1e30f, -1e30f}, lrun[2] = {0.f, 0.f};

    // K staging constants
    const int s8 = lane >> 3;
    const int kswz = 8 * ((lane & 7) ^ s8);
    const ushort* gK0 = Kh + (rowbase + kv0 + wid*16 + s8) * Hdim + colbase + kswz;
    const ushort* gK1 = Kl + (rowbase + kv0 + wid*16 + s8) * Hdim + colbase + kswz;

    // V staging constants
    const int vrow = tid >> 2, vsp = tid & 3;
    const int kx = vrow ^ (vsp << 4);
    const size_t vgbase = (rowbase + kv0 + vrow) * Hdim + colbase;
    uint4 vrh[2], vrl[2];

    const int fsw = l15 & 7;

    // ---- prologue: stage tile 0 ------------------------------------------
    gload16(gK0,          &sm[0]    + wid*1024);
    gload16(gK0 + 8*Hdim, &sm[0]    + wid*1024 + 512);
    gload16(gK1,          &sm[4096] + wid*1024);
    gload16(gK1 + 8*Hdim, &sm[4096] + wid*1024 + 512);
    #pragma unroll
    for (int u = 0; u < 2; ++u) {
        vrh[u] = *(const uint4*)(Vh + vgbase + (vsp*2 + u) * 8);
        vrl[u] = *(const uint4*)(Vl + vgbase + (vsp*2 + u) * 8);
    }
    __syncthreads();
    #pragma unroll
    for (int u = 0; u < 2; ++u) {
        const int seg = vsp * 2 + u;
        const ushort* hs = (const ushort*)&vrh[u];
        const ushort* ls = (const ushort*)&vrl[u];
        #pragma unroll
        for (int j = 0; j < 8; ++j) {
            sm[16384 + (seg*8 + j) * 72 + kx] = hs[j];
            sm[20992 + (seg*8 + j) * 72 + kx] = ls[j];
        }
    }
    __syncthreads();

    for (int t = 0; t < 8; ++t) {
        const int cur = (t & 1) * 8192;
        // ---- prefetch tile t+1 (K -> other LDS buf; V -> regs) -----------
        if (t < 7) {
            const int nxt = ((t + 1) & 1) * 8192;
            const size_t ko = (size_t)((t + 1) * 64) * Hdim;
            gload16(gK0 + ko,          &sm[nxt]        + wid*1024);
            gload16(gK0 + ko + 8*Hdim, &sm[nxt]        + wid*1024 + 512);
            gload16(gK1 + ko,          &sm[nxt + 4096] + wid*1024);
            gload16(gK1 + ko + 8*Hdim, &sm[nxt + 4096] + wid*1024 + 512);
            const size_t vg = vgbase + (size_t)((t + 1) * 64) * Hdim;
            #pragma unroll
            for (int u = 0; u < 2; ++u) {
                vrh[u] = *(const uint4*)(Vh + vg + (vsp*2 + u) * 8);
                vrl[u] = *(const uint4*)(Vl + vg + (vsp*2 + u) * 8);
            }
        }

        // ---- S^T = K · Q^T (split 3-term) --------------------------------
        f32x4 sc[4][2];
        #pragma unroll
        for (int m = 0; m < 4; ++m)
            #pragma unroll
            for (int nf = 0; nf < 2; ++nf) sc[m][nf] = (f32x4){0.f, 0.f, 0.f, 0.f};
        __builtin_amdgcn_s_setprio(1);
        #pragma unroll
        for (int ks = 0; ks < 2; ++ks) {
            const int so = 8 * ((ks*4 + g) ^ fsw);
            #pragma unroll
            for (int m = 0; m < 4; ++m) {
                const int off = cur + (m * 16 + l15) * 64 + so;
                bf16x8 kh_ = *(const bf16x8*)&sm[off];
                bf16x8 kl_ = *(const bf16x8*)&sm[off + 4096];
                #pragma unroll
                for (int nf = 0; nf < 2; ++nf) {
                    sc[m][nf] = __builtin_amdgcn_mfma_f32_16x16x32_bf16(kh_, qf[nf][ks][0], sc[m][nf], 0, 0, 0);
                    sc[m][nf] = __builtin_amdgcn_mfma_f32_16x16x32_bf16(kh_, qf[nf][ks][1], sc[m][nf], 0, 0, 0);
                    sc[m][nf] = __builtin_amdgcn_mfma_f32_16x16x32_bf16(kl_, qf[nf][ks][0], sc[m][nf], 0, 0, 0);
                }
            }
        }
        __builtin_amdgcn_s_setprio(0);

        // ---- online softmax (lane-local per q) + pack P hi/lo ------------
        bf16x4 pbh[4][2], pbl[4][2];
        #pragma unroll
        for (int nf = 0; nf < 2; ++nf) {
            float tmax = -1e30f;
            #pragma unroll
            for (int m = 0; m < 4; ++m)
                #pragma unroll
                for (int r = 0; r < 4; ++r) {
                    sc[m][nf][r] *= 0.125f;
                    tmax = fmaxf(tmax, sc[m][nf][r]);
                }
            tmax = fmaxf(tmax, __shfl_xor(tmax, 16));
            tmax = fmaxf(tmax, __shfl_xor(tmax, 32));
            const float mnew = fmaxf(mrun[nf], tmax);
            const float corr = __expf(mrun[nf] - mnew);
            mrun[nf] = mnew;
            float psum = 0.f;
            #pragma unroll
            for (int m = 0; m < 4; ++m)
                #pragma unroll
                for (int r = 0; r < 4; ++r) {
                    const float p = __expf(sc[m][nf][r] - mnew);
                    sc[m][nf][r] = p;
                    psum += p;
                }
            psum += __shfl_xor(psum, 16);
            psum += __shfl_xor(psum, 32);
            lrun[nf] = lrun[nf] * corr + psum;
            #pragma unroll
            for (int mf = 0; mf < 4; ++mf) {
                accO[mf][nf][0] *= corr; accO[mf][nf][1] *= corr;
                accO[mf][nf][2] *= corr; accO[mf][nf][3] *= corr;
            }
            #pragma unroll
            for (int kt = 0; kt < 4; ++kt)
                #pragma unroll
                for (int r = 0; r < 4; ++r) {
                    const float p = sc[kt][nf][r];
                    const ushort hh = f2bf(p);
                    pbh[kt][nf][r] = (short)hh;
                    pbl[kt][nf][r] = (short)f2bf(p - bf2f(hh));
                }
        }

        // ---- O^T += V^T · P^T (16x16x16, split 3-term) -------------------
        __builtin_amdgcn_s_setprio(1);
        #pragma unroll
        for (int kt = 0; kt < 4; ++kt)
            #pragma unroll
            for (int mf = 0; mf < 4; ++mf) {
                const int voff = (mf * 16 + l15) * 72 + ((kt ^ mf) * 16 + g * 4);
                bf16x4 vh_ = *(const bf16x4*)&sm[16384 + voff];
                bf16x4 vl_ = *(const bf16x4*)&sm[20992 + voff];
                #pragma unroll
                for (int nf = 0; nf < 2; ++nf) {
                    accO[mf][nf] = mfma16(vh_, pbh[kt][nf], accO[mf][nf]);
                    accO[mf][nf] = mfma16(vh_, pbl[kt][nf], accO[mf][nf]);
                    accO[mf][nf] = mfma16(vl_, pbh[kt][nf], accO[mf][nf]);
                }
            }
        __builtin_amdgcn_s_setprio(0);

        __syncthreads();   // drains K(t+1) gloads + V regs; all PV reads done
        if (t < 7) {
            #pragma unroll
            for (int u = 0; u < 2; ++u) {
                const int seg = vsp * 2 + u;
                const ushort* hs = (const ushort*)&vrh[u];
                const ushort* ls = (const ushort*)&vrl[u];
                #pragma unroll
                for (int j = 0; j < 8; ++j) {
                    sm[16384 + (seg*8 + j) * 72 + kx] = hs[j];
                    sm[20992 + (seg*8 + j) * 72 + kx] = ls[j];
                }
            }
        }
        __syncthreads();
    }

    // ---- epilogue: transpose raw O^T through LDS, write fp32 partials ----
    float* ot = (float*)sm + wid * 2176;   // 32 rows x stride 68
    #pragma unroll
    for (int nf = 0; nf < 2; ++nf) {
        #pragma unroll
        for (int mf = 0; mf < 4; ++mf)
            #pragma unroll
            for (int r = 0; r < 4; ++r)
                ot[(nf * 16 + l15) * 68 + mf * 16 + g * 4 + r] = accO[mf][nf][r];
    }
    if (g == 0) {
        #pragma unroll
        for (int nf = 0; nf < 2; ++nf) {
            const size_t idx = (size_t)part * PL +
                (((size_t)b * NH + h) * Ss + q0 + nf * 16 + l15);
            Mp[idx] = mrun[nf];
            Lp[idx] = lrun[nf];
        }
    }
    __syncthreads();
    float* Op = part ? Op1 : Op0;
    const int orow = lane >> 1, oc = (lane & 1) * 32;
    const size_t pbase = (((size_t)b * NH + h) * Ss + q0 + orow) * 64 + oc;
    #pragma unroll
    for (int i = 0; i < 8; ++i)
        *(float4*)(Op + pbase + i * 4) = *(float4*)&ot[orow * 68 + oc + i * 4];
}

// ---------------------------------------------------------------------------
// Merge the two KV-split partials -> attn output (bf16 hi/lo).
// ---------------------------------------------------------------------------
__global__ void merge_kernel(const float* __restrict__ Op0, const float* __restrict__ Op1,
                             const float* __restrict__ Mp, const float* __restrict__ Lp,
                             ushort* __restrict__ ah, ushort* __restrict__ al) {
    const int id = blockIdx.x * 256 + threadIdx.x;   // 0..196607
    const int idx = id >> 2, dseg = id & 3;
    const int b = idx / (NH * Ss);
    const int rem = idx - b * NH * Ss;
    const int h = rem / Ss, q = rem - h * Ss;
    const float m0 = Mp[idx], m1 = Mp[PL + idx];
    const float l0 = Lp[idx], l1 = Lp[PL + idx];
    const float M  = fmaxf(m0, m1);
    const float e0 = __expf(m0 - M), e1 = __expf(m1 - M);
    const float inv = 1.f / (l0 * e0 + l1 * e1);
    const size_t pb = (size_t)idx * 64 + dseg * 16;
    const size_t ga = ((size_t)(b * Ss + q)) * Hdim + h * 64 + dseg * 16;
    #pragma unroll
    for (int i = 0; i < 4; ++i) {
        float4 a = *(const float4*)(Op0 + pb + i * 4);
        float4 c = *(const float4*)(Op1 + pb + i * 4);
        float4 o;
        o.x = (a.x * e0 + c.x * e1) * inv;
        o.y = (a.y * e0 + c.y * e1) * inv;
        o.z = (a.z * e0 + c.z * e1) * inv;
        o.w = (a.w * e0 + c.w * e1) * inv;
        ushort4 hh, ll;
        hh.x = f2bf(o.x); ll.x = f2bf(o.x - bf2f(hh.x));
        hh.y = f2bf(o.y); ll.y = f2bf(o.y - bf2f(hh.y));
        hh.z = f2bf(o.z); ll.z = f2bf(o.z - bf2f(hh.z));
        hh.w = f2bf(o.w); ll.w = f2bf(o.w - bf2f(hh.w));
        *(ushort4*)(ah + ga + i * 4) = hh;
        *(ushort4*)(al + ga + i * 4) = ll;
    }
}

// ---------------------------------------------------------------------------
// Classifier: logits[b,n] = dot(x[b,0,:], Wc[n,:]) + bc[n]  (x from hi/lo)
// ---------------------------------------------------------------------------
__global__ void cls_kernel(const ushort* __restrict__ xh, const ushort* __restrict__ xl,
                           const float* __restrict__ Wc,
                           const float* __restrict__ bc,
                           float* __restrict__ out) {
    const int b = blockIdx.x >> 1;
    const int n = blockIdx.x & 1;
    const int t = threadIdx.x;
    const ushort* ph = xh + (size_t)b * Ss * Hdim;   // row s=0
    const ushort* pl = xl + (size_t)b * Ss * Hdim;
    const float* pw = Wc + (size_t)n * Hdim;
    float partial = 0.f;
    for (int k = t; k < Hdim; k += 256)
        partial = fmaf(bf2f(ph[k]) + bf2f(pl[k]), pw[k], partial);
    __shared__ float red[256];
    red[t] = partial;
    __syncthreads();
    for (int off = 128; off > 0; off >>= 1) {
        if (t < off) red[t] += red[t + off];
        __syncthreads();
    }
    if (t == 0) out[blockIdx.x] = red[0] + bc[n];
}

// ---------------------------------------------------------------------------
extern "C" void kernel_launch(void* const* d_in, const int* in_sizes, int n_in,
                              void* d_out, int out_size, void* d_ws, size_t ws_size,
                              hipStream_t stream) {
    const int*   ids = (const int*)d_in[0];
    const float* emb = (const float*)d_in[1];
    const float* Wq  = (const float*)d_in[2];
    const float* bq  = (const float*)d_in[3];
    const float* Wk  = (const float*)d_in[4];
    const float* bk  = (const float*)d_in[5];
    const float* Wv  = (const float*)d_in[6];
    const float* bv  = (const float*)d_in[7];
    const float* Wi  = (const float*)d_in[8];
    const float* bi  = (const float*)d_in[9];
    const float* Wo  = (const float*)d_in[10];
    const float* bo  = (const float*)d_in[11];
    const float* Wc  = (const float*)d_in[12];
    const float* bc  = (const float*)d_in[13];
    float* out = (float*)d_out;

    const size_t F  = (size_t)Mm * Hdim;      // 3,145,728
    const size_t WS = (size_t)Hdim * Hdim;    // 589,824

    ushort* hb_hi  = (ushort*)d_ws;
    ushort* hb_lo  = hb_hi + F;
    ushort* qkv_hi = hb_lo + F;               // 3F
    ushort* qkv_lo = qkv_hi + 3 * F;          // 3F
    ushort* ah     = qkv_lo + 3 * F;
    ushort* al     = ah + F;
    ushort* ih     = al + F;
    ushort* il     = ih + F;
    ushort* w_hi   = il + F;                  // 5*WS per layer (reused)
    ushort* w_lo   = w_hi + 5 * WS;
    float*  Mp     = (float*)(w_lo + 5 * WS); // [2][PL]
    float*  Lp     = Mp + 2 * PL;             // [2][PL]
    // fp32 attention partials overlay dead regions:
    float*  Op0    = (float*)hb_hi;           // 3.1M f32 over hb (dead during attn)
    float*  Op1    = (float*)ih;              // 3.1M f32 over ih/il (dead during attn)

    embed_kernel<<<Mm, 192, 0, stream>>>(ids, emb, hb_hi, hb_lo);

    for (int l = 0; l < NLAYER; ++l) {
        const size_t off = (size_t)l * WS;
        split5_kernel<<<2880, 256, 0, stream>>>(Wq + off, Wk + off, Wv + off,
                                                Wi + off, Wo + off, w_hi, w_lo);
        // fused QKV: W rows 0..2303 = Wq|Wk|Wv (contiguous in w_hi)
        gemm_mfma<4><<<dim3(Mm/64, 2304/128), 256, 0, stream>>>(
            hb_hi, hb_lo, w_hi, w_lo,
            bq + l*Hdim, bk + l*Hdim, bv + l*Hdim,
            nullptr, nullptr, qkv_hi, qkv_lo, 0, F);
        attn_mfma<<<dim3(16, NH, Bb), 256, 0, stream>>>(
            qkv_hi, qkv_lo, qkv_hi + F, qkv_lo + F, qkv_hi + 2*F, qkv_lo + 2*F,
            Op0, Op1, Mp, Lp);
        merge_kernel<<<PL * 4 / 256, 256, 0, stream>>>(Op0, Op1, Mp, Lp, ah, al);
        gemm_mfma<2><<<dim3(Mm/64, Hdim/64), 256, 0, stream>>>(
            ah, al, w_hi + 3*WS, w_lo + 3*WS,
            bi + l*Hdim, bi + l*Hdim, bi + l*Hdim,
            nullptr, nullptr, ih, il, 1, 0);
        gemm_mfma<2><<<dim3(Mm/64, Hdim/64), 256, 0, stream>>>(
            ih, il, w_hi + 4*WS, w_lo + 4*WS,
            bo + l*Hdim, bo + l*Hdim, bo + l*Hdim,
            ah, al, hb_hi, hb_lo, 0, 0);
    }

    cls_kernel<<<Bb * NL, 256, 0, stream>>>(hb_hi, hb_lo, Wc, bc, out);
}

// Round 8
// 589.218 us; speedup vs baseline: 8.2296x; 1.2252x over previous
//
#include <hip/hip_runtime.h>
#include <hip/hip_bf16.h>
#include <math.h>

// Problem constants
constexpr int Hdim = 768;
constexpr int NH   = 12;
constexpr int HD   = 64;
constexpr int NLAYER = 4;
constexpr int Bb   = 4;
constexpr int Ss   = 1024;
constexpr int Mm   = Bb * Ss;   // 4096 rows
constexpr int NL   = 2;
constexpr int PL   = Bb * NH * Ss;   // 49152 q-rows total

typedef short  bf16x8 __attribute__((ext_vector_type(8)));
typedef short  bf16x4 __attribute__((ext_vector_type(4)));
typedef float  f32x4  __attribute__((ext_vector_type(4)));

__device__ __forceinline__ ushort f2bf(float f) {
    uint u = __float_as_uint(f);
    u += 0x7FFF + ((u >> 16) & 1);          // round-to-nearest-even
    return (ushort)(u >> 16);
}
__device__ __forceinline__ float bf2f(ushort h) {
    return __uint_as_float(((uint)h) << 16);
}

// 16x16x16 bf16 MFMA (K=16). Builtin when available; else tied-accumulator asm.
__device__ __forceinline__ f32x4 mfma16(bf16x4 a, bf16x4 b, f32x4 c) {
#if __has_builtin(__builtin_amdgcn_mfma_f32_16x16x16bf16_1k)
    return __builtin_amdgcn_mfma_f32_16x16x16bf16_1k(a, b, c, 0, 0, 0);
#else
    asm("v_mfma_f32_16x16x16_bf16 %0, %1, %2, %0" : "+v"(c) : "v"(a), "v"(b));
    return c;
#endif
}

// async global->LDS, 16B per lane; LDS dest = wave-uniform base + lane*16.
__device__ __forceinline__ void gload16(const void* g, void* l) {
    __builtin_amdgcn_global_load_lds(
        (const __attribute__((address_space(1))) unsigned int*)g,
        (__attribute__((address_space(3))) unsigned int*)l, 16, 0, 0);
}

// ---------------------------------------------------------------------------
// Embedding gather: emits bf16 hi/lo split of x.
// ---------------------------------------------------------------------------
__global__ void embed_kernel(const int* __restrict__ ids,
                             const float* __restrict__ emb,
                             ushort* __restrict__ xh, ushort* __restrict__ xl) {
    int row = blockIdx.x;              // 0..4095
    int t = threadIdx.x;               // 0..191
    int id = ids[row];
    float4 v = ((const float4*)(emb + (size_t)id * Hdim))[t];
    ushort4 h, l;
    h.x = f2bf(v.x); l.x = f2bf(v.x - bf2f(h.x));
    h.y = f2bf(v.y); l.y = f2bf(v.y - bf2f(h.y));
    h.z = f2bf(v.z); l.z = f2bf(v.z - bf2f(h.z));
    h.w = f2bf(v.w); l.w = f2bf(v.w - bf2f(h.w));
    *(ushort4*)(xh + (size_t)row * Hdim + t * 4) = h;
    *(ushort4*)(xl + (size_t)row * Hdim + t * 4) = l;
}

// ---------------------------------------------------------------------------
// Split one layer's five weight matrices (768x768) into bf16 hi/lo.
// ---------------------------------------------------------------------------
__global__ void split5_kernel(const float* __restrict__ w0, const float* __restrict__ w1,
                              const float* __restrict__ w2, const float* __restrict__ w3,
                              const float* __restrict__ w4,
                              ushort* __restrict__ hi, ushort* __restrict__ lo) {
    int i = blockIdx.x * 256 + threadIdx.x;   // quad index
    int which = i / 147456;
    int j = i - which * 147456;
    const float* src = which == 0 ? w0 : which == 1 ? w1 : which == 2 ? w2
                     : which == 3 ? w3 : w4;
    float4 v = ((const float4*)src)[j];
    ushort4 h, l;
    h.x = f2bf(v.x); l.x = f2bf(v.x - bf2f(h.x));
    h.y = f2bf(v.y); l.y = f2bf(v.y - bf2f(h.y));
    h.z = f2bf(v.z); l.z = f2bf(v.z - bf2f(h.z));
    h.w = f2bf(v.w); l.w = f2bf(v.w - bf2f(h.w));
    size_t o = (size_t)which * 589824 + (size_t)j * 4;
    *(ushort4*)(hi + o) = h;
    *(ushort4*)(lo + o) = l;
}

// ---------------------------------------------------------------------------
// Split-bf16 MFMA GEMM: BM=64, BN=NFR*32, BK=64, 4 waves (wave 32 x NFR*16).
// NFR=4 -> BN=128 (QKV fused, N=2304); NFR=2 -> BN=64 (Wi/Wo, grid 768).
// qscale multiplies seg-0 output (folds the attention 1/sqrt(HD) into Q).
// ---------------------------------------------------------------------------
template<int NFR>
__global__ __launch_bounds__(256) void gemm_mfma(
    const ushort* __restrict__ Xh, const ushort* __restrict__ Xl,
    const ushort* __restrict__ Wh, const ushort* __restrict__ Wl,
    const float* __restrict__ b0, const float* __restrict__ b1,
    const float* __restrict__ b2,
    const ushort* __restrict__ residH, const ushort* __restrict__ residL,
    ushort* __restrict__ Yh, ushort* __restrict__ Yl,
    int relu, size_t outSeg, float qscale)
{
    constexpr int BOFF = 8192;                 // B-hi base (ushorts)
    constexpr int BLO  = 8192 + NFR * 2048;    // B-lo base
    __shared__ ushort lds[8192 + NFR * 4096];

    const int tid = threadIdx.x;
    const int lane = tid & 63, w = tid >> 6;
    const int l15 = lane & 15, g = lane >> 4;
    const int wr = w >> 1, wc = w & 1;
    const int m0 = blockIdx.x * 64, n0 = blockIdx.y * (NFR * 32);

    const int srow = lane >> 3;                    // 0..7
    const int sswz = 8 * ((lane & 7) ^ srow);      // swizzled slot (ushorts)
    const ushort* pAh = Xh + (size_t)(m0 + w*16 + srow) * Hdim + sswz;
    const ushort* pAl = Xl + (size_t)(m0 + w*16 + srow) * Hdim + sswz;
    const ushort* pBh = Wh + (size_t)(n0 + w*(NFR*8) + srow) * Hdim + sswz;
    const ushort* pBl = Wl + (size_t)(n0 + w*(NFR*8) + srow) * Hdim + sswz;
    ushort* lAh = &lds[0]    + w * 1024;
    ushort* lAl = &lds[4096] + w * 1024;
    ushort* lBh = &lds[BOFF] + w * (NFR * 512);
    ushort* lBl = &lds[BLO]  + w * (NFR * 512);

    f32x4 acc[2][NFR];
    #pragma unroll
    for (int m = 0; m < 2; ++m)
        #pragma unroll
        for (int n = 0; n < NFR; ++n) acc[m][n] = (f32x4){0.f, 0.f, 0.f, 0.f};

    const int fsw = l15 & 7;

    for (int k0 = 0; k0 < Hdim; k0 += 64) {
        __syncthreads();
        gload16(pAh + k0,          lAh);
        gload16(pAh + k0 + 8*Hdim, lAh + 512);
        gload16(pAl + k0,          lAl);
        gload16(pAl + k0 + 8*Hdim, lAl + 512);
        #pragma unroll
        for (int j = 0; j < NFR; ++j) {
            gload16(pBh + k0 + j*8*Hdim, lBh + j*512);
            gload16(pBl + k0 + j*8*Hdim, lBl + j*512);
        }
        __syncthreads();

        #pragma unroll
        for (int ks = 0; ks < 2; ++ks) {
            const int so = 8 * ((ks*4 + g) ^ fsw);
            bf16x8 xh_[2], xl_[2];
            #pragma unroll
            for (int m = 0; m < 2; ++m) {
                const int off = (wr*32 + m*16 + l15) * 64 + so;
                xh_[m] = *(const bf16x8*)&lds[off];
                xl_[m] = *(const bf16x8*)&lds[4096 + off];
            }
            #pragma unroll
            for (int n = 0; n < NFR; ++n) {
                const int off = (wc*(NFR*16) + n*16 + l15) * 64 + so;
                bf16x8 wh_ = *(const bf16x8*)&lds[BOFF + off];
                bf16x8 wl_ = *(const bf16x8*)&lds[BLO + off];
                #pragma unroll
                for (int m = 0; m < 2; ++m) {
                    acc[m][n] = __builtin_amdgcn_mfma_f32_16x16x32_bf16(xh_[m], wh_, acc[m][n], 0, 0, 0);
                    acc[m][n] = __builtin_amdgcn_mfma_f32_16x16x32_bf16(xh_[m], wl_, acc[m][n], 0, 0, 0);
                    acc[m][n] = __builtin_amdgcn_mfma_f32_16x16x32_bf16(xl_[m], wh_, acc[m][n], 0, 0, 0);
                }
            }
        }
    }

    // Epilogue. D layout: col=lane&15, row=(lane>>4)*4+reg.
    const int rb = m0 + wr*32 + g*4;
    #pragma unroll
    for (int n = 0; n < NFR; ++n) {
        const int col = n0 + wc*(NFR*16) + n*16 + l15;
        const int seg = col / Hdim;
        const int lc  = col - seg * Hdim;
        const float bias = (seg == 0 ? b0 : seg == 1 ? b1 : b2)[lc];
        #pragma unroll
        for (int m = 0; m < 2; ++m) {
            #pragma unroll
            for (int r = 0; r < 4; ++r) {
                const size_t idx = (size_t)seg * outSeg + (size_t)(rb + m*16 + r) * Hdim + lc;
                float v = acc[m][n][r] + bias;
                if (seg == 0) v *= qscale;          // exact (power of 2)
                if (relu) v = v > 0.f ? v : 0.f;
                if (residH) v += bf2f(residH[idx]) + bf2f(residL[idx]);
                const ushort hh = f2bf(v);
                Yh[idx] = hh;
                Yl[idx] = f2bf(v - bf2f(hh));
            }
        }
    }
}

// ---------------------------------------------------------------------------
// MFMA flash attention partials, KV-split 2-way. Block = 128 q rows x 512 KV
// rows. Q pre-scaled by 1/8 (QKV epilogue). Scores 3-term split; P enters PV
// as plain bf16 (P-lo dropped: linear 2^-9 error, measured-anchored safe);
// V stays hi/lo. Defer-max THR=8 (T13): common path has no shuffles and no
// accO rescale; l-sum is per-lane, reduced once in the epilogue.
// LDS map (ushorts): K0h@0 K0l@4096(x2 dbuf @8192) Vth@16384 Vtl@20992.
// ---------------------------------------------------------------------------
__global__ __launch_bounds__(256, 3) void attn_mfma(
    const ushort* __restrict__ Qh, const ushort* __restrict__ Ql,
    const ushort* __restrict__ Kh, const ushort* __restrict__ Kl,
    const ushort* __restrict__ Vh, const ushort* __restrict__ Vl,
    float* __restrict__ Op0, float* __restrict__ Op1,
    float* __restrict__ Mp, float* __restrict__ Lp)
{
    __shared__ ushort sm[25600];   // 51200 B

    const int tid  = threadIdx.x;
    const int lane = tid & 63, wid = tid >> 6;
    const int l15  = lane & 15, g = lane >> 4;
    const int qtile = blockIdx.x >> 1, part = blockIdx.x & 1;
    const int h = blockIdx.y, b = blockIdx.z;

    const size_t rowbase = (size_t)b * Ss;
    const int    colbase = h * HD;
    const int    q0 = qtile * 128 + wid * 32;
    const int    kv0 = part * 512;

    // Hoisted Q fragments [qfrag][kstep][hi/lo]
    bf16x8 qf[2][2][2];
    #pragma unroll
    for (int nf = 0; nf < 2; ++nf) {
        const size_t r = (rowbase + q0 + nf * 16 + l15) * Hdim + colbase;
        #pragma unroll
        for (int ks = 0; ks < 2; ++ks) {
            qf[nf][ks][0] = *(const bf16x8*)(Qh + r + ks * 32 + g * 8);
            qf[nf][ks][1] = *(const bf16x8*)(Ql + r + ks * 32 + g * 8);
        }
    }

    f32x4 accO[4][2];
    #pragma unroll
    for (int mf = 0; mf < 4; ++mf)
        #pragma unroll
        for (int nf = 0; nf < 2; ++nf) accO[mf][nf] = (f32x4){0.f, 0.f, 0.f, 0.f};
    float mrun[2] = {-1e30f, -1e30f}, lsum[2] = {0.f, 0.f};

    // K staging constants
    const int s8 = lane >> 3;
    const int kswz = 8 * ((lane & 7) ^ s8);
    const ushort* gK0 = Kh + (rowbase + kv0 + wid*16 + s8) * Hdim + colbase + kswz;
    const ushort* gK1 = Kl + (rowbase + kv0 + wid*16 + s8) * Hdim + colbase + kswz;

    // V staging constants
    const int vrow = tid >> 2, vsp = tid & 3;
    const int kx = vrow ^ (vsp << 4);
    const size_t vgbase = (rowbase + kv0 + vrow) * Hdim + colbase;
    uint4 vrh[2], vrl[2];

    const int fsw = l15 & 7;

    // ---- prologue: stage tile 0 ------------------------------------------
    gload16(gK0,          &sm[0]    + wid*1024);
    gload16(gK0 + 8*Hdim, &sm[0]    + wid*1024 + 512);
    gload16(gK1,          &sm[4096] + wid*1024);
    gload16(gK1 + 8*Hdim, &sm[4096] + wid*1024 + 512);
    #pragma unroll
    for (int u = 0; u < 2; ++u) {
        vrh[u] = *(const uint4*)(Vh + vgbase + (vsp*2 + u) * 8);
        vrl[u] = *(const uint4*)(Vl + vgbase + (vsp*2 + u) * 8);
    }
    __syncthreads();
    #pragma unroll
    for (int u = 0; u < 2; ++u) {
        const int seg = vsp * 2 + u;
        const ushort* hs = (const ushort*)&vrh[u];
        const ushort* ls = (const ushort*)&vrl[u];
        #pragma unroll
        for (int j = 0; j < 8; ++j) {
            sm[16384 + (seg*8 + j) * 72 + kx] = hs[j];
            sm[20992 + (seg*8 + j) * 72 + kx] = ls[j];
        }
    }
    __syncthreads();

    for (int t = 0; t < 8; ++t) {
        const int cur = (t & 1) * 8192;
        // ---- prefetch tile t+1 (K -> other LDS buf; V -> regs) -----------
        if (t < 7) {
            const int nxt = ((t + 1) & 1) * 8192;
            const size_t ko = (size_t)((t + 1) * 64) * Hdim;
            gload16(gK0 + ko,          &sm[nxt]        + wid*1024);
            gload16(gK0 + ko + 8*Hdim, &sm[nxt]        + wid*1024 + 512);
            gload16(gK1 + ko,          &sm[nxt + 4096] + wid*1024);
            gload16(gK1 + ko + 8*Hdim, &sm[nxt + 4096] + wid*1024 + 512);
            const size_t vg = vgbase + (size_t)((t + 1) * 64) * Hdim;
            #pragma unroll
            for (int u = 0; u < 2; ++u) {
                vrh[u] = *(const uint4*)(Vh + vg + (vsp*2 + u) * 8);
                vrl[u] = *(const uint4*)(Vl + vg + (vsp*2 + u) * 8);
            }
        }

        // ---- S^T = K · Q^T (split 3-term) --------------------------------
        f32x4 sc[4][2];
        #pragma unroll
        for (int m = 0; m < 4; ++m)
            #pragma unroll
            for (int nf = 0; nf < 2; ++nf) sc[m][nf] = (f32x4){0.f, 0.f, 0.f, 0.f};
        __builtin_amdgcn_s_setprio(1);
        #pragma unroll
        for (int ks = 0; ks < 2; ++ks) {
            const int so = 8 * ((ks*4 + g) ^ fsw);
            #pragma unroll
            for (int m = 0; m < 4; ++m) {
                const int off = cur + (m * 16 + l15) * 64 + so;
                bf16x8 kh_ = *(const bf16x8*)&sm[off];
                bf16x8 kl_ = *(const bf16x8*)&sm[off + 4096];
                #pragma unroll
                for (int nf = 0; nf < 2; ++nf) {
                    sc[m][nf] = __builtin_amdgcn_mfma_f32_16x16x32_bf16(kh_, qf[nf][ks][0], sc[m][nf], 0, 0, 0);
                    sc[m][nf] = __builtin_amdgcn_mfma_f32_16x16x32_bf16(kh_, qf[nf][ks][1], sc[m][nf], 0, 0, 0);
                    sc[m][nf] = __builtin_amdgcn_mfma_f32_16x16x32_bf16(kl_, qf[nf][ks][0], sc[m][nf], 0, 0, 0);
                }
            }
        }
        __builtin_amdgcn_s_setprio(0);

        // ---- online softmax: defer-max common path (no shuffles) ---------
        bf16x4 pb[4][2];
        #pragma unroll
        for (int nf = 0; nf < 2; ++nf) {
            float tl = -1e30f;
            #pragma unroll
            for (int m = 0; m < 4; ++m)
                #pragma unroll
                for (int r = 0; r < 4; ++r) tl = fmaxf(tl, sc[m][nf][r]);
            if (__any(tl > mrun[nf] + 8.f)) {
                float tmax = fmaxf(tl, __shfl_xor(tl, 16));
                tmax = fmaxf(tmax, __shfl_xor(tmax, 32));
                const float mnew = fmaxf(mrun[nf], tmax);
                const float corr = __expf(mrun[nf] - mnew);
                mrun[nf] = mnew;
                lsum[nf] *= corr;
                #pragma unroll
                for (int mf = 0; mf < 4; ++mf) {
                    accO[mf][nf][0] *= corr; accO[mf][nf][1] *= corr;
                    accO[mf][nf][2] *= corr; accO[mf][nf][3] *= corr;
                }
            }
            float ps = 0.f;
            #pragma unroll
            for (int m = 0; m < 4; ++m)
                #pragma unroll
                for (int r = 0; r < 4; ++r) {
                    const float p = __expf(sc[m][nf][r] - mrun[nf]);
                    sc[m][nf][r] = p;
                    ps += p;
                }
            lsum[nf] += ps;
            #pragma unroll
            for (int kt = 0; kt < 4; ++kt)
                #pragma unroll
                for (int r = 0; r < 4; ++r)
                    pb[kt][nf][r] = (short)f2bf(sc[kt][nf][r]);
        }

        // ---- O^T += V^T · P^T (16x16x16; P plain bf16, V split) ----------
        __builtin_amdgcn_s_setprio(1);
        #pragma unroll
        for (int kt = 0; kt < 4; ++kt)
            #pragma unroll
            for (int mf = 0; mf < 4; ++mf) {
                const int voff = (mf * 16 + l15) * 72 + ((kt ^ mf) * 16 + g * 4);
                bf16x4 vh_ = *(const bf16x4*)&sm[16384 + voff];
                bf16x4 vl_ = *(const bf16x4*)&sm[20992 + voff];
                #pragma unroll
                for (int nf = 0; nf < 2; ++nf) {
                    accO[mf][nf] = mfma16(vh_, pb[kt][nf], accO[mf][nf]);
                    accO[mf][nf] = mfma16(vl_, pb[kt][nf], accO[mf][nf]);
                }
            }
        __builtin_amdgcn_s_setprio(0);

        __syncthreads();   // drains K(t+1) gloads + V regs; all PV reads done
        if (t < 7) {
            #pragma unroll
            for (int u = 0; u < 2; ++u) {
                const int seg = vsp * 2 + u;
                const ushort* hs = (const ushort*)&vrh[u];
                const ushort* ls = (const ushort*)&vrl[u];
                #pragma unroll
                for (int j = 0; j < 8; ++j) {
                    sm[16384 + (seg*8 + j) * 72 + kx] = hs[j];
                    sm[20992 + (seg*8 + j) * 72 + kx] = ls[j];
                }
            }
        }
        __syncthreads();
    }

    // ---- epilogue: reduce l across lanes; write fp32 partials ------------
    #pragma unroll
    for (int nf = 0; nf < 2; ++nf) {
        lsum[nf] += __shfl_xor(lsum[nf], 16);
        lsum[nf] += __shfl_xor(lsum[nf], 32);
    }
    float* ot = (float*)sm + wid * 2176;   // 32 rows x stride 68
    #pragma unroll
    for (int nf = 0; nf < 2; ++nf) {
        #pragma unroll
        for (int mf = 0; mf < 4; ++mf)
            #pragma unroll
            for (int r = 0; r < 4; ++r)
                ot[(nf * 16 + l15) * 68 + mf * 16 + g * 4 + r] = accO[mf][nf][r];
    }
    if (g == 0) {
        #pragma unroll
        for (int nf = 0; nf < 2; ++nf) {
            const size_t idx = (size_t)part * PL +
                (((size_t)b * NH + h) * Ss + q0 + nf * 16 + l15);
            Mp[idx] = mrun[nf];
            Lp[idx] = lsum[nf];
        }
    }
    __syncthreads();
    float* Op = part ? Op1 : Op0;
    const int orow = lane >> 1, oc = (lane & 1) * 32;
    const size_t pbase = (((size_t)b * NH + h) * Ss + q0 + orow) * 64 + oc;
    #pragma unroll
    for (int i = 0; i < 8; ++i)
        *(float4*)(Op + pbase + i * 4) = *(float4*)&ot[orow * 68 + oc + i * 4];
}

// ---------------------------------------------------------------------------
// Merge the two KV-split partials -> attn output (bf16 hi/lo).
// ---------------------------------------------------------------------------
__global__ void merge_kernel(const float* __restrict__ Op0, const float* __restrict__ Op1,
                             const float* __restrict__ Mp, const float* __restrict__ Lp,
                             ushort* __restrict__ ah, ushort* __restrict__ al) {
    const int id = blockIdx.x * 256 + threadIdx.x;   // 0..196607
    const int idx = id >> 2, dseg = id & 3;
    const int b = idx / (NH * Ss);
    const int rem = idx - b * NH * Ss;
    const int h = rem / Ss, q = rem - h * Ss;
    const float m0 = Mp[idx], m1 = Mp[PL + idx];
    const float l0 = Lp[idx], l1 = Lp[PL + idx];
    const float M  = fmaxf(m0, m1);
    const float e0 = __expf(m0 - M), e1 = __expf(m1 - M);
    const float inv = 1.f / (l0 * e0 + l1 * e1);
    const size_t pb = (size_t)idx * 64 + dseg * 16;
    const size_t ga = ((size_t)(b * Ss + q)) * Hdim + h * 64 + dseg * 16;
    #pragma unroll
    for (int i = 0; i < 4; ++i) {
        float4 a = *(const float4*)(Op0 + pb + i * 4);
        float4 c = *(const float4*)(Op1 + pb + i * 4);
        float4 o;
        o.x = (a.x * e0 + c.x * e1) * inv;
        o.y = (a.y * e0 + c.y * e1) * inv;
        o.z = (a.z * e0 + c.z * e1) * inv;
        o.w = (a.w * e0 + c.w * e1) * inv;
        ushort4 hh, ll;
        hh.x = f2bf(o.x); ll.x = f2bf(o.x - bf2f(hh.x));
        hh.y = f2bf(o.y); ll.y = f2bf(o.y - bf2f(hh.y));
        hh.z = f2bf(o.z); ll.z = f2bf(o.z - bf2f(hh.z));
        hh.w = f2bf(o.w); ll.w = f2bf(o.w - bf2f(hh.w));
        *(ushort4*)(ah + ga + i * 4) = hh;
        *(ushort4*)(al + ga + i * 4) = ll;
    }
}

// ---------------------------------------------------------------------------
// Classifier: logits[b,n] = dot(x[b,0,:], Wc[n,:]) + bc[n]  (x from hi/lo)
// ---------------------------------------------------------------------------
__global__ void cls_kernel(const ushort* __restrict__ xh, const ushort* __restrict__ xl,
                           const float* __restrict__ Wc,
                           const float* __restrict__ bc,
                           float* __restrict__ out) {
    const int b = blockIdx.x >> 1;
    const int n = blockIdx.x & 1;
    const int t = threadIdx.x;
    const ushort* ph = xh + (size_t)b * Ss * Hdim;   // row s=0
    const ushort* pl = xl + (size_t)b * Ss * Hdim;
    const float* pw = Wc + (size_t)n * Hdim;
    float partial = 0.f;
    for (int k = t; k < Hdim; k += 256)
        partial = fmaf(bf2f(ph[k]) + bf2f(pl[k]), pw[k], partial);
    __shared__ float red[256];
    red[t] = partial;
    __syncthreads();
    for (int off = 128; off > 0; off >>= 1) {
        if (t < off) red[t] += red[t + off];
        __syncthreads();
    }
    if (t == 0) out[blockIdx.x] = red[0] + bc[n];
}

// ---------------------------------------------------------------------------
extern "C" void kernel_launch(void* const* d_in, const int* in_sizes, int n_in,
                              void* d_out, int out_size, void* d_ws, size_t ws_size,
                              hipStream_t stream) {
    const int*   ids = (const int*)d_in[0];
    const float* emb = (const float*)d_in[1];
    const float* Wq  = (const float*)d_in[2];
    const float* bq  = (const float*)d_in[3];
    const float* Wk  = (const float*)d_in[4];
    const float* bk  = (const float*)d_in[5];
    const float* Wv  = (const float*)d_in[6];
    const float* bv  = (const float*)d_in[7];
    const float* Wi  = (const float*)d_in[8];
    const float* bi  = (const float*)d_in[9];
    const float* Wo  = (const float*)d_in[10];
    const float* bo  = (const float*)d_in[11];
    const float* Wc  = (const float*)d_in[12];
    const float* bc  = (const float*)d_in[13];
    float* out = (float*)d_out;

    const size_t F  = (size_t)Mm * Hdim;      // 3,145,728
    const size_t WS = (size_t)Hdim * Hdim;    // 589,824

    ushort* hb_hi  = (ushort*)d_ws;
    ushort* hb_lo  = hb_hi + F;
    ushort* qkv_hi = hb_lo + F;               // 3F
    ushort* qkv_lo = qkv_hi + 3 * F;          // 3F
    ushort* ah     = qkv_lo + 3 * F;
    ushort* al     = ah + F;
    ushort* ih     = al + F;
    ushort* il     = ih + F;
    ushort* w_hi   = il + F;                  // 5*WS per layer (reused)
    ushort* w_lo   = w_hi + 5 * WS;
    float*  Mp     = (float*)(w_lo + 5 * WS); // [2][PL]
    float*  Lp     = Mp + 2 * PL;             // [2][PL]
    // fp32 attention partials overlay dead regions:
    float*  Op0    = (float*)hb_hi;           // over hb (dead during attn)
    float*  Op1    = (float*)ih;              // over ih/il (dead during attn)

    embed_kernel<<<Mm, 192, 0, stream>>>(ids, emb, hb_hi, hb_lo);

    for (int l = 0; l < NLAYER; ++l) {
        const size_t off = (size_t)l * WS;
        split5_kernel<<<2880, 256, 0, stream>>>(Wq + off, Wk + off, Wv + off,
                                                Wi + off, Wo + off, w_hi, w_lo);
        // fused QKV: W rows 0..2303 = Wq|Wk|Wv (contiguous in w_hi)
        gemm_mfma<4><<<dim3(Mm/64, 2304/128), 256, 0, stream>>>(
            hb_hi, hb_lo, w_hi, w_lo,
            bq + l*Hdim, bk + l*Hdim, bv + l*Hdim,
            nullptr, nullptr, qkv_hi, qkv_lo, 0, F, 0.125f);
        attn_mfma<<<dim3(16, NH, Bb), 256, 0, stream>>>(
            qkv_hi, qkv_lo, qkv_hi + F, qkv_lo + F, qkv_hi + 2*F, qkv_lo + 2*F,
            Op0, Op1, Mp, Lp);
        merge_kernel<<<PL * 4 / 256, 256, 0, stream>>>(Op0, Op1, Mp, Lp, ah, al);
        gemm_mfma<2><<<dim3(Mm/64, Hdim/64), 256, 0, stream>>>(
            ah, al, w_hi + 3*WS, w_lo + 3*WS,
            bi + l*Hdim, bi + l*Hdim, bi + l*Hdim,
            nullptr, nullptr, ih, il, 1, 0, 1.f);
        gemm_mfma<2><<<dim3(Mm/64, Hdim/64), 256, 0, stream>>>(
            ih, il, w_hi + 4*WS, w_lo + 4*WS,
            bo + l*Hdim, bo + l*Hdim, bo + l*Hdim,
            ah, al, hb_hi, hb_lo, 0, 0, 1.f);
    }

    cls_kernel<<<Bb * NL, 256, 0, stream>>>(hb_hi, hb_lo, Wc, bc, out);
}

// Round 9
// 543.510 us; speedup vs baseline: 8.9217x; 1.0841x over previous
//
#include <hip/hip_runtime.h>
#include <hip/hip_bf16.h>
#include <math.h>

// Problem constants
constexpr int Hdim = 768;
constexpr int NH   = 12;
constexpr int HD   = 64;
constexpr int NLAYER = 4;
constexpr int Bb   = 4;
constexpr int Ss   = 1024;
constexpr int Mm   = Bb * Ss;   // 4096 rows
constexpr int NL   = 2;
constexpr int PL   = Bb * NH * Ss;   // 49152 q-rows total

typedef _Float16 f16x8 __attribute__((ext_vector_type(8)));
typedef _Float16 f16x4 __attribute__((ext_vector_type(4)));
typedef float    f32x4 __attribute__((ext_vector_type(4)));

__device__ __forceinline__ f32x4 mfma32h(f16x8 a, f16x8 b, f32x4 c) {
#if __has_builtin(__builtin_amdgcn_mfma_f32_16x16x32_f16)
    return __builtin_amdgcn_mfma_f32_16x16x32_f16(a, b, c, 0, 0, 0);
#else
    asm("v_mfma_f32_16x16x32_f16 %0, %1, %2, %0" : "+v"(c) : "v"(a), "v"(b));
    return c;
#endif
}
__device__ __forceinline__ f32x4 mfma16h(f16x4 a, f16x4 b, f32x4 c) {
#if __has_builtin(__builtin_amdgcn_mfma_f32_16x16x16f16)
    return __builtin_amdgcn_mfma_f32_16x16x16f16(a, b, c, 0, 0, 0);
#else
    asm("v_mfma_f32_16x16x16_f16 %0, %1, %2, %0" : "+v"(c) : "v"(a), "v"(b));
    return c;
#endif
}

// async global->LDS, 16B per lane; LDS dest = wave-uniform base + lane*16.
__device__ __forceinline__ void gload16(const void* g, void* l) {
    __builtin_amdgcn_global_load_lds(
        (const __attribute__((address_space(1))) unsigned int*)g,
        (__attribute__((address_space(3))) unsigned int*)l, 16, 0, 0);
}

// ---------------------------------------------------------------------------
// Embedding gather: fp32 residual copy + fp16 GEMM-input copy.
// ---------------------------------------------------------------------------
__global__ void embed_kernel(const int* __restrict__ ids,
                             const float* __restrict__ emb,
                             float* __restrict__ x32, _Float16* __restrict__ xh) {
    int row = blockIdx.x;              // 0..4095
    int t = threadIdx.x;               // 0..191
    int id = ids[row];
    float4 v = ((const float4*)(emb + (size_t)id * Hdim))[t];
    ((float4*)(x32 + (size_t)row * Hdim))[t] = v;
    f16x4 h;
    h[0] = (_Float16)v.x; h[1] = (_Float16)v.y;
    h[2] = (_Float16)v.z; h[3] = (_Float16)v.w;
    *(f16x4*)(xh + (size_t)row * Hdim + t * 4) = h;
}

// ---------------------------------------------------------------------------
// Convert one layer's five weight matrices (768x768) to fp16.
// ---------------------------------------------------------------------------
__global__ void cvt5_kernel(const float* __restrict__ w0, const float* __restrict__ w1,
                            const float* __restrict__ w2, const float* __restrict__ w3,
                            const float* __restrict__ w4,
                            _Float16* __restrict__ out) {
    int i = blockIdx.x * 256 + threadIdx.x;   // quad index
    int which = i / 147456;
    int j = i - which * 147456;
    const float* src = which == 0 ? w0 : which == 1 ? w1 : which == 2 ? w2
                     : which == 3 ? w3 : w4;
    float4 v = ((const float4*)src)[j];
    f16x4 h;
    h[0] = (_Float16)v.x; h[1] = (_Float16)v.y;
    h[2] = (_Float16)v.z; h[3] = (_Float16)v.w;
    *(f16x4*)(out + (size_t)which * 589824 + (size_t)j * 4) = h;
}

// ---------------------------------------------------------------------------
// fp16 MFMA GEMM: BM=128, BN=128, BK=64, 4 waves (2x2), wave tile 64x64.
// 1-D grid with XCD swizzle (nwg % 8 == 0). N=2304 (QKV fused) or 768.
// Outputs fp16 Yh always; optional fp32 Y32; optional fp32 residual.
// ---------------------------------------------------------------------------
__global__ __launch_bounds__(256) void gemm_f16(
    const _Float16* __restrict__ Xh, const _Float16* __restrict__ Wh,
    const float* __restrict__ b0, const float* __restrict__ b1,
    const float* __restrict__ b2,
    const float* __restrict__ resid32,
    _Float16* __restrict__ Yh, float* __restrict__ Y32,
    int relu, size_t outSeg, float qscale, int gm)
{
    __shared__ _Float16 lds[16384];   // A[128][64]@0, B[128][64]@8192

    const int tid = threadIdx.x;
    const int lane = tid & 63, w = tid >> 6;
    const int l15 = lane & 15, g = lane >> 4;
    const int wr = w >> 1, wc = w & 1;

    // XCD-aware block swizzle (bijective since nwg % 8 == 0)
    const int nwg = gridDim.x;
    const int cpx = nwg >> 3;
    const int bid = blockIdx.x;
    const int x   = (bid & 7) * cpx + (bid >> 3);
    const int m0  = (x % gm) * 128;
    const int n0  = (x / gm) * 128;

    const int srow = lane >> 3;                    // 0..7
    const int sswz = 8 * ((lane & 7) ^ srow);      // swizzled slot (halves)
    const _Float16* pA = Xh + (size_t)(m0 + w*32 + srow) * Hdim + sswz;
    const _Float16* pB = Wh + (size_t)(n0 + w*32 + srow) * Hdim + sswz;
    _Float16* lA = &lds[0]    + w * 2048;
    _Float16* lB = &lds[8192] + w * 2048;

    f32x4 acc[4][4];
    #pragma unroll
    for (int m = 0; m < 4; ++m)
        #pragma unroll
        for (int n = 0; n < 4; ++n) acc[m][n] = (f32x4){0.f, 0.f, 0.f, 0.f};

    const int fsw = l15 & 7;

    for (int k0 = 0; k0 < Hdim; k0 += 64) {
        __syncthreads();
        #pragma unroll
        for (int j = 0; j < 4; ++j) {
            gload16(pA + k0 + j*8*Hdim, lA + j*512);
            gload16(pB + k0 + j*8*Hdim, lB + j*512);
        }
        __syncthreads();

        #pragma unroll
        for (int ks = 0; ks < 2; ++ks) {
            const int so = 8 * ((ks*4 + g) ^ fsw);
            f16x8 af[4], bf[4];
            #pragma unroll
            for (int m = 0; m < 4; ++m)
                af[m] = *(const f16x8*)&lds[(wr*64 + m*16 + l15) * 64 + so];
            #pragma unroll
            for (int n = 0; n < 4; ++n)
                bf[n] = *(const f16x8*)&lds[8192 + (wc*64 + n*16 + l15) * 64 + so];
            #pragma unroll
            for (int m = 0; m < 4; ++m)
                #pragma unroll
                for (int n = 0; n < 4; ++n)
                    acc[m][n] = mfma32h(af[m], bf[n], acc[m][n]);
        }
    }

    // Epilogue. D layout: col=lane&15, row=(lane>>4)*4+reg.
    const int rb = m0 + wr*64 + g*4;
    #pragma unroll
    for (int n = 0; n < 4; ++n) {
        const int col = n0 + wc*64 + n*16 + l15;
        const int seg = col / Hdim;
        const int lc  = col - seg * Hdim;
        const float bias = (seg == 0 ? b0 : seg == 1 ? b1 : b2)[lc];
        #pragma unroll
        for (int m = 0; m < 4; ++m) {
            #pragma unroll
            for (int r = 0; r < 4; ++r) {
                const size_t idx = (size_t)seg * outSeg + (size_t)(rb + m*16 + r) * Hdim + lc;
                float v = acc[m][n][r] + bias;
                if (seg == 0) v *= qscale;          // exact (power of 2)
                if (relu) v = v > 0.f ? v : 0.f;
                if (resid32) v += resid32[idx];
                Yh[idx] = (_Float16)v;
                if (Y32) Y32[idx] = v;
            }
        }
    }
}

// ---------------------------------------------------------------------------
// fp16 MFMA flash attention partials, KV-split 2-way. Block = 128 q x 512 KV.
// Q pre-scaled by 1/8. Single-term fp16 QK and PV (fp32 accum). Defer-max.
// K double-buffered via global_load_lds; V reg-prefetched, transposed into
// LDS with wave=col-group / lane=row mapping (2-way banks, free).
// LDS map (halves): K0@0 K1@4096 Vt@8192 (stride 72); epilogue overlays.
// ---------------------------------------------------------------------------
__global__ __launch_bounds__(256, 3) void attn_mfma(
    const _Float16* __restrict__ Qh, const _Float16* __restrict__ Kh,
    const _Float16* __restrict__ Vh,
    float* __restrict__ Op0, float* __restrict__ Op1,
    float* __restrict__ Mp, float* __restrict__ Lp)
{
    __shared__ _Float16 sm[17408];   // 34816 B

    const int tid  = threadIdx.x;
    const int lane = tid & 63, wid = tid >> 6;
    const int l15  = lane & 15, g = lane >> 4;
    const int qtile = blockIdx.x >> 1, part = blockIdx.x & 1;
    const int h = blockIdx.y, b = blockIdx.z;

    const size_t rowbase = (size_t)b * Ss;
    const int    colbase = h * HD;
    const int    q0 = qtile * 128 + wid * 32;
    const int    kv0 = part * 512;

    // Hoisted Q fragments [qfrag][kstep]
    f16x8 qf[2][2];
    #pragma unroll
    for (int nf = 0; nf < 2; ++nf) {
        const size_t r = (rowbase + q0 + nf * 16 + l15) * Hdim + colbase;
        #pragma unroll
        for (int ks = 0; ks < 2; ++ks)
            qf[nf][ks] = *(const f16x8*)(Qh + r + ks * 32 + g * 8);
    }

    f32x4 accO[4][2];
    #pragma unroll
    for (int mf = 0; mf < 4; ++mf)
        #pragma unroll
        for (int nf = 0; nf < 2; ++nf) accO[mf][nf] = (f32x4){0.f, 0.f, 0.f, 0.f};
    float mrun[2] = {-1e30f, -1e30f}, lsum[2] = {0.f, 0.f};

    // K staging constants (gload16: 8 rows x 8 slots per instr)
    const int s8 = lane >> 3;
    const int kswz = 8 * ((lane & 7) ^ s8);
    const _Float16* gK = Kh + (rowbase + kv0 + wid*16 + s8) * Hdim + colbase + kswz;

    // V staging: wave wid covers cols [wid*16, wid*16+16), lane = KV row.
    const int kx = lane ^ (wid << 4);
    const _Float16* gV = Vh + (rowbase + kv0 + lane) * Hdim + colbase + wid * 16;
    uint4 vr[2];

    const int fsw = l15 & 7;

    // ---- prologue: stage tile 0 ------------------------------------------
    gload16(gK,          &sm[0] + wid*1024);
    gload16(gK + 8*Hdim, &sm[0] + wid*1024 + 512);
    #pragma unroll
    for (int u = 0; u < 2; ++u) vr[u] = *(const uint4*)(gV + u * 8);
    __syncthreads();
    #pragma unroll
    for (int u = 0; u < 2; ++u) {
        const _Float16* hs = (const _Float16*)&vr[u];
        #pragma unroll
        for (int j = 0; j < 8; ++j)
            sm[8192 + (wid*16 + u*8 + j) * 72 + kx] = hs[j];
    }
    __syncthreads();

    for (int t = 0; t < 8; ++t) {
        const int cur = (t & 1) * 4096;
        // ---- prefetch tile t+1 (K -> other LDS buf; V -> regs) -----------
        if (t < 7) {
            const int nxt = ((t + 1) & 1) * 4096;
            const size_t ko = (size_t)((t + 1) * 64) * Hdim;
            gload16(gK + ko,          &sm[nxt] + wid*1024);
            gload16(gK + ko + 8*Hdim, &sm[nxt] + wid*1024 + 512);
            #pragma unroll
            for (int u = 0; u < 2; ++u)
                vr[u] = *(const uint4*)(gV + ko + u * 8);
        }

        // ---- S^T = K · Q^T (fp16 single-term) ----------------------------
        f32x4 sc[4][2];
        #pragma unroll
        for (int m = 0; m < 4; ++m)
            #pragma unroll
            for (int nf = 0; nf < 2; ++nf) sc[m][nf] = (f32x4){0.f, 0.f, 0.f, 0.f};
        __builtin_amdgcn_s_setprio(1);
        #pragma unroll
        for (int ks = 0; ks < 2; ++ks) {
            const int so = 8 * ((ks*4 + g) ^ fsw);
            #pragma unroll
            for (int m = 0; m < 4; ++m) {
                f16x8 kh_ = *(const f16x8*)&sm[cur + (m * 16 + l15) * 64 + so];
                #pragma unroll
                for (int nf = 0; nf < 2; ++nf)
                    sc[m][nf] = mfma32h(kh_, qf[nf][ks], sc[m][nf]);
            }
        }
        __builtin_amdgcn_s_setprio(0);

        // ---- online softmax: defer-max common path -----------------------
        f16x4 pb[4][2];
        #pragma unroll
        for (int nf = 0; nf < 2; ++nf) {
            float tl = -1e30f;
            #pragma unroll
            for (int m = 0; m < 4; ++m)
                #pragma unroll
                for (int r = 0; r < 4; ++r) tl = fmaxf(tl, sc[m][nf][r]);
            if (__any(tl > mrun[nf] + 8.f)) {
                float tmax = fmaxf(tl, __shfl_xor(tl, 16));
                tmax = fmaxf(tmax, __shfl_xor(tmax, 32));
                const float mnew = fmaxf(mrun[nf], tmax);
                const float corr = __expf(mrun[nf] - mnew);
                mrun[nf] = mnew;
                lsum[nf] *= corr;
                #pragma unroll
                for (int mf = 0; mf < 4; ++mf) {
                    accO[mf][nf][0] *= corr; accO[mf][nf][1] *= corr;
                    accO[mf][nf][2] *= corr; accO[mf][nf][3] *= corr;
                }
            }
            float ps = 0.f;
            #pragma unroll
            for (int m = 0; m < 4; ++m)
                #pragma unroll
                for (int r = 0; r < 4; ++r) {
                    const float p = __expf(sc[m][nf][r] - mrun[nf]);
                    sc[m][nf][r] = p;
                    ps += p;
                }
            lsum[nf] += ps;
            #pragma unroll
            for (int kt = 0; kt < 4; ++kt)
                #pragma unroll
                for (int r = 0; r < 4; ++r)
                    pb[kt][nf][r] = (_Float16)sc[kt][nf][r];
        }

        // ---- O^T += V^T · P^T (fp16 single-term) -------------------------
        __builtin_amdgcn_s_setprio(1);
        #pragma unroll
        for (int kt = 0; kt < 4; ++kt)
            #pragma unroll
            for (int mf = 0; mf < 4; ++mf) {
                const int voff = (mf * 16 + l15) * 72 + ((kt ^ mf) * 16 + g * 4);
                f16x4 vh_ = *(const f16x4*)&sm[8192 + voff];
                #pragma unroll
                for (int nf = 0; nf < 2; ++nf)
                    accO[mf][nf] = mfma16h(vh_, pb[kt][nf], accO[mf][nf]);
            }
        __builtin_amdgcn_s_setprio(0);

        __syncthreads();   // drains K(t+1) gloads + V regs; all PV reads done
        if (t < 7) {
            #pragma unroll
            for (int u = 0; u < 2; ++u) {
                const _Float16* hs = (const _Float16*)&vr[u];
                #pragma unroll
                for (int j = 0; j < 8; ++j)
                    sm[8192 + (wid*16 + u*8 + j) * 72 + kx] = hs[j];
            }
        }
        __syncthreads();
    }

    // ---- epilogue: reduce l across lanes; write fp32 partials ------------
    #pragma unroll
    for (int nf = 0; nf < 2; ++nf) {
        lsum[nf] += __shfl_xor(lsum[nf], 16);
        lsum[nf] += __shfl_xor(lsum[nf], 32);
    }
    float* ot = (float*)sm + wid * 2176;   // 32 rows x stride 68
    #pragma unroll
    for (int nf = 0; nf < 2; ++nf) {
        #pragma unroll
        for (int mf = 0; mf < 4; ++mf)
            #pragma unroll
            for (int r = 0; r < 4; ++r)
                ot[(nf * 16 + l15) * 68 + mf * 16 + g * 4 + r] = accO[mf][nf][r];
    }
    if (g == 0) {
        #pragma unroll
        for (int nf = 0; nf < 2; ++nf) {
            const size_t idx = (size_t)part * PL +
                (((size_t)b * NH + h) * Ss + q0 + nf * 16 + l15);
            Mp[idx] = mrun[nf];
            Lp[idx] = lsum[nf];
        }
    }
    __syncthreads();
    float* Op = part ? Op1 : Op0;
    const int orow = lane >> 1, oc = (lane & 1) * 32;
    const size_t pbase = (((size_t)b * NH + h) * Ss + q0 + orow) * 64 + oc;
    #pragma unroll
    for (int i = 0; i < 8; ++i)
        *(float4*)(Op + pbase + i * 4) = *(float4*)&ot[orow * 68 + oc + i * 4];
}

// ---------------------------------------------------------------------------
// Merge the two KV-split partials -> attn output (fp16 for Wi, fp32 resid).
// ---------------------------------------------------------------------------
__global__ void merge_kernel(const float* __restrict__ Op0, const float* __restrict__ Op1,
                             const float* __restrict__ Mp, const float* __restrict__ Lp,
                             _Float16* __restrict__ a16, float* __restrict__ a32) {
    const int id = blockIdx.x * 256 + threadIdx.x;   // 0..196607
    const int idx = id >> 2, dseg = id & 3;
    const int b = idx / (NH * Ss);
    const int rem = idx - b * NH * Ss;
    const int h = rem / Ss, q = rem - h * Ss;
    const float m0 = Mp[idx], m1 = Mp[PL + idx];
    const float l0 = Lp[idx], l1 = Lp[PL + idx];
    const float M  = fmaxf(m0, m1);
    const float e0 = __expf(m0 - M), e1 = __expf(m1 - M);
    const float inv = 1.f / (l0 * e0 + l1 * e1);
    const size_t pb = (size_t)idx * 64 + dseg * 16;
    const size_t ga = ((size_t)(b * Ss + q)) * Hdim + h * 64 + dseg * 16;
    #pragma unroll
    for (int i = 0; i < 4; ++i) {
        float4 a = *(const float4*)(Op0 + pb + i * 4);
        float4 c = *(const float4*)(Op1 + pb + i * 4);
        float4 o;
        o.x = (a.x * e0 + c.x * e1) * inv;
        o.y = (a.y * e0 + c.y * e1) * inv;
        o.z = (a.z * e0 + c.z * e1) * inv;
        o.w = (a.w * e0 + c.w * e1) * inv;
        *(float4*)(a32 + ga + i * 4) = o;
        f16x4 hh;
        hh[0] = (_Float16)o.x; hh[1] = (_Float16)o.y;
        hh[2] = (_Float16)o.z; hh[3] = (_Float16)o.w;
        *(f16x4*)(a16 + ga + i * 4) = hh;
    }
}

// ---------------------------------------------------------------------------
// Classifier: logits[b,n] = dot(x32[b,0,:], Wc[n,:]) + bc[n]
// ---------------------------------------------------------------------------
__global__ void cls_kernel(const float* __restrict__ x32,
                           const float* __restrict__ Wc,
                           const float* __restrict__ bc,
                           float* __restrict__ out) {
    const int b = blockIdx.x >> 1;
    const int n = blockIdx.x & 1;
    const int t = threadIdx.x;
    const float* px = x32 + (size_t)b * Ss * Hdim;   // row s=0
    const float* pw = Wc + (size_t)n * Hdim;
    float partial = 0.f;
    for (int k = t; k < Hdim; k += 256) partial = fmaf(px[k], pw[k], partial);
    __shared__ float red[256];
    red[t] = partial;
    __syncthreads();
    for (int off = 128; off > 0; off >>= 1) {
        if (t < off) red[t] += red[t + off];
        __syncthreads();
    }
    if (t == 0) out[blockIdx.x] = red[0] + bc[n];
}

// ---------------------------------------------------------------------------
extern "C" void kernel_launch(void* const* d_in, const int* in_sizes, int n_in,
                              void* d_out, int out_size, void* d_ws, size_t ws_size,
                              hipStream_t stream) {
    const int*   ids = (const int*)d_in[0];
    const float* emb = (const float*)d_in[1];
    const float* Wq  = (const float*)d_in[2];
    const float* bq  = (const float*)d_in[3];
    const float* Wk  = (const float*)d_in[4];
    const float* bk  = (const float*)d_in[5];
    const float* Wv  = (const float*)d_in[6];
    const float* bv  = (const float*)d_in[7];
    const float* Wi  = (const float*)d_in[8];
    const float* bi  = (const float*)d_in[9];
    const float* Wo  = (const float*)d_in[10];
    const float* bo  = (const float*)d_in[11];
    const float* Wc  = (const float*)d_in[12];
    const float* bc  = (const float*)d_in[13];
    float* out = (float*)d_out;

    const size_t F  = (size_t)Mm * Hdim;      // 3,145,728
    const size_t WS = (size_t)Hdim * Hdim;    // 589,824

    float*    x32 = (float*)d_ws;             // fp32 residual stream
    _Float16* xh  = (_Float16*)(x32 + F);     // fp16 GEMM input copy
    _Float16* qkv = xh + F;                   // 3F fp16
    _Float16* a16 = qkv + 3 * F;              // attn out fp16
    _Float16* i16 = a16 + F;                  // inter fp16
    _Float16* w16 = i16 + F;                  // 5*WS fp16 (per-layer, reused)
    float*    a32 = (float*)(w16 + 5 * WS);   // attn out fp32 (Wo residual)
    float*    Op0 = a32 + F;                  // fp32 partials
    float*    Op1 = Op0 + F;
    float*    Mp  = Op1 + F;                  // [2][PL]
    float*    Lp  = Mp + 2 * PL;              // [2][PL]

    embed_kernel<<<Mm, 192, 0, stream>>>(ids, emb, x32, xh);

    for (int l = 0; l < NLAYER; ++l) {
        const size_t off = (size_t)l * WS;
        cvt5_kernel<<<2880, 256, 0, stream>>>(Wq + off, Wk + off, Wv + off,
                                              Wi + off, Wo + off, w16);
        // fused QKV: W rows 0..2303 = Wq|Wk|Wv (contiguous in w16)
        gemm_f16<<<576, 256, 0, stream>>>(
            xh, w16, bq + l*Hdim, bk + l*Hdim, bv + l*Hdim,
            nullptr, qkv, nullptr, 0, F, 0.125f, 32);
        attn_mfma<<<dim3(16, NH, Bb), 256, 0, stream>>>(
            qkv, qkv + F, qkv + 2*F, Op0, Op1, Mp, Lp);
        merge_kernel<<<PL * 4 / 256, 256, 0, stream>>>(Op0, Op1, Mp, Lp, a16, a32);
        gemm_f16<<<192, 256, 0, stream>>>(
            a16, w16 + 3*WS, bi + l*Hdim, bi + l*Hdim, bi + l*Hdim,
            nullptr, i16, nullptr, 1, 0, 1.f, 32);
        gemm_f16<<<192, 256, 0, stream>>>(
            i16, w16 + 4*WS, bo + l*Hdim, bo + l*Hdim, bo + l*Hdim,
            a32, xh, x32, 0, 0, 1.f, 32);
    }

    cls_kernel<<<Bb * NL, 256, 0, stream>>>(x32, Wc, bc, out);
}

// Round 11
// 436.601 us; speedup vs baseline: 11.1063x; 1.2449x over previous
//
#include <hip/hip_runtime.h>
#include <hip/hip_bf16.h>
#include <math.h>

// Problem constants
constexpr int Hdim = 768;
constexpr int NH   = 12;
constexpr int HD   = 64;
constexpr int NLAYER = 4;
constexpr int Bb   = 4;
constexpr int Ss   = 1024;
constexpr int Mm   = Bb * Ss;   // 4096 rows
constexpr int NL   = 2;
constexpr int PL   = Bb * NH * Ss;   // 49152 q-rows total
constexpr float LOG2E = 1.44269504088896f;

typedef _Float16 f16x8 __attribute__((ext_vector_type(8)));
typedef _Float16 f16x4 __attribute__((ext_vector_type(4)));
typedef __fp16   h16x2 __attribute__((ext_vector_type(2)));
typedef float    f32x4 __attribute__((ext_vector_type(4)));

__device__ __forceinline__ f32x4 mfma32h(f16x8 a, f16x8 b, f32x4 c) {
#if __has_builtin(__builtin_amdgcn_mfma_f32_16x16x32_f16)
    return __builtin_amdgcn_mfma_f32_16x16x32_f16(a, b, c, 0, 0, 0);
#else
    asm("v_mfma_f32_16x16x32_f16 %0, %1, %2, %0" : "+v"(c) : "v"(a), "v"(b));
    return c;
#endif
}
__device__ __forceinline__ f32x4 mfma16h(f16x4 a, f16x4 b, f32x4 c) {
#if __has_builtin(__builtin_amdgcn_mfma_f32_16x16x16f16)
    return __builtin_amdgcn_mfma_f32_16x16x16f16(a, b, c, 0, 0, 0);
#else
    asm("v_mfma_f32_16x16x16_f16 %0, %1, %2, %0" : "+v"(c) : "v"(a), "v"(b));
    return c;
#endif
}

// async global->LDS, 16B per lane; LDS dest = wave-uniform base + lane*16.
__device__ __forceinline__ void gload16(const void* g, void* l) {
    __builtin_amdgcn_global_load_lds(
        (const __attribute__((address_space(1))) unsigned int*)g,
        (__attribute__((address_space(3))) unsigned int*)l, 16, 0, 0);
}

// ---------------------------------------------------------------------------
// Embedding gather: fp32 residual copy + fp16 GEMM-input copy.
// ---------------------------------------------------------------------------
__global__ void embed_kernel(const int* __restrict__ ids,
                             const float* __restrict__ emb,
                             float* __restrict__ x32, _Float16* __restrict__ xh) {
    int row = blockIdx.x;              // 0..4095
    int t = threadIdx.x;               // 0..191
    int id = ids[row];
    float4 v = ((const float4*)(emb + (size_t)id * Hdim))[t];
    ((float4*)(x32 + (size_t)row * Hdim))[t] = v;
    f16x4 h;
    h[0] = (_Float16)v.x; h[1] = (_Float16)v.y;
    h[2] = (_Float16)v.z; h[3] = (_Float16)v.w;
    *(f16x4*)(xh + (size_t)row * Hdim + t * 4) = h;
}

// ---------------------------------------------------------------------------
// Convert ALL layers' weight matrices (4 layers x 5 x 768x768) to fp16.
// ---------------------------------------------------------------------------
__global__ void cvtw_kernel(const float* __restrict__ Wq, const float* __restrict__ Wk,
                            const float* __restrict__ Wv, const float* __restrict__ Wi,
                            const float* __restrict__ Wo,
                            _Float16* __restrict__ out) {
    int i = blockIdx.x * 256 + threadIdx.x;   // quad index, 0..2949119
    int l = i / (5 * 147456);
    int rem = i - l * (5 * 147456);
    int which = rem / 147456;
    int j = rem - which * 147456;
    const float* src = (which == 0 ? Wq : which == 1 ? Wk : which == 2 ? Wv
                      : which == 3 ? Wi : Wo) + (size_t)l * 589824;
    float4 v = ((const float4*)src)[j];
    f16x4 h;
    h[0] = (_Float16)v.x; h[1] = (_Float16)v.y;
    h[2] = (_Float16)v.z; h[3] = (_Float16)v.w;
    *(f16x4*)(out + ((size_t)l * 5 + which) * 589824 + (size_t)j * 4) = h;
}

// ---------------------------------------------------------------------------
// fp16 MFMA GEMM: BM=64, BN=128, BK=64, 4 waves (2x2), wave tile 32x64.
// 1-D grid with XCD swizzle (nwg % 8 == 0). N=2304 (QKV fused) or 768.
// ---------------------------------------------------------------------------
__global__ __launch_bounds__(256) void gemm_f16(
    const _Float16* __restrict__ Xh, const _Float16* __restrict__ Wh,
    const float* __restrict__ b0, const float* __restrict__ b1,
    const float* __restrict__ b2,
    const float* __restrict__ resid32,
    _Float16* __restrict__ Yh, float* __restrict__ Y32,
    int relu, size_t outSeg, float qscale, int gm)
{
    __shared__ _Float16 lds[12288];   // A[64][64]@0, B[128][64]@4096

    const int tid = threadIdx.x;
    const int lane = tid & 63, w = tid >> 6;
    const int l15 = lane & 15, g = lane >> 4;
    const int wr = w >> 1, wc = w & 1;

    // XCD-aware block swizzle (bijective since nwg % 8 == 0)
    const int nwg = gridDim.x;
    const int cpx = nwg >> 3;
    const int bid = blockIdx.x;
    const int x   = (bid & 7) * cpx + (bid >> 3);
    const int m0  = (x % gm) * 64;
    const int n0  = (x / gm) * 128;

    const int srow = lane >> 3;                    // 0..7
    const int sswz = 8 * ((lane & 7) ^ srow);      // swizzled slot (halves)
    const _Float16* pA = Xh + (size_t)(m0 + w*16 + srow) * Hdim + sswz;
    const _Float16* pB = Wh + (size_t)(n0 + w*32 + srow) * Hdim + sswz;
    _Float16* lA = &lds[0]    + w * 1024;
    _Float16* lB = &lds[4096] + w * 2048;

    f32x4 acc[2][4];
    #pragma unroll
    for (int m = 0; m < 2; ++m)
        #pragma unroll
        for (int n = 0; n < 4; ++n) acc[m][n] = (f32x4){0.f, 0.f, 0.f, 0.f};

    const int fsw = l15 & 7;

    for (int k0 = 0; k0 < Hdim; k0 += 64) {
        __syncthreads();
        gload16(pA + k0,          lA);
        gload16(pA + k0 + 8*Hdim, lA + 512);
        #pragma unroll
        for (int j = 0; j < 4; ++j)
            gload16(pB + k0 + j*8*Hdim, lB + j*512);
        __syncthreads();

        #pragma unroll
        for (int ks = 0; ks < 2; ++ks) {
            const int so = 8 * ((ks*4 + g) ^ fsw);
            f16x8 af[2], bf[4];
            #pragma unroll
            for (int m = 0; m < 2; ++m)
                af[m] = *(const f16x8*)&lds[(wr*32 + m*16 + l15) * 64 + so];
            #pragma unroll
            for (int n = 0; n < 4; ++n)
                bf[n] = *(const f16x8*)&lds[4096 + (wc*64 + n*16 + l15) * 64 + so];
            #pragma unroll
            for (int m = 0; m < 2; ++m)
                #pragma unroll
                for (int n = 0; n < 4; ++n)
                    acc[m][n] = mfma32h(af[m], bf[n], acc[m][n]);
        }
    }

    // Epilogue. D layout: col=lane&15, row=(lane>>4)*4+reg.
    const int rb = m0 + wr*32 + g*4;
    #pragma unroll
    for (int n = 0; n < 4; ++n) {
        const int col = n0 + wc*64 + n*16 + l15;
        const int seg = col / Hdim;
        const int lc  = col - seg * Hdim;
        const float bias = (seg == 0 ? b0 : seg == 1 ? b1 : b2)[lc];
        #pragma unroll
        for (int m = 0; m < 2; ++m) {
            #pragma unroll
            for (int r = 0; r < 4; ++r) {
                const size_t idx = (size_t)seg * outSeg + (size_t)(rb + m*16 + r) * Hdim + lc;
                float v = acc[m][n][r] + bias;
                if (seg == 0) v *= qscale;
                if (relu) v = v > 0.f ? v : 0.f;
                if (resid32) v += resid32[idx];
                Yh[idx] = (_Float16)v;
                if (Y32) Y32[idx] = v;
            }
        }
    }
}

// ---------------------------------------------------------------------------
// fp16 MFMA flash attention partials, KV-split 2-way. Block = 128 q x 512 KV.
// Q pre-scaled by log2e/8 (scores in log2 domain -> native v_exp for exp2).
// K AND V double-buffered -> ONE barrier per tile: issue K(t+1) gload + V(t+1)
// reg loads at top; QK; softmax; V(t+1) LDS-write (off buffer); PV; barrier.
// LDS (halves): K0@0 K1@4096 V0@8192 V1@12800 (stride 72) = 34816 B.
// ---------------------------------------------------------------------------
__global__ __launch_bounds__(256, 3) void attn_mfma(
    const _Float16* __restrict__ Qh, const _Float16* __restrict__ Kh,
    const _Float16* __restrict__ Vh,
    float* __restrict__ Op0, float* __restrict__ Op1,
    float* __restrict__ Mp, float* __restrict__ Lp)
{
    __shared__ _Float16 sm[17408];   // 34816 B

    const int tid  = threadIdx.x;
    const int lane = tid & 63, wid = tid >> 6;
    const int l15  = lane & 15, g = lane >> 4;
    const int qtile = blockIdx.x >> 1, part = blockIdx.x & 1;
    const int h = blockIdx.y, b = blockIdx.z;

    const size_t rowbase = (size_t)b * Ss;
    const int    colbase = h * HD;
    const int    q0 = qtile * 128 + wid * 32;
    const int    kv0 = part * 512;

    // Hoisted Q fragments [qfrag][kstep]
    f16x8 qf[2][2];
    #pragma unroll
    for (int nf = 0; nf < 2; ++nf) {
        const size_t r = (rowbase + q0 + nf * 16 + l15) * Hdim + colbase;
        #pragma unroll
        for (int ks = 0; ks < 2; ++ks)
            qf[nf][ks] = *(const f16x8*)(Qh + r + ks * 32 + g * 8);
    }

    f32x4 accO[4][2];
    #pragma unroll
    for (int mf = 0; mf < 4; ++mf)
        #pragma unroll
        for (int nf = 0; nf < 2; ++nf) accO[mf][nf] = (f32x4){0.f, 0.f, 0.f, 0.f};
    float mrun[2] = {-1e30f, -1e30f}, lsum[2] = {0.f, 0.f};

    // K staging constants
    const int s8 = lane >> 3;
    const int kswz = 8 * ((lane & 7) ^ s8);
    const _Float16* gK = Kh + (rowbase + kv0 + wid*16 + s8) * Hdim + colbase + kswz;

    // V staging: wave wid covers cols [wid*16, wid*16+16), lane = KV row.
    const int kx = lane ^ (wid << 4);
    const _Float16* gV = Vh + (rowbase + kv0 + lane) * Hdim + colbase + wid * 16;
    uint4 vr[2];

    const int fsw = l15 & 7;

    // ---- prologue: stage tile 0 into K0/V0 -------------------------------
    gload16(gK,          &sm[0] + wid*1024);
    gload16(gK + 8*Hdim, &sm[0] + wid*1024 + 512);
    #pragma unroll
    for (int u = 0; u < 2; ++u) vr[u] = *(const uint4*)(gV + u * 8);
    #pragma unroll
    for (int u = 0; u < 2; ++u) {
        const _Float16* hs = (const _Float16*)&vr[u];
        #pragma unroll
        for (int j = 0; j < 8; ++j)
            sm[8192 + (wid*16 + u*8 + j) * 72 + kx] = hs[j];
    }
    __syncthreads();

    for (int t = 0; t < 8; ++t) {
        const int cur = t & 1;
        const int kb = cur * 4096;
        const int vb = 8192 + cur * 4608;
        // ---- prefetch tile t+1: K -> off LDS buf, V -> regs --------------
        if (t < 7) {
            const int nkb = (cur ^ 1) * 4096;
            const size_t ko = (size_t)((t + 1) * 64) * Hdim;
            gload16(gK + ko,          &sm[nkb] + wid*1024);
            gload16(gK + ko + 8*Hdim, &sm[nkb] + wid*1024 + 512);
            #pragma unroll
            for (int u = 0; u < 2; ++u)
                vr[u] = *(const uint4*)(gV + ko + u * 8);
        }

        // ---- S^T = K · Q^T (fp16 single-term; log2-domain scores) --------
        f32x4 sc[4][2];
        #pragma unroll
        for (int m = 0; m < 4; ++m)
            #pragma unroll
            for (int nf = 0; nf < 2; ++nf) sc[m][nf] = (f32x4){0.f, 0.f, 0.f, 0.f};
        __builtin_amdgcn_s_setprio(1);
        #pragma unroll
        for (int ks = 0; ks < 2; ++ks) {
            const int so = 8 * ((ks*4 + g) ^ fsw);
            #pragma unroll
            for (int m = 0; m < 4; ++m) {
                f16x8 kh_ = *(const f16x8*)&sm[kb + (m * 16 + l15) * 64 + so];
                #pragma unroll
                for (int nf = 0; nf < 2; ++nf)
                    sc[m][nf] = mfma32h(kh_, qf[nf][ks], sc[m][nf]);
            }
        }
        __builtin_amdgcn_s_setprio(0);

        // ---- online softmax (exp2 domain, defer-max) ---------------------
        f16x4 pb[4][2];
        #pragma unroll
        for (int nf = 0; nf < 2; ++nf) {
            float tl = -1e30f;
            #pragma unroll
            for (int m = 0; m < 4; ++m)
                #pragma unroll
                for (int r = 0; r < 4; ++r) tl = fmaxf(tl, sc[m][nf][r]);
            if (__any(tl > mrun[nf] + 11.5416f)) {       // 8 nats in log2 units
                float tmax = fmaxf(tl, __shfl_xor(tl, 16));
                tmax = fmaxf(tmax, __shfl_xor(tmax, 32));
                const float mnew = fmaxf(mrun[nf], tmax);
                const float corr = __builtin_amdgcn_exp2f(mrun[nf] - mnew);
                mrun[nf] = mnew;
                lsum[nf] *= corr;
                #pragma unroll
                for (int mf = 0; mf < 4; ++mf) {
                    accO[mf][nf][0] *= corr; accO[mf][nf][1] *= corr;
                    accO[mf][nf][2] *= corr; accO[mf][nf][3] *= corr;
                }
            }
            float ps = 0.f;
            #pragma unroll
            for (int m = 0; m < 4; ++m)
                #pragma unroll
                for (int r = 0; r < 4; ++r) {
                    const float p = __builtin_amdgcn_exp2f(sc[m][nf][r] - mrun[nf]);
                    sc[m][nf][r] = p;
                    ps += p;
                }
            lsum[nf] += ps;
            #pragma unroll
            for (int kt = 0; kt < 4; ++kt) {
                union { h16x2 h2[2]; f16x4 v; } u;
                u.h2[0] = __builtin_amdgcn_cvt_pkrtz(sc[kt][nf][0], sc[kt][nf][1]);
                u.h2[1] = __builtin_amdgcn_cvt_pkrtz(sc[kt][nf][2], sc[kt][nf][3]);
                pb[kt][nf] = u.v;
            }
        }

        // ---- write V(t+1) into the off buffer ----------------------------
        if (t < 7) {
            const int nvb = 8192 + (cur ^ 1) * 4608;
            #pragma unroll
            for (int u = 0; u < 2; ++u) {
                const _Float16* hs = (const _Float16*)&vr[u];
                #pragma unroll
                for (int j = 0; j < 8; ++j)
                    sm[nvb + (wid*16 + u*8 + j) * 72 + kx] = hs[j];
            }
        }

        // ---- O^T += V^T · P^T (fp16 single-term) -------------------------
        __builtin_amdgcn_s_setprio(1);
        #pragma unroll
        for (int kt = 0; kt < 4; ++kt)
            #pragma unroll
            for (int mf = 0; mf < 4; ++mf) {
                const int voff = vb + (mf * 16 + l15) * 72 + ((kt ^ mf) * 16 + g * 4);
                f16x4 vh_ = *(const f16x4*)&sm[voff];
                #pragma unroll
                for (int nf = 0; nf < 2; ++nf)
                    accO[mf][nf] = mfma16h(vh_, pb[kt][nf], accO[mf][nf]);
            }
        __builtin_amdgcn_s_setprio(0);

        __syncthreads();   // drains K(t+1) gloads; publishes V(t+1); all
                           // reads of the cur buffers complete
    }

    // ---- epilogue: reduce l across lanes; write fp32 partials ------------
    #pragma unroll
    for (int nf = 0; nf < 2; ++nf) {
        lsum[nf] += __shfl_xor(lsum[nf], 16);
        lsum[nf] += __shfl_xor(lsum[nf], 32);
    }
    float* ot = (float*)sm + wid * 2176;   // 32 rows x stride 68
    #pragma unroll
    for (int nf = 0; nf < 2; ++nf) {
        #pragma unroll
        for (int mf = 0; mf < 4; ++mf)
            #pragma unroll
            for (int r = 0; r < 4; ++r)
                ot[(nf * 16 + l15) * 68 + mf * 16 + g * 4 + r] = accO[mf][nf][r];
    }
    if (g == 0) {
        #pragma unroll
        for (int nf = 0; nf < 2; ++nf) {
            const size_t idx = (size_t)part * PL +
                (((size_t)b * NH + h) * Ss + q0 + nf * 16 + l15);
            Mp[idx] = mrun[nf];
            Lp[idx] = lsum[nf];
        }
    }
    __syncthreads();
    float* Op = part ? Op1 : Op0;
    const int orow = lane >> 1, oc = (lane & 1) * 32;
    const size_t pbase = (((size_t)b * NH + h) * Ss + q0 + orow) * 64 + oc;
    #pragma unroll
    for (int i = 0; i < 8; ++i)
        *(float4*)(Op + pbase + i * 4) = *(float4*)&ot[orow * 68 + oc + i * 4];
}

// ---------------------------------------------------------------------------
// Merge the two KV-split partials -> attn output (fp16 for Wi, fp32 resid).
// m values are in log2 domain.
// ---------------------------------------------------------------------------
__global__ void merge_kernel(const float* __restrict__ Op0, const float* __restrict__ Op1,
                             const float* __restrict__ Mp, const float* __restrict__ Lp,
                             _Float16* __restrict__ a16, float* __restrict__ a32) {
    const int id = blockIdx.x * 256 + threadIdx.x;   // 0..196607
    const int idx = id >> 2, dseg = id & 3;
    const int b = idx / (NH * Ss);
    const int rem = idx - b * NH * Ss;
    const int h = rem / Ss, q = rem - h * Ss;
    const float m0 = Mp[idx], m1 = Mp[PL + idx];
    const float l0 = Lp[idx], l1 = Lp[PL + idx];
    const float M  = fmaxf(m0, m1);
    const float e0 = __builtin_amdgcn_exp2f(m0 - M);
    const float e1 = __builtin_amdgcn_exp2f(m1 - M);
    const float inv = 1.f / (l0 * e0 + l1 * e1);
    const size_t pb = (size_t)idx * 64 + dseg * 16;
    const size_t ga = ((size_t)(b * Ss + q)) * Hdim + h * 64 + dseg * 16;
    #pragma unroll
    for (int i = 0; i < 4; ++i) {
        float4 a = *(const float4*)(Op0 + pb + i * 4);
        float4 c = *(const float4*)(Op1 + pb + i * 4);
        float4 o;
        o.x = (a.x * e0 + c.x * e1) * inv;
        o.y = (a.y * e0 + c.y * e1) * inv;
        o.z = (a.z * e0 + c.z * e1) * inv;
        o.w = (a.w * e0 + c.w * e1) * inv;
        *(float4*)(a32 + ga + i * 4) = o;
        f16x4 hh;
        hh[0] = (_Float16)o.x; hh[1] = (_Float16)o.y;
        hh[2] = (_Float16)o.z; hh[3] = (_Float16)o.w;
        *(f16x4*)(a16 + ga + i * 4) = hh;
    }
}

// ---------------------------------------------------------------------------
// Classifier: logits[b,n] = dot(x32[b,0,:], Wc[n,:]) + bc[n]
// ---------------------------------------------------------------------------
__global__ void cls_kernel(const float* __restrict__ x32,
                           const float* __restrict__ Wc,
                           const float* __restrict__ bc,
                           float* __restrict__ out) {
    const int b = blockIdx.x >> 1;
    const int n = blockIdx.x & 1;
    const int t = threadIdx.x;
    const float* px = x32 + (size_t)b * Ss * Hdim;   // row s=0
    const float* pw = Wc + (size_t)n * Hdim;
    float partial = 0.f;
    for (int k = t; k < Hdim; k += 256) partial = fmaf(px[k], pw[k], partial);
    __shared__ float red[256];
    red[t] = partial;
    __syncthreads();
    for (int off = 128; off > 0; off >>= 1) {
        if (t < off) red[t] += red[t + off];
        __syncthreads();
    }
    if (t == 0) out[blockIdx.x] = red[0] + bc[n];
}

// ---------------------------------------------------------------------------
extern "C" void kernel_launch(void* const* d_in, const int* in_sizes, int n_in,
                              void* d_out, int out_size, void* d_ws, size_t ws_size,
                              hipStream_t stream) {
    const int*   ids = (const int*)d_in[0];
    const float* emb = (const float*)d_in[1];
    const float* Wq  = (const float*)d_in[2];
    const float* bq  = (const float*)d_in[3];
    const float* Wk  = (const float*)d_in[4];
    const float* bk  = (const float*)d_in[5];
    const float* Wv  = (const float*)d_in[6];
    const float* bv  = (const float*)d_in[7];
    const float* Wi  = (const float*)d_in[8];
    const float* bi  = (const float*)d_in[9];
    const float* Wo  = (const float*)d_in[10];
    const float* bo  = (const float*)d_in[11];
    const float* Wc  = (const float*)d_in[12];
    const float* bc  = (const float*)d_in[13];
    float* out = (float*)d_out;

    const size_t F  = (size_t)Mm * Hdim;      // 3,145,728
    const size_t WS = (size_t)Hdim * Hdim;    // 589,824

    float*    x32 = (float*)d_ws;             // fp32 residual stream
    _Float16* xh  = (_Float16*)(x32 + F);     // fp16 GEMM input copy
    _Float16* qkv = xh + F;                   // 3F fp16
    _Float16* a16 = qkv + 3 * F;              // attn out fp16
    _Float16* i16 = a16 + F;                  // inter fp16
    _Float16* w16 = i16 + F;                  // ALL layers' weights fp16 (20*WS)
    float*    a32 = (float*)(w16 + 20 * WS);  // attn out fp32 (Wo residual)
    float*    Op0 = a32 + F;                  // fp32 partials
    float*    Op1 = Op0 + F;
    float*    Mp  = Op1 + F;                  // [2][PL]
    float*    Lp  = Mp + 2 * PL;              // [2][PL]

    embed_kernel<<<Mm, 192, 0, stream>>>(ids, emb, x32, xh);
    cvtw_kernel<<<NLAYER * 5 * 147456 / 256, 256, 0, stream>>>(Wq, Wk, Wv, Wi, Wo, w16);

    for (int l = 0; l < NLAYER; ++l) {
        _Float16* wl = w16 + (size_t)l * 5 * WS;
        // fused QKV: W rows 0..2303 = Wq|Wk|Wv (contiguous in wl)
        gemm_f16<<<1152, 256, 0, stream>>>(
            xh, wl, bq + l*Hdim, bk + l*Hdim, bv + l*Hdim,
            nullptr, qkv, nullptr, 0, F, 0.125f * LOG2E, 64);
        attn_mfma<<<dim3(16, NH, Bb), 256, 0, stream>>>(
            qkv, qkv + F, qkv + 2*F, Op0, Op1, Mp, Lp);
        merge_kernel<<<PL * 4 / 256, 256, 0, stream>>>(Op0, Op1, Mp, Lp, a16, a32);
        gemm_f16<<<384, 256, 0, stream>>>(
            a16, wl + 3*WS, bi + l*Hdim, bi + l*Hdim, bi + l*Hdim,
            nullptr, i16, nullptr, 1, 0, 1.f, 64);
        gemm_f16<<<384, 256, 0, stream>>>(
            i16, wl + 4*WS, bo + l*Hdim, bo + l*Hdim, bo + l*Hdim,
            a32, xh, x32, 0, 0, 1.f, 64);
    }

    cls_kernel<<<Bb * NL, 256, 0, stream>>>(x32, Wc, bc, out);
}

// Round 12
// 412.592 us; speedup vs baseline: 11.7526x; 1.0582x over previous
//
#include <hip/hip_runtime.h>
#include <hip/hip_bf16.h>
#include <math.h>

// Problem constants
constexpr int Hdim = 768;
constexpr int NH   = 12;
constexpr int HD   = 64;
constexpr int NLAYER = 4;
constexpr int Bb   = 4;
constexpr int Ss   = 1024;
constexpr int Mm   = Bb * Ss;   // 4096 rows
constexpr int NL   = 2;
constexpr int PL   = Bb * NH * Ss;   // 49152 q-rows total
constexpr float LOG2E = 1.44269504088896f;

typedef _Float16 f16x8 __attribute__((ext_vector_type(8)));
typedef _Float16 f16x4 __attribute__((ext_vector_type(4)));
typedef __fp16   h16x2 __attribute__((ext_vector_type(2)));
typedef float    f32x4 __attribute__((ext_vector_type(4)));

__device__ __forceinline__ f32x4 mfma32h(f16x8 a, f16x8 b, f32x4 c) {
#if __has_builtin(__builtin_amdgcn_mfma_f32_16x16x32_f16)
    return __builtin_amdgcn_mfma_f32_16x16x32_f16(a, b, c, 0, 0, 0);
#else
    asm("v_mfma_f32_16x16x32_f16 %0, %1, %2, %0" : "+v"(c) : "v"(a), "v"(b));
    return c;
#endif
}
__device__ __forceinline__ f32x4 mfma16h(f16x4 a, f16x4 b, f32x4 c) {
#if __has_builtin(__builtin_amdgcn_mfma_f32_16x16x16f16)
    return __builtin_amdgcn_mfma_f32_16x16x16f16(a, b, c, 0, 0, 0);
#else
    asm("v_mfma_f32_16x16x16_f16 %0, %1, %2, %0" : "+v"(c) : "v"(a), "v"(b));
    return c;
#endif
}

// async global->LDS, 16B per lane; LDS dest = wave-uniform base + lane*16.
__device__ __forceinline__ void gload16(const void* g, void* l) {
    __builtin_amdgcn_global_load_lds(
        (const __attribute__((address_space(1))) unsigned int*)g,
        (__attribute__((address_space(3))) unsigned int*)l, 16, 0, 0);
}

// ---------------------------------------------------------------------------
// Fused prep: embedding gather (fp32 + fp16) and all-layer weight fp16 cvt.
// Blocks [0, 3072): embed (4096 rows x 192 quad-jobs).
// Blocks [3072, 14592): weight convert (4 layers x 5 x 147456 quads).
// ---------------------------------------------------------------------------
__global__ void prep_kernel(const int* __restrict__ ids,
                            const float* __restrict__ emb,
                            float* __restrict__ x32, _Float16* __restrict__ xh,
                            const float* __restrict__ Wq, const float* __restrict__ Wk,
                            const float* __restrict__ Wv, const float* __restrict__ Wi,
                            const float* __restrict__ Wo,
                            _Float16* __restrict__ w16) {
    if (blockIdx.x < 3072) {
        int gidx = blockIdx.x * 256 + threadIdx.x;   // 0..786431
        int row = gidx / 192, t = gidx - row * 192;
        int id = ids[row];
        float4 v = ((const float4*)(emb + (size_t)id * Hdim))[t];
        ((float4*)(x32 + (size_t)row * Hdim))[t] = v;
        f16x4 h;
        h[0] = (_Float16)v.x; h[1] = (_Float16)v.y;
        h[2] = (_Float16)v.z; h[3] = (_Float16)v.w;
        *(f16x4*)(xh + (size_t)row * Hdim + t * 4) = h;
    } else {
        int i = (blockIdx.x - 3072) * 256 + threadIdx.x;   // 0..2949119
        int l = i / (5 * 147456);
        int rem = i - l * (5 * 147456);
        int which = rem / 147456;
        int j = rem - which * 147456;
        const float* src = (which == 0 ? Wq : which == 1 ? Wk : which == 2 ? Wv
                          : which == 3 ? Wi : Wo) + (size_t)l * 589824;
        float4 v = ((const float4*)src)[j];
        f16x4 h;
        h[0] = (_Float16)v.x; h[1] = (_Float16)v.y;
        h[2] = (_Float16)v.z; h[3] = (_Float16)v.w;
        *(f16x4*)(w16 + ((size_t)l * 5 + which) * 589824 + (size_t)j * 4) = h;
    }
}

// ---------------------------------------------------------------------------
// fp16 MFMA GEMM, BK=64, 256 threads = 4 waves, BN=128.
// BM=64: wave grid 2x2, wave tile 32x64 (QKV fused N=2304, grid 1152).
// BM=32: waves split N 4 ways, wave tile 32x32 (Wi/Wo, grid 768 = 3/CU).
// 1-D grid with XCD swizzle (nwg % 8 == 0).
// ---------------------------------------------------------------------------
template<int BM>
__global__ __launch_bounds__(256) void gemm_f16(
    const _Float16* __restrict__ Xh, const _Float16* __restrict__ Wh,
    const float* __restrict__ b0, const float* __restrict__ b1,
    const float* __restrict__ b2,
    const float* __restrict__ resid32,
    _Float16* __restrict__ Yh, float* __restrict__ Y32,
    int relu, size_t outSeg, float qscale, int gm)
{
    constexpr int ABASE = BM * 64;            // halves
    constexpr int NFR   = (BM == 64) ? 4 : 2; // B fragments per wave
    __shared__ _Float16 lds[ABASE + 8192];

    const int tid = threadIdx.x;
    const int lane = tid & 63, w = tid >> 6;
    const int l15 = lane & 15, g = lane >> 4;

    // XCD-aware block swizzle (bijective since nwg % 8 == 0)
    const int nwg = gridDim.x;
    const int cpx = nwg >> 3;
    const int bid = blockIdx.x;
    const int x   = (bid & 7) * cpx + (bid >> 3);
    const int m0  = (x % gm) * BM;
    const int n0  = (x / gm) * 128;

    const int srow = lane >> 3;                    // 0..7
    const int sswz = 8 * ((lane & 7) ^ srow);      // swizzled slot (halves)
    const _Float16* pA;
    _Float16* lA;
    if constexpr (BM == 64) {
        pA = Xh + (size_t)(m0 + w*16 + srow) * Hdim + sswz;
        lA = &lds[0] + w * 1024;
    } else {
        pA = Xh + (size_t)(m0 + w*8 + srow) * Hdim + sswz;
        lA = &lds[0] + w * 512;
    }
    const _Float16* pB = Wh + (size_t)(n0 + w*32 + srow) * Hdim + sswz;
    _Float16* lB = &lds[ABASE] + w * 2048;

    f32x4 acc[2][NFR];
    #pragma unroll
    for (int m = 0; m < 2; ++m)
        #pragma unroll
        for (int n = 0; n < NFR; ++n) acc[m][n] = (f32x4){0.f, 0.f, 0.f, 0.f};

    const int fsw = l15 & 7;

    for (int k0 = 0; k0 < Hdim; k0 += 64) {
        __syncthreads();
        if constexpr (BM == 64) {
            gload16(pA + k0,          lA);
            gload16(pA + k0 + 8*Hdim, lA + 512);
        } else {
            gload16(pA + k0, lA);
        }
        #pragma unroll
        for (int j = 0; j < 4; ++j)
            gload16(pB + k0 + j*8*Hdim, lB + j*512);
        __syncthreads();

        #pragma unroll
        for (int ks = 0; ks < 2; ++ks) {
            const int so = 8 * ((ks*4 + g) ^ fsw);
            f16x8 af[2], bf[NFR];
            #pragma unroll
            for (int m = 0; m < 2; ++m) {
                const int ar = (BM == 64) ? ((w >> 1)*32 + m*16 + l15)
                                          : (m*16 + l15);
                af[m] = *(const f16x8*)&lds[ar * 64 + so];
            }
            #pragma unroll
            for (int n = 0; n < NFR; ++n) {
                const int br = (BM == 64) ? ((w & 1)*64 + n*16 + l15)
                                          : (w*32 + n*16 + l15);
                bf[n] = *(const f16x8*)&lds[ABASE + br * 64 + so];
            }
            #pragma unroll
            for (int m = 0; m < 2; ++m)
                #pragma unroll
                for (int n = 0; n < NFR; ++n)
                    acc[m][n] = mfma32h(af[m], bf[n], acc[m][n]);
        }
    }

    // Epilogue. D layout: col=lane&15, row=(lane>>4)*4+reg.
    const int rb = (BM == 64) ? (m0 + (w >> 1)*32 + g*4) : (m0 + g*4);
    #pragma unroll
    for (int n = 0; n < NFR; ++n) {
        const int col = (BM == 64) ? (n0 + (w & 1)*64 + n*16 + l15)
                                   : (n0 + w*32 + n*16 + l15);
        const int seg = col / Hdim;
        const int lc  = col - seg * Hdim;
        const float bias = (seg == 0 ? b0 : seg == 1 ? b1 : b2)[lc];
        #pragma unroll
        for (int m = 0; m < 2; ++m) {
            #pragma unroll
            for (int r = 0; r < 4; ++r) {
                const size_t idx = (size_t)seg * outSeg + (size_t)(rb + m*16 + r) * Hdim + lc;
                float v = acc[m][n][r] + bias;
                if (seg == 0) v *= qscale;
                if (relu) v = v > 0.f ? v : 0.f;
                if (resid32) v += resid32[idx];
                Yh[idx] = (_Float16)v;
                if (Y32) Y32[idx] = v;
            }
        }
    }
}

// ---------------------------------------------------------------------------
// fp16 MFMA flash attention partials, KV-split 2-way. Block = 128 q x 512 KV.
// Q pre-scaled by log2e/8 (scores in log2 domain -> native v_exp for exp2).
// K AND V double-buffered -> ONE barrier per tile.
// LDS (halves): K0@0 K1@4096 V0@8192 V1@12800 (stride 72) = 34816 B.
// ---------------------------------------------------------------------------
__global__ __launch_bounds__(256, 4) void attn_mfma(
    const _Float16* __restrict__ Qh, const _Float16* __restrict__ Kh,
    const _Float16* __restrict__ Vh,
    float* __restrict__ Op0, float* __restrict__ Op1,
    float* __restrict__ Mp, float* __restrict__ Lp)
{
    __shared__ _Float16 sm[17408];   // 34816 B

    const int tid  = threadIdx.x;
    const int lane = tid & 63, wid = tid >> 6;
    const int l15  = lane & 15, g = lane >> 4;
    const int qtile = blockIdx.x >> 1, part = blockIdx.x & 1;
    const int h = blockIdx.y, b = blockIdx.z;

    const size_t rowbase = (size_t)b * Ss;
    const int    colbase = h * HD;
    const int    q0 = qtile * 128 + wid * 32;
    const int    kv0 = part * 512;

    // Hoisted Q fragments [qfrag][kstep]
    f16x8 qf[2][2];
    #pragma unroll
    for (int nf = 0; nf < 2; ++nf) {
        const size_t r = (rowbase + q0 + nf * 16 + l15) * Hdim + colbase;
        #pragma unroll
        for (int ks = 0; ks < 2; ++ks)
            qf[nf][ks] = *(const f16x8*)(Qh + r + ks * 32 + g * 8);
    }

    f32x4 accO[4][2];
    #pragma unroll
    for (int mf = 0; mf < 4; ++mf)
        #pragma unroll
        for (int nf = 0; nf < 2; ++nf) accO[mf][nf] = (f32x4){0.f, 0.f, 0.f, 0.f};
    float mrun[2] = {-1e30f, -1e30f}, lsum[2] = {0.f, 0.f};

    // K staging constants
    const int s8 = lane >> 3;
    const int kswz = 8 * ((lane & 7) ^ s8);
    const _Float16* gK = Kh + (rowbase + kv0 + wid*16 + s8) * Hdim + colbase + kswz;

    // V staging: wave wid covers cols [wid*16, wid*16+16), lane = KV row.
    const int kx = lane ^ (wid << 4);
    const _Float16* gV = Vh + (rowbase + kv0 + lane) * Hdim + colbase + wid * 16;
    uint4 vr[2];

    const int fsw = l15 & 7;

    // ---- prologue: stage tile 0 into K0/V0 -------------------------------
    gload16(gK,          &sm[0] + wid*1024);
    gload16(gK + 8*Hdim, &sm[0] + wid*1024 + 512);
    #pragma unroll
    for (int u = 0; u < 2; ++u) vr[u] = *(const uint4*)(gV + u * 8);
    #pragma unroll
    for (int u = 0; u < 2; ++u) {
        const _Float16* hs = (const _Float16*)&vr[u];
        #pragma unroll
        for (int j = 0; j < 8; ++j)
            sm[8192 + (wid*16 + u*8 + j) * 72 + kx] = hs[j];
    }
    __syncthreads();

    for (int t = 0; t < 8; ++t) {
        const int cur = t & 1;
        const int kb = cur * 4096;
        const int vb = 8192 + cur * 4608;
        // ---- prefetch tile t+1: K -> off LDS buf, V -> regs --------------
        if (t < 7) {
            const int nkb = (cur ^ 1) * 4096;
            const size_t ko = (size_t)((t + 1) * 64) * Hdim;
            gload16(gK + ko,          &sm[nkb] + wid*1024);
            gload16(gK + ko + 8*Hdim, &sm[nkb] + wid*1024 + 512);
            #pragma unroll
            for (int u = 0; u < 2; ++u)
                vr[u] = *(const uint4*)(gV + ko + u * 8);
        }

        // ---- S^T = K · Q^T (fp16 single-term; log2-domain scores) --------
        f32x4 sc[4][2];
        #pragma unroll
        for (int m = 0; m < 4; ++m)
            #pragma unroll
            for (int nf = 0; nf < 2; ++nf) sc[m][nf] = (f32x4){0.f, 0.f, 0.f, 0.f};
        __builtin_amdgcn_s_setprio(1);
        #pragma unroll
        for (int ks = 0; ks < 2; ++ks) {
            const int so = 8 * ((ks*4 + g) ^ fsw);
            #pragma unroll
            for (int m = 0; m < 4; ++m) {
                f16x8 kh_ = *(const f16x8*)&sm[kb + (m * 16 + l15) * 64 + so];
                #pragma unroll
                for (int nf = 0; nf < 2; ++nf)
                    sc[m][nf] = mfma32h(kh_, qf[nf][ks], sc[m][nf]);
            }
        }
        __builtin_amdgcn_s_setprio(0);

        // ---- online softmax (exp2 domain, defer-max) ---------------------
        f16x4 pb[4][2];
        #pragma unroll
        for (int nf = 0; nf < 2; ++nf) {
            float tl = -1e30f;
            #pragma unroll
            for (int m = 0; m < 4; ++m)
                #pragma unroll
                for (int r = 0; r < 4; ++r) tl = fmaxf(tl, sc[m][nf][r]);
            if (__any(tl > mrun[nf] + 11.5416f)) {       // 8 nats in log2 units
                float tmax = fmaxf(tl, __shfl_xor(tl, 16));
                tmax = fmaxf(tmax, __shfl_xor(tmax, 32));
                const float mnew = fmaxf(mrun[nf], tmax);
                const float corr = __builtin_amdgcn_exp2f(mrun[nf] - mnew);
                mrun[nf] = mnew;
                lsum[nf] *= corr;
                #pragma unroll
                for (int mf = 0; mf < 4; ++mf) {
                    accO[mf][nf][0] *= corr; accO[mf][nf][1] *= corr;
                    accO[mf][nf][2] *= corr; accO[mf][nf][3] *= corr;
                }
            }
            float ps = 0.f;
            #pragma unroll
            for (int m = 0; m < 4; ++m)
                #pragma unroll
                for (int r = 0; r < 4; ++r) {
                    const float p = __builtin_amdgcn_exp2f(sc[m][nf][r] - mrun[nf]);
                    sc[m][nf][r] = p;
                    ps += p;
                }
            lsum[nf] += ps;
            #pragma unroll
            for (int kt = 0; kt < 4; ++kt) {
                union { h16x2 h2[2]; f16x4 v; } u;
                u.h2[0] = __builtin_amdgcn_cvt_pkrtz(sc[kt][nf][0], sc[kt][nf][1]);
                u.h2[1] = __builtin_amdgcn_cvt_pkrtz(sc[kt][nf][2], sc[kt][nf][3]);
                pb[kt][nf] = u.v;
            }
        }

        // ---- write V(t+1) into the off buffer ----------------------------
        if (t < 7) {
            const int nvb = 8192 + (cur ^ 1) * 4608;
            #pragma unroll
            for (int u = 0; u < 2; ++u) {
                const _Float16* hs = (const _Float16*)&vr[u];
                #pragma unroll
                for (int j = 0; j < 8; ++j)
                    sm[nvb + (wid*16 + u*8 + j) * 72 + kx] = hs[j];
            }
        }

        // ---- O^T += V^T · P^T (fp16 single-term) -------------------------
        __builtin_amdgcn_s_setprio(1);
        #pragma unroll
        for (int kt = 0; kt < 4; ++kt)
            #pragma unroll
            for (int mf = 0; mf < 4; ++mf) {
                const int voff = vb + (mf * 16 + l15) * 72 + ((kt ^ mf) * 16 + g * 4);
                f16x4 vh_ = *(const f16x4*)&sm[voff];
                #pragma unroll
                for (int nf = 0; nf < 2; ++nf)
                    accO[mf][nf] = mfma16h(vh_, pb[kt][nf], accO[mf][nf]);
            }
        __builtin_amdgcn_s_setprio(0);

        __syncthreads();   // drains K(t+1) gloads; publishes V(t+1)
    }

    // ---- epilogue: reduce l across lanes; write fp32 partials ------------
    #pragma unroll
    for (int nf = 0; nf < 2; ++nf) {
        lsum[nf] += __shfl_xor(lsum[nf], 16);
        lsum[nf] += __shfl_xor(lsum[nf], 32);
    }
    float* ot = (float*)sm + wid * 2176;   // 32 rows x stride 68
    #pragma unroll
    for (int nf = 0; nf < 2; ++nf) {
        #pragma unroll
        for (int mf = 0; mf < 4; ++mf)
            #pragma unroll
            for (int r = 0; r < 4; ++r)
                ot[(nf * 16 + l15) * 68 + mf * 16 + g * 4 + r] = accO[mf][nf][r];
    }
    if (g == 0) {
        #pragma unroll
        for (int nf = 0; nf < 2; ++nf) {
            const size_t idx = (size_t)part * PL +
                (((size_t)b * NH + h) * Ss + q0 + nf * 16 + l15);
            Mp[idx] = mrun[nf];
            Lp[idx] = lsum[nf];
        }
    }
    __syncthreads();
    float* Op = part ? Op1 : Op0;
    const int orow = lane >> 1, oc = (lane & 1) * 32;
    const size_t pbase = (((size_t)b * NH + h) * Ss + q0 + orow) * 64 + oc;
    #pragma unroll
    for (int i = 0; i < 8; ++i)
        *(float4*)(Op + pbase + i * 4) = *(float4*)&ot[orow * 68 + oc + i * 4];
}

// ---------------------------------------------------------------------------
// Merge the two KV-split partials -> attn output (fp16 for Wi, fp32 resid).
// m values are in log2 domain.
// ---------------------------------------------------------------------------
__global__ void merge_kernel(const float* __restrict__ Op0, const float* __restrict__ Op1,
                             const float* __restrict__ Mp, const float* __restrict__ Lp,
                             _Float16* __restrict__ a16, float* __restrict__ a32) {
    const int id = blockIdx.x * 256 + threadIdx.x;   // 0..196607
    const int idx = id >> 2, dseg = id & 3;
    const int b = idx / (NH * Ss);
    const int rem = idx - b * NH * Ss;
    const int h = rem / Ss, q = rem - h * Ss;
    const float m0 = Mp[idx], m1 = Mp[PL + idx];
    const float l0 = Lp[idx], l1 = Lp[PL + idx];
    const float M  = fmaxf(m0, m1);
    const float e0 = __builtin_amdgcn_exp2f(m0 - M);
    const float e1 = __builtin_amdgcn_exp2f(m1 - M);
    const float inv = 1.f / (l0 * e0 + l1 * e1);
    const size_t pb = (size_t)idx * 64 + dseg * 16;
    const size_t ga = ((size_t)(b * Ss + q)) * Hdim + h * 64 + dseg * 16;
    #pragma unroll
    for (int i = 0; i < 4; ++i) {
        float4 a = *(const float4*)(Op0 + pb + i * 4);
        float4 c = *(const float4*)(Op1 + pb + i * 4);
        float4 o;
        o.x = (a.x * e0 + c.x * e1) * inv;
        o.y = (a.y * e0 + c.y * e1) * inv;
        o.z = (a.z * e0 + c.z * e1) * inv;
        o.w = (a.w * e0 + c.w * e1) * inv;
        *(float4*)(a32 + ga + i * 4) = o;
        f16x4 hh;
        hh[0] = (_Float16)o.x; hh[1] = (_Float16)o.y;
        hh[2] = (_Float16)o.z; hh[3] = (_Float16)o.w;
        *(f16x4*)(a16 + ga + i * 4) = hh;
    }
}

// ---------------------------------------------------------------------------
// Classifier: logits[b,n] = dot(x32[b,0,:], Wc[n,:]) + bc[n]
// ---------------------------------------------------------------------------
__global__ void cls_kernel(const float* __restrict__ x32,
                           const float* __restrict__ Wc,
                           const float* __restrict__ bc,
                           float* __restrict__ out) {
    const int b = blockIdx.x >> 1;
    const int n = blockIdx.x & 1;
    const int t = threadIdx.x;
    const float* px = x32 + (size_t)b * Ss * Hdim;   // row s=0
    const float* pw = Wc + (size_t)n * Hdim;
    float partial = 0.f;
    for (int k = t; k < Hdim; k += 256) partial = fmaf(px[k], pw[k], partial);
    __shared__ float red[256];
    red[t] = partial;
    __syncthreads();
    for (int off = 128; off > 0; off >>= 1) {
        if (t < off) red[t] += red[t + off];
        __syncthreads();
    }
    if (t == 0) out[blockIdx.x] = red[0] + bc[n];
}

// ---------------------------------------------------------------------------
extern "C" void kernel_launch(void* const* d_in, const int* in_sizes, int n_in,
                              void* d_out, int out_size, void* d_ws, size_t ws_size,
                              hipStream_t stream) {
    const int*   ids = (const int*)d_in[0];
    const float* emb = (const float*)d_in[1];
    const float* Wq  = (const float*)d_in[2];
    const float* bq  = (const float*)d_in[3];
    const float* Wk  = (const float*)d_in[4];
    const float* bk  = (const float*)d_in[5];
    const float* Wv  = (const float*)d_in[6];
    const float* bv  = (const float*)d_in[7];
    const float* Wi  = (const float*)d_in[8];
    const float* bi  = (const float*)d_in[9];
    const float* Wo  = (const float*)d_in[10];
    const float* bo  = (const float*)d_in[11];
    const float* Wc  = (const float*)d_in[12];
    const float* bc  = (const float*)d_in[13];
    float* out = (float*)d_out;

    const size_t F  = (size_t)Mm * Hdim;      // 3,145,728
    const size_t WS = (size_t)Hdim * Hdim;    // 589,824

    float*    x32 = (float*)d_ws;             // fp32 residual stream
    _Float16* xh  = (_Float16*)(x32 + F);     // fp16 GEMM input copy
    _Float16* qkv = xh + F;                   // 3F fp16
    _Float16* a16 = qkv + 3 * F;              // attn out fp16
    _Float16* i16 = a16 + F;                  // inter fp16
    _Float16* w16 = i16 + F;                  // ALL layers' weights fp16 (20*WS)
    float*    a32 = (float*)(w16 + 20 * WS);  // attn out fp32 (Wo residual)
    float*    Op0 = a32 + F;                  // fp32 partials
    float*    Op1 = Op0 + F;
    float*    Mp  = Op1 + F;                  // [2][PL]
    float*    Lp  = Mp + 2 * PL;              // [2][PL]

    prep_kernel<<<14592, 256, 0, stream>>>(ids, emb, x32, xh, Wq, Wk, Wv, Wi, Wo, w16);

    for (int l = 0; l < NLAYER; ++l) {
        _Float16* wl = w16 + (size_t)l * 5 * WS;
        // fused QKV: W rows 0..2303 = Wq|Wk|Wv (contiguous in wl)
        gemm_f16<64><<<1152, 256, 0, stream>>>(
            xh, wl, bq + l*Hdim, bk + l*Hdim, bv + l*Hdim,
            nullptr, qkv, nullptr, 0, F, 0.125f * LOG2E, 64);
        attn_mfma<<<dim3(16, NH, Bb), 256, 0, stream>>>(
            qkv, qkv + F, qkv + 2*F, Op0, Op1, Mp, Lp);
        merge_kernel<<<PL * 4 / 256, 256, 0, stream>>>(Op0, Op1, Mp, Lp, a16, a32);
        gemm_f16<32><<<768, 256, 0, stream>>>(
            a16, wl + 3*WS, bi + l*Hdim, bi + l*Hdim, bi + l*Hdim,
            nullptr, i16, nullptr, 1, 0, 1.f, 128);
        gemm_f16<32><<<768, 256, 0, stream>>>(
            i16, wl + 4*WS, bo + l*Hdim, bo + l*Hdim, bo + l*Hdim,
            a32, xh, x32, 0, 0, 1.f, 128);
    }

    cls_kernel<<<Bb * NL, 256, 0, stream>>>(x32, Wc, bc, out);
}